// Round 10
// baseline (865.222 us; speedup 1.0000x reference)
//
#include <hip/hip_runtime.h>
#include <math.h>

// Performer FAVOR+ causal linear attention, MI355X.
// B=4 H=16 S=4096 D=64 M=256 features, COND=128 non-causal prefix.
// v11 = v10 + kf-persistence: b_kernel writes its swizzled kf LDS tile
// (byte-identical image, 32KB/subtile) to workspace; d_kernel loads it with
// producer-pattern addresses instead of recomputing (conv_k + dd_k + exp/pack
// = 24 MFMA + ~110 VALU + 1 barrier per subtile removed; barriers 7->6).
// z-update reconstructed from unpacked hi+lo (2^-16 rel). dgq/rmax moved to
// dedicated LDS (kf head overlay would race with the merged P2 writes).
// GATED on ws_size >= ~397MB: kfg==nullptr -> exact v10 path (uniform branch).
// ws: [0..4) kmax, [256..) Ph/Pl bf16[256][64], Pfh/Pfl frag-major (32KB ea),
//     states [64][nch][SLOT_F] f32, then optional kfglob [64][124][8192] u32.

#define S_TOT 4096
#define CONDL 128
#define SLOT_F 16640
#define RATIO 0.0625f
#define DNORM 0.35355339059327378f
#define KEPS  1e-4f
#define AEPS  1e-6f

typedef __attribute__((ext_vector_type(8))) short bf16x8;
typedef __attribute__((ext_vector_type(2))) unsigned uint2v;
typedef __attribute__((ext_vector_type(4))) float f32x4;

#define MFMA16(a,b,c) __builtin_amdgcn_mfma_f32_16x16x32_bf16(a,b,c,0,0,0)

static __device__ __forceinline__ unsigned cvtpk(float a, float b){
    unsigned r;
    asm("v_cvt_pk_bf16_f32 %0, %1, %2" : "=v"(r) : "v"(a), "v"(b));
    return r;
}
static __device__ __forceinline__ float lo16f(unsigned u){ return __uint_as_float(u << 16); }
static __device__ __forceinline__ float hi16f(unsigned u){ return __uint_as_float(u & 0xffff0000u); }
static __device__ __forceinline__ float unpackhl(unsigned u){ return lo16f(u) + hi16f(u); }

static __device__ __forceinline__ unsigned short f2bh(float x){
    unsigned u = __float_as_uint(x);
    u += 0x7fffu + ((u >> 16) & 1u);
    return (unsigned short)(u >> 16);
}
static __device__ __forceinline__ float bh2f(unsigned short h){
    return __uint_as_float((unsigned)h << 16);
}
// pack hi/lo bf16 of x into one dword (hi in low16, residual-lo in high16)
static __device__ __forceinline__ unsigned packhl(float x){
    unsigned u1 = cvtpk(x, x);
    float r = x - lo16f(u1);
    return cvtpk(x, r);
}
// two uint4 (halves k=[0..15],[16..31] of this lane's 4+4 elems) -> hi/lo frags
static __device__ __forceinline__ void unpk(const uint4 a, const uint4 b, bf16x8& h, bf16x8& l){
    h[0]=(short)a.x; h[1]=(short)a.y; h[2]=(short)a.z; h[3]=(short)a.w;
    h[4]=(short)b.x; h[5]=(short)b.y; h[6]=(short)b.z; h[7]=(short)b.w;
    l[0]=(short)(a.x>>16); l[1]=(short)(a.y>>16); l[2]=(short)(a.z>>16); l[3]=(short)(a.w>>16);
    l[4]=(short)(b.x>>16); l[5]=(short)(b.y>>16); l[6]=(short)(b.z>>16); l[7]=(short)(b.w>>16);
}
static __device__ __forceinline__ unsigned mapf(float x){
    unsigned u = __float_as_uint(x);
    return (u & 0x80000000u) ? ~u : (u | 0x80000000u);
}
static __device__ __forceinline__ float unmapf(unsigned u){
    return __uint_as_float((u & 0x80000000u) ? (u ^ 0x80000000u) : ~u);
}

// Convert a pre-loaded 32x64 f32 tile row-quad into frag-major hi/lo bf16
// planes + row diag (cooperative across 512 threads).
static __device__ __forceinline__ void conv_store(float4 x4, int tid,
        short (*Xh)[64][8], short (*Xl)[64][8], float* __restrict__ diag_)
{
    int row = tid >> 4;
    int c4  = (tid & 15) * 4;
    float x0 = x4.x*DNORM, x1 = x4.y*DNORM, x2 = x4.z*DNORM, x3 = x4.w*DNORM;
    float ss = x0*x0 + x1*x1 + x2*x2 + x3*x3;
    ss += __shfl_xor(ss, 1, 64);
    ss += __shfl_xor(ss, 2, 64);
    ss += __shfl_xor(ss, 4, 64);
    ss += __shfl_xor(ss, 8, 64);
    if ((tid & 15) == 0) diag_[row] = 0.5f * ss;
    int rt = row >> 4, lr = row & 15;
    int kk = c4 >> 5, c5 = c4 & 31;
    int fg, j0;
    if (c5 < 16){ fg = c5 >> 2; j0 = 0; } else { fg = (c5 - 16) >> 2; j0 = 4; }
    int f = kk*2 + rt;
    unsigned a01 = cvtpk(x0, x1), a23 = cvtpk(x2, x3);
    unsigned b01 = cvtpk(x0 - lo16f(a01), x1 - hi16f(a01));
    unsigned b23 = cvtpk(x2 - lo16f(a23), x3 - hi16f(a23));
    uint2v hv, lv;
    hv[0] = a01; hv[1] = a23;
    lv[0] = b01; lv[1] = b23;
    *(uint2v*)&Xh[f][fg*16 + lr][j0] = hv;
    *(uint2v*)&Xl[f][fg*16 + lr][j0] = lv;
}

static __device__ __forceinline__ void conv_write(const float* __restrict__ Xg, long r0,
        int tid, short (*Xh)[64][8], short (*Xl)[64][8], float* __restrict__ diag_)
{
    int row = tid >> 4;
    int c4  = (tid & 15) * 4;
    float4 x4 = *(const float4*)(Xg + (r0 + row)*64 + c4);
    conv_store(x4, tid, Xh, Xl, diag_);
}

// ---- old-style P fragment load (Ph/Pl flat [m][d]) -- used by b_kernel ----
static __device__ __forceinline__ void load_pfrags(const unsigned short* __restrict__ Ph,
        const unsigned short* __restrict__ Pl, int w, int l15, int g,
        bf16x8 (&Pfh)[2][2], bf16x8 (&Pfl)[2][2])
{
#pragma unroll
    for (int mt=0; mt<2; mt++)
#pragma unroll
      for (int kk=0; kk<2; kk++){
        const unsigned short* ph = Ph + (w*32 + mt*16 + l15)*64 + kk*32 + g*4;
        const unsigned short* pl = Pl + (w*32 + mt*16 + l15)*64 + kk*32 + g*4;
        bf16x8 fh, fl;
#pragma unroll
        for (int j=0;j<4;j++){
            fh[j]=(short)ph[j]; fh[4+j]=(short)ph[16+j];
            fl[j]=(short)pl[j]; fl[4+j]=(short)pl[16+j];
        }
        Pfh[mt][kk]=fh; Pfl[mt][kk]=fl;
      }
}

// frag-major P load (coalesced b128) -- used by d_kernel, held in registers
static __device__ __forceinline__ void load_pfrags_fm(const unsigned short* __restrict__ Pfh,
        const unsigned short* __restrict__ Pfl, int w, int lane,
        bf16x8 (&Ph_r)[2][2], bf16x8 (&Pl_r)[2][2])
{
#pragma unroll
    for (int kk=0; kk<2; kk++)
#pragma unroll
      for (int mt=0; mt<2; mt++){
        int f = w*4 + kk*2 + mt;
        Ph_r[mt][kk] = *(const bf16x8*)(Pfh + (f*64 + lane)*8);
        Pl_r[mt][kk] = *(const bf16x8*)(Pfl + (f*64 + lane)*8);
      }
}

// dd GEMM from shared frags, register P-frags
static __device__ __forceinline__ void dd_frags(const short (*Xh)[64][8], const short (*Xl)[64][8],
        int lane, const bf16x8 (&Pfh)[2][2], const bf16x8 (&Pfl)[2][2], f32x4 (&acc)[2][2])
{
#pragma unroll
    for (int rt=0;rt<2;rt++)
#pragma unroll
      for (int mt=0;mt<2;mt++) acc[rt][mt] = f32x4{0.f,0.f,0.f,0.f};
#pragma unroll
    for (int kk=0;kk<2;kk++)
#pragma unroll
      for (int rt=0;rt<2;rt++){
        bf16x8 xh = *(const bf16x8*)&Xh[kk*2+rt][lane][0];
        bf16x8 xl = *(const bf16x8*)&Xl[kk*2+rt][lane][0];
#pragma unroll
        for (int mt=0;mt<2;mt++){
            acc[rt][mt] = MFMA16(xh, Pfh[mt][kk], acc[rt][mt]);
            acc[rt][mt] = MFMA16(xh, Pfl[mt][kk], acc[rt][mt]);
            acc[rt][mt] = MFMA16(xl, Pfh[mt][kk], acc[rt][mt]);
        }
      }
}

// build hi/lo bf16 B-frag for one kt directly from f32 values (C-layout regs)
static __device__ __forceinline__ void sfrag(const f32x4 a, const f32x4 b, bf16x8& h, bf16x8& l){
    union U { bf16x8 v; unsigned u[4]; } H, L;
    H.u[0] = cvtpk(a[0], a[1]); H.u[1] = cvtpk(a[2], a[3]);
    H.u[2] = cvtpk(b[0], b[1]); H.u[3] = cvtpk(b[2], b[3]);
    L.u[0] = cvtpk(a[0] - lo16f(H.u[0]), a[1] - hi16f(H.u[0]));
    L.u[1] = cvtpk(a[2] - lo16f(H.u[1]), a[3] - hi16f(H.u[1]));
    L.u[2] = cvtpk(b[0] - lo16f(H.u[2]), b[1] - hi16f(H.u[2]));
    L.u[3] = cvtpk(b[2] - lo16f(H.u[3]), b[3] - hi16f(H.u[3]));
    h = H.v; l = L.v;
}

// inter partials over this wave's feature half (ft = rt*4 + ktl), both row-tiles
static __device__ __forceinline__ void inter_half(const unsigned* __restrict__ qf_,
        const f32x4 (&S)[8], int rt, int l15, int g, int xsw,
        f32x4 &Cp0, f32x4 &Cp1)
{
#pragma unroll
    for (int ktl=0; ktl<4; ktl++){
        int ft = rt*4 + ktl;
        bf16x8 sh, sl; sfrag(S[2*ktl], S[2*ktl+1], sh, sl);
        {
            int rowb = l15*256;                 // row-tile 0
            uint4 q0 = *(const uint4*)&qf_[rowb + ((ft*32 + g*4) ^ xsw)];
            uint4 q1 = *(const uint4*)&qf_[rowb + ((ft*32 + 16 + g*4) ^ xsw)];
            bf16x8 qh, ql; unpk(q0, q1, qh, ql);
            Cp0 = MFMA16(qh, sh, Cp0);
            Cp0 = MFMA16(qh, sl, Cp0);
            Cp0 = MFMA16(ql, sh, Cp0);
        }
        {
            int rowb = (16 + l15)*256;          // row-tile 1
            uint4 q0 = *(const uint4*)&qf_[rowb + ((ft*32 + g*4) ^ xsw)];
            uint4 q1 = *(const uint4*)&qf_[rowb + ((ft*32 + 16 + g*4) ^ xsw)];
            bf16x8 qh, ql; unpk(q0, q1, qh, ql);
            Cp1 = MFMA16(qh, sh, Cp1);
            Cp1 = MFMA16(qh, sl, Cp1);
            Cp1 = MFMA16(ql, sh, Cp1);
        }
    }
}

// ---------------- init: P -> bf16 hi/lo (flat + frag-major) ----------------
__global__ __launch_bounds__(256) void init_p_kernel(const float* __restrict__ proj,
        unsigned short* __restrict__ Ph, unsigned short* __restrict__ Pl,
        unsigned short* __restrict__ Pfh, unsigned short* __restrict__ Pfl){
    int i = blockIdx.x*256 + threadIdx.x;   // 16384
    float x = proj[i];
    unsigned short h = f2bh(x);
    unsigned short l = f2bh(x - bh2f(h));
    Ph[i] = h;
    Pl[i] = l;
    // frag-major: i = m*64 + d
    int m = i >> 6, d = i & 63;
    int w = m >> 5, mt = (m >> 4) & 1, l15 = m & 15;
    int kk = d >> 5, r5 = d & 31;
    int half = r5 >> 4, g = (r5 & 15) >> 2, jj = r5 & 3;
    int f = w*4 + kk*2 + mt, lane = g*16 + l15, j = half*4 + jj;
    int o = (f*64 + lane)*8 + j;
    Pfh[o] = h; Pfl[o] = l;
}

// ---------------- kmax: global max of k's data_dash (hi-only is safe) ----------------
__global__ __launch_bounds__(256) void kmax_kernel(const float* __restrict__ k,
        const unsigned short* __restrict__ Ph, unsigned* __restrict__ kmax_u){
    __shared__ float red[4];
    int tid = threadIdx.x;
    int lane = tid & 63, w = tid >> 6;
    int l15 = lane & 15, g = lane >> 4;
    long r0 = (long)blockIdx.x * 32;
    bf16x8 xh[2][2];  // [kk][rt]
#pragma unroll
    for (int kk=0;kk<2;kk++)
#pragma unroll
      for (int rt=0;rt<2;rt++){
        const float* rp = k + (r0 + rt*16 + l15)*64 + kk*32 + g*4;
        float4 a = *(const float4*)rp;
        float4 b = *(const float4*)(rp + 16);
        float xs[8] = {a.x,a.y,a.z,a.w,b.x,b.y,b.z,b.w};
#pragma unroll
        for (int j=0;j<8;j++) xh[kk][rt][j] = (short)f2bh(xs[j]*DNORM);
      }
    float mx = -1e30f;
#pragma unroll
    for (int mtl=0; mtl<4; mtl++){
        int mtile = w*4 + mtl;
        bf16x8 pf[2];
#pragma unroll
        for (int kk=0;kk<2;kk++){
            const unsigned short* ph = Ph + (mtile*16 + l15)*64 + kk*32 + g*4;
#pragma unroll
            for (int j=0;j<4;j++){ pf[kk][j]=(short)ph[j]; pf[kk][4+j]=(short)ph[16+j]; }
        }
        f32x4 acc[2] = {f32x4{0.f,0.f,0.f,0.f}, f32x4{0.f,0.f,0.f,0.f}};
#pragma unroll
        for (int kk=0;kk<2;kk++)
#pragma unroll
          for (int rt=0;rt<2;rt++)
            acc[rt] = MFMA16(xh[kk][rt], pf[kk], acc[rt]);
#pragma unroll
        for (int rt=0;rt<2;rt++)
#pragma unroll
          for (int i=0;i<4;i++) mx = fmaxf(mx, acc[rt][i]);
    }
#pragma unroll
    for (int d=1; d<64; d<<=1) mx = fmaxf(mx, __shfl_xor(mx, d, 64));
    if (lane == 0) red[w] = mx;
    __syncthreads();
    if (tid == 0){
        float m2 = fmaxf(fmaxf(red[0],red[1]), fmaxf(red[2],red[3]));
        atomicMax(kmax_u, mapf(m2));
    }
}

// ---------------- B: per-chunk states S = Kf^T V, z = sum Kf ----------------
__global__ __launch_bounds__(512, 2) void b_kernel(const float* __restrict__ k,
        const float* __restrict__ v,
        const unsigned short* __restrict__ Ph, const unsigned short* __restrict__ Pl,
        const unsigned* __restrict__ kmax_u, float* __restrict__ states,
        unsigned* __restrict__ kfg, int CH, int nch){
    __shared__ short Xh[4][64][8], Xl[4][64][8];
    __shared__ unsigned kf_[256*32];     // [m][t] swizzled: m*32 + (t ^ ((m&7)<<2))
    __shared__ unsigned Vt_u[64][36];    // [e][t] packed hi/lo
    __shared__ float diagk_[32];
    int tid = threadIdx.x;
    int lane = tid & 63, w = tid >> 6;
    int l15 = lane & 15, g = lane >> 4;
    int cx = blockIdx.x, bh = blockIdx.y;
    int o = (cx == 0) ? 0 : CONDL + (cx-1)*CH;
    int nsub = ((cx == 0) ? CONDL : CH) >> 5;
    long rowbase = (long)bh * S_TOT + o;
    float kmax = unmapf(*kmax_u);
    int xsw = (l15 & 7) << 2;
    bf16x8 Pfh[2][2], Pfl[2][2];
    load_pfrags(Ph, Pl, w, l15, g, Pfh, Pfl);
    f32x4 Sacc[2][4];   // [mt][et]
#pragma unroll
    for (int mt=0;mt<2;mt++)
#pragma unroll
      for (int et=0;et<4;et++) Sacc[mt][et] = f32x4{0.f,0.f,0.f,0.f};
    float zacc[2] = {0.f, 0.f};

    for (int st = 0; st < nsub; st++){
        long r0 = rowbase + st*32;
        // P0: cooperative k conversion + diag + V staging
        conv_write(k, r0, tid, Xh, Xl, diagk_);
        {
            int t = tid >> 4, e4 = (tid & 15)*4;
            float4 v4 = *(const float4*)(v + (r0 + t)*64 + e4);
            Vt_u[e4+0][t] = packhl(v4.x);
            Vt_u[e4+1][t] = packhl(v4.y);
            Vt_u[e4+2][t] = packhl(v4.z);
            Vt_u[e4+3][t] = packhl(v4.w);
        }
        __syncthreads();
        // P1: dd + kf finalize (b128 swizzled stores)
        f32x4 dk[2][2];
        dd_frags(Xh, Xl, lane, Pfh, Pfl, dk);
        float zd0 = 0.f, zd1 = 0.f;
#pragma unroll
        for (int rr=0;rr<2;rr++){
            float dg0 = diagk_[rr*16 + g*4 + 0];
            float dg1 = diagk_[rr*16 + g*4 + 1];
            float dg2 = diagk_[rr*16 + g*4 + 2];
            float dg3 = diagk_[rr*16 + g*4 + 3];
#pragma unroll
            for (int mt=0;mt<2;mt++){
                float k0 = RATIO * (__expf(dk[rr][mt][0] - dg0 - kmax) + KEPS);
                float k1 = RATIO * (__expf(dk[rr][mt][1] - dg1 - kmax) + KEPS);
                float k2 = RATIO * (__expf(dk[rr][mt][2] - dg2 - kmax) + KEPS);
                float k3 = RATIO * (__expf(dk[rr][mt][3] - dg3 - kmax) + KEPS);
                if (mt == 0) zd0 += k0+k1+k2+k3; else zd1 += k0+k1+k2+k3;
                uint4 kw;
                kw.x = packhl(k0); kw.y = packhl(k1);
                kw.z = packhl(k2); kw.w = packhl(k3);
                int m = w*32 + mt*16 + l15;
                *(uint4*)&kf_[m*32 + ((rr*16 + g*4) ^ xsw)] = kw;
            }
        }
        zd0 += __shfl_xor(zd0, 16, 64); zd0 += __shfl_xor(zd0, 32, 64);
        zd1 += __shfl_xor(zd1, 16, 64); zd1 += __shfl_xor(zd1, 32, 64);
        zacc[0] += zd0; zacc[1] += zd1;
        __syncthreads();
        // P2: state delta MFMAs + kf tile persist (linear image copy)
        if (kfg != nullptr && cx > 0){
            long tix = (long)bh*124 + ((o - CONDL) >> 5) + st;
            unsigned* tb = kfg + tix*8192;
            int base = tid*16;
#pragma unroll
            for (int j=0;j<4;j++)
                *(uint4*)(tb + base + j*4) = *(const uint4*)&kf_[base + j*4];
        }
#pragma unroll
        for (int mt=0;mt<2;mt++){
            int m = (w*2 + mt)*16 + l15;
            uint4 kp0 = *(const uint4*)&kf_[m*32 + ((g*4) ^ xsw)];
            uint4 kp1 = *(const uint4*)&kf_[m*32 + ((16 + g*4) ^ xsw)];
            bf16x8 kh, kl; unpk(kp0, kp1, kh, kl);
#pragma unroll
            for (int et=0;et<4;et++){
                const uint4* vp0 = (const uint4*)&Vt_u[et*16 + l15][g*4];
                const uint4* vp1 = (const uint4*)&Vt_u[et*16 + l15][16 + g*4];
                bf16x8 vh, vl; unpk(*vp0, *vp1, vh, vl);
                Sacc[mt][et] = MFMA16(kh, vh, Sacc[mt][et]);
                Sacc[mt][et] = MFMA16(kh, vl, Sacc[mt][et]);
                Sacc[mt][et] = MFMA16(kl, vh, Sacc[mt][et]);
            }
        }
        __syncthreads();
    }
    // write state slot
    float* Sg = states + ((long)(bh*nch + cx)) * SLOT_F;
#pragma unroll
    for (int mt=0;mt<2;mt++)
#pragma unroll
      for (int et=0;et<4;et++)
#pragma unroll
        for (int i=0;i<4;i++)
            Sg[((w*2+mt)*16 + g*4 + i)*64 + et*16 + l15] = Sacc[mt][et][i];
    if (g == 0){
        Sg[16384 + w*32 + l15]      = zacc[0];
        Sg[16384 + w*32 + 16 + l15] = zacc[1];
    }
}

// ---------------- C: exclusive scan over chunk slots ----------------
__global__ __launch_bounds__(256) void scan_kernel(float* __restrict__ states, int nch){
    int idx = blockIdx.x*256 + threadIdx.x;
    if (idx >= SLOT_F) return;
    float* base = states + (long)blockIdx.y * nch * SLOT_F + idx;
    float prev = 0.f;
    for (int c = 0; c < nch; c++){
        float t = base[(long)c * SLOT_F];
        base[(long)c * SLOT_F] = prev;
        prev += t;
    }
}

// ---------------- D: outputs (kf from workspace when available) ----------------
__global__ __launch_bounds__(512, 1) void d_kernel(const float* __restrict__ q,
        const float* __restrict__ k, const float* __restrict__ v,
        const unsigned short* __restrict__ Pfh, const unsigned short* __restrict__ Pfl,
        const unsigned* __restrict__ kmax_u, const float* __restrict__ states,
        const unsigned* __restrict__ kfg,
        float* __restrict__ out, int CH, int nch){
    // LDS map (uints), total = 26,752 uints = 107,008 B (1 block/CU):
    //  [0,8192)      qf  [32][256]  row*256 + (m ^ ((row&7)<<2)), packed hi/lo
    //  [8192,16384)  kf  [256][32]  m*32 + (t ^ ((m&7)<<2)), packed hi/lo
    //  [16384,24576) kfT [32][256]  t*256 + (m ^ ((t&7)<<2))  (A-prod B-operand)
    //  [24576,26624) X frags (P0-P1/P2) / A[32][32] + xch (P4-P7)
    //  [26624,26656) den f32[32]
    //  [26656,26688) dgk f32[32]   (fallback path only)
    //  [26688,26720) dgq f32[32]   (dedicated -- kf head overlay removed)
    //  [26720,26752) rmax u32[32]
    __shared__ __attribute__((aligned(16))) unsigned lds_[26752];
    unsigned* qf_  = lds_;
    unsigned* kf_  = lds_ + 8192;
    unsigned* kfT_ = lds_ + 16384;
    unsigned* XA_  = lds_ + 24576;
    float*   den_ = (float*)(lds_ + 26624);
    float*   dgk_ = (float*)(lds_ + 26656);
    float*   dgq_ = (float*)(lds_ + 26688);
    unsigned* rmax_ = lds_ + 26720;
    unsigned* A_ = XA_;
    float*   xch_ = (float*)(XA_ + 1024);
    short (*Xh)[64][8] = (short (*)[64][8])XA_;
    short (*Xl)[64][8] = (short (*)[64][8])(XA_ + 1024);

    int tid = threadIdx.x;
    int lane = tid & 63, w = tid >> 6;
    int l15 = lane & 15, g = lane >> 4;
    int et = w & 3, rt = w >> 2;
    bool owner = (rt == 0);     // owners: A at P4, inter at P6, output rows 0..15
    int cx = blockIdx.x, bh = blockIdx.y;
    bool causal = (cx > 0);
    int o = causal ? (CONDL + (cx-1)*CH) : 0;
    int nsub = (causal ? CH : CONDL) >> 5;
    float epsv = causal ? AEPS : 0.f;
    int slot = causal ? cx : 1;
    const float* Sg = states + ((long)(bh*nch + slot)) * SLOT_F;
    long rowbase = (long)bh * S_TOT + o;
    float kmax = unmapf(*kmax_u);
    int xsw = (l15 & 7) << 2;   // row/m/t & 7 == l15 & 7 for all our frag rows
    bool use_kfg = (kfg != nullptr);

    // P-fragments in registers (coalesced frag-major load, once)
    bf16x8 Ph_r[2][2], Pl_r[2][2];
    load_pfrags_fm(Pfh, Pfl, w, lane, Ph_r, Pl_r);

    // split state -> registers: wave (rt,et) holds features rt*128..+127:
    f32x4 S[8];
#pragma unroll
    for (int Mtl=0; Mtl<8; Mtl++){
#pragma unroll
        for (int i=0;i<4;i++)
            S[Mtl][i] = Sg[((rt*8 + Mtl)*16 + g*4 + i)*64 + et*16 + l15];
    }
    float z0 = Sg[16384 + w*32 + l15];
    float z1 = Sg[16384 + w*32 + 16 + l15];

    // prefetch pointers (per-thread fixed offsets within a 32-row subtile)
    const float* qptr = q + rowbase*64 + (tid >> 4)*64 + (tid & 15)*4;
    const float* kptr = k + rowbase*64 + (tid >> 4)*64 + (tid & 15)*4;
    float4 qpre = *(const float4*)qptr;
    // kfg tile addressing (producer-pattern per-lane offsets)
    long tix0 = causal ? ((long)bh*124 + ((o - CONDL) >> 5)) : 0;

    for (int st = 0; st < nsub; st++){
        long r0 = rowbase + st*32;
        // ---- P0: k/kf prefetch issue; q conversion + init ----
        float4 kpre;
        uint4 kreg[2][2];
        if (causal){
            if (use_kfg){
                const unsigned* tb = kfg + (tix0 + st)*8192;
#pragma unroll
                for (int rr=0;rr<2;rr++)
#pragma unroll
                  for (int mt=0;mt<2;mt++){
                    int m = w*32 + mt*16 + l15;
                    kreg[rr][mt] = *(const uint4*)(tb + m*32 + ((rr*16 + g*4) ^ xsw));
                  }
            } else {
                kpre = *(const float4*)(kptr + st*2048);
            }
        }
        conv_store(qpre, tid, Xh, Xl, dgq_);
        if (tid < 32){ den_[tid] = 0.f; rmax_[tid] = 0u; }
        __syncthreads();                      // B1
        // ---- P1: dd_q + rowmax atomics ----
        f32x4 dq[2][2];
        dd_frags(Xh, Xl, lane, Ph_r, Pl_r, dq);
#pragma unroll
        for (int rr=0;rr<2;rr++)
#pragma unroll
          for (int i=0;i<4;i++){
            float mx = fmaxf(dq[rr][0][i], dq[rr][1][i]);
            mx = fmaxf(mx, __shfl_xor(mx, 1, 64));
            mx = fmaxf(mx, __shfl_xor(mx, 2, 64));
            mx = fmaxf(mx, __shfl_xor(mx, 4, 64));
            mx = fmaxf(mx, __shfl_xor(mx, 8, 64));
            if (l15 == 0) atomicMax(&rmax_[rr*16 + g*4 + i], mapf(mx));
          }
        __syncthreads();                      // B2
        // ---- P2: qf finalize + den(z) || kf writes (kfg) / k conv (fallback) ----
        {
#pragma unroll
            for (int rr=0;rr<2;rr++)
#pragma unroll
              for (int i=0;i<4;i++){
                int row = rr*16 + g*4 + i;
                float dgv = dgq_[row];
                float rm = unmapf(rmax_[row]);
                float s1p = 0.f, s2p = 0.f;
#pragma unroll
                for (int mt=0;mt<2;mt++){
                    float qv = RATIO * (__expf(dq[rr][mt][i] - dgv - rm) + KEPS);
                    s1p += qv;
                    s2p += qv * (mt ? z1 : z0);
                    int m = w*32 + mt*16 + l15;
                    qf_[row*256 + (m ^ ((row & 7) << 2))] = packhl(qv);
                }
#pragma unroll
                for (int d2=1; d2<16; d2<<=1){
                    s1p += __shfl_xor(s1p, d2, 64);
                    s2p += __shfl_xor(s2p, d2, 64);
                }
                if (l15 == 0) atomicAdd(&den_[row], s2p + epsv * s1p);
              }
        }
        if (causal){
            if (use_kfg){
                float zd0 = 0.f, zd1 = 0.f;
#pragma unroll
                for (int rr=0;rr<2;rr++)
#pragma unroll
                  for (int mt=0;mt<2;mt++){
                    uint4 kw = kreg[rr][mt];
                    int m = w*32 + mt*16 + l15;
                    *(uint4*)&kf_[m*32 + ((rr*16 + g*4) ^ xsw)] = kw;
                    int t0r = rr*16 + g*4;
                    kfT_[(t0r+0)*256 + (m ^ ((((g*4)+0) & 7) << 2))] = kw.x;
                    kfT_[(t0r+1)*256 + (m ^ ((((g*4)+1) & 7) << 2))] = kw.y;
                    kfT_[(t0r+2)*256 + (m ^ ((((g*4)+2) & 7) << 2))] = kw.z;
                    kfT_[(t0r+3)*256 + (m ^ ((((g*4)+3) & 7) << 2))] = kw.w;
                    float s = unpackhl(kw.x) + unpackhl(kw.y)
                            + unpackhl(kw.z) + unpackhl(kw.w);
                    if (mt == 0) zd0 += s; else zd1 += s;
                  }
                zd0 += __shfl_xor(zd0, 16, 64); zd0 += __shfl_xor(zd0, 32, 64);
                zd1 += __shfl_xor(zd1, 16, 64); zd1 += __shfl_xor(zd1, 32, 64);
                z0 += zd0; z1 += zd1;
            } else {
                conv_store(kpre, tid, Xh, Xl, dgk_);
            }
        }
        __syncthreads();                      // B3
        // ---- P3 (fallback only): dd_k + kf/kfT finalize + z update ----
        if (!use_kfg){
            if (causal){
                f32x4 dk[2][2];
                dd_frags(Xh, Xl, lane, Ph_r, Pl_r, dk);
                float zd0 = 0.f, zd1 = 0.f;
#pragma unroll
                for (int rr=0;rr<2;rr++){
                    float dg0 = dgk_[rr*16 + g*4 + 0];
                    float dg1 = dgk_[rr*16 + g*4 + 1];
                    float dg2 = dgk_[rr*16 + g*4 + 2];
                    float dg3 = dgk_[rr*16 + g*4 + 3];
#pragma unroll
                    for (int mt=0;mt<2;mt++){
                        float k0 = RATIO * (__expf(dk[rr][mt][0] - dg0 - kmax) + KEPS);
                        float k1 = RATIO * (__expf(dk[rr][mt][1] - dg1 - kmax) + KEPS);
                        float k2 = RATIO * (__expf(dk[rr][mt][2] - dg2 - kmax) + KEPS);
                        float k3 = RATIO * (__expf(dk[rr][mt][3] - dg3 - kmax) + KEPS);
                        if (mt == 0) zd0 += k0+k1+k2+k3; else zd1 += k0+k1+k2+k3;
                        uint4 kw;
                        kw.x = packhl(k0); kw.y = packhl(k1);
                        kw.z = packhl(k2); kw.w = packhl(k3);
                        int m = w*32 + mt*16 + l15;
                        *(uint4*)&kf_[m*32 + ((rr*16 + g*4) ^ xsw)] = kw;
                        int t0r = rr*16 + g*4;
                        kfT_[(t0r+0)*256 + (m ^ ((((g*4)+0) & 7) << 2))] = kw.x;
                        kfT_[(t0r+1)*256 + (m ^ ((((g*4)+1) & 7) << 2))] = kw.y;
                        kfT_[(t0r+2)*256 + (m ^ ((((g*4)+2) & 7) << 2))] = kw.z;
                        kfT_[(t0r+3)*256 + (m ^ ((((g*4)+3) & 7) << 2))] = kw.w;
                    }
                }
                zd0 += __shfl_xor(zd0, 16, 64); zd0 += __shfl_xor(zd0, 32, 64);
                zd1 += __shfl_xor(zd1, 16, 64); zd1 += __shfl_xor(zd1, 32, 64);
                z0 += zd0; z1 += zd1;
            }
            __syncthreads();                  // B3b
        }
        // ---- P4: q prefetch (st+1); owners: A-product; rt=1: inter + slot ----
        if (st + 1 < nsub) qpre = *(const float4*)(qptr + (st+1)*2048);
        float vv[8];
        if (causal){
            const float* vb = v + r0*64 + et*16 + l15;
#pragma unroll
            for (int p2=0;p2<2;p2++)
#pragma unroll
              for (int j=0;j<4;j++)
                vv[p2*4+j] = vb[(p2*16 + g*4 + j)*64];
        }
        f32x4 Cp0{0.f,0.f,0.f,0.f}, Cp1{0.f,0.f,0.f,0.f};
        if (owner){
            if (causal){
                int ar = et >> 1, tt = et & 1;
                int t = tt*16 + l15;
                int tb2 = t*256;
                f32x4 c{0.f,0.f,0.f,0.f};
                int rowb = (ar*16 + l15)*256;
                __builtin_amdgcn_s_setprio(1);
#pragma unroll
                for (int kt=0;kt<8;kt++){
                    uint4 q0 = *(const uint4*)&qf_[rowb + ((kt*32 + g*4) ^ xsw)];
                    uint4 q1 = *(const uint4*)&qf_[rowb + ((kt*32 + 16 + g*4) ^ xsw)];
                    bf16x8 qh, ql; unpk(q0, q1, qh, ql);
                    uint4 kt0 = *(const uint4*)&kfT_[tb2 + ((kt*32 + g*4) ^ xsw)];
                    uint4 kt1 = *(const uint4*)&kfT_[tb2 + ((kt*32 + 16 + g*4) ^ xsw)];
                    bf16x8 kh, kl; unpk(kt0, kt1, kh, kl);
                    c = MFMA16(qh, kh, c);
                    c = MFMA16(qh, kl, c);
                    c = MFMA16(ql, kh, c);
                }
                __builtin_amdgcn_s_setprio(0);
#pragma unroll
                for (int i=0;i<4;i++){
                    int r = ar*16 + g*4 + i;
                    float a = (t <= r) ? c[i] : 0.f;
                    A_[r*32 + (t ^ ((r & 7) << 2))] = packhl(a);
                    float p = a;
                    p += __shfl_xor(p, 1, 64);
                    p += __shfl_xor(p, 2, 64);
                    p += __shfl_xor(p, 4, 64);
                    p += __shfl_xor(p, 8, 64);
                    if (l15 == 0) atomicAdd(&den_[r], p);
                }
            }
        } else {
            __builtin_amdgcn_s_setprio(1);
            inter_half(qf_, S, rt, l15, g, xsw, Cp0, Cp1);
            __builtin_amdgcn_s_setprio(0);
            *(float4*)&xch_[(et*64 + lane)*4] = float4{Cp0[0],Cp0[1],Cp0[2],Cp0[3]};
        }
        __syncthreads();                      // B5
        // ---- P6: owners: inter + partner-add + slot write; all: delta + intra ----
        if (owner){
            __builtin_amdgcn_s_setprio(1);
            inter_half(qf_, S, rt, l15, g, xsw, Cp0, Cp1);
            __builtin_amdgcn_s_setprio(0);
            float4 pp = *(const float4*)&xch_[(et*64 + lane)*4];
            Cp0[0] += pp.x; Cp0[1] += pp.y; Cp0[2] += pp.z; Cp0[3] += pp.w;
            *(float4*)&xch_[(et*64 + lane)*4] = float4{Cp1[0],Cp1[1],Cp1[2],Cp1[3]};
        }
        if (causal){
            f32x4 va{vv[0], vv[1], vv[2], vv[3]};
            f32x4 vb2{vv[4], vv[5], vv[6], vv[7]};
            bf16x8 vh, vl; sfrag(va, vb2, vh, vl);
            __builtin_amdgcn_s_setprio(1);
#pragma unroll
            for (int Mtl=0;Mtl<8;Mtl++){
                int mb = ((rt*8 + Mtl)*16 + l15)*32;
                uint4 k0 = *(const uint4*)&kf_[mb + ((g*4) ^ xsw)];
                uint4 k1 = *(const uint4*)&kf_[mb + ((16 + g*4) ^ xsw)];
                bf16x8 kh, kl; unpk(k0, k1, kh, kl);
                S[Mtl] = MFMA16(kh, vh, S[Mtl]);
                S[Mtl] = MFMA16(kh, vl, S[Mtl]);
                S[Mtl] = MFMA16(kl, vh, S[Mtl]);
            }
            __builtin_amdgcn_s_setprio(0);
            int rb = (rt*16 + l15)*32;
            uint4 a0 = *(const uint4*)&A_[rb + ((g*4) ^ xsw)];
            uint4 a1 = *(const uint4*)&A_[rb + ((16 + g*4) ^ xsw)];
            bf16x8 ah, al; unpk(a0, a1, ah, al);
            f32x4& Ct = owner ? Cp0 : Cp1;
            Ct = MFMA16(ah, vh, Ct);
            Ct = MFMA16(ah, vl, Ct);
            Ct = MFMA16(al, vh, Ct);
        }
        if (owner){
#pragma unroll
            for (int i=0;i<4;i++){
                int row = g*4 + i;
                out[(r0 + row)*64 + et*16 + l15] = Cp0[i] / den_[row];
            }
        }
        __syncthreads();                      // B6
        // ---- P7: rt=1 waves: partner-add + output rows 16..31 ----
        if (!owner){
            float4 pp = *(const float4*)&xch_[(et*64 + lane)*4];
            Cp1[0] += pp.x; Cp1[1] += pp.y; Cp1[2] += pp.z; Cp1[3] += pp.w;
#pragma unroll
            for (int i=0;i<4;i++){
                int row = 16 + g*4 + i;
                out[(r0 + row)*64 + et*16 + l15] = Cp1[i] / den_[row];
            }
        }
        __syncthreads();                      // B7 (end)
    }
}

extern "C" void kernel_launch(void* const* d_in, const int* in_sizes, int n_in,
                              void* d_out, int out_size, void* d_ws, size_t ws_size,
                              hipStream_t stream) {
    const float* q = (const float*)d_in[0];
    const float* k = (const float*)d_in[1];
    const float* v = (const float*)d_in[2];
    const float* proj = (const float*)d_in[3];
    float* out = (float*)d_out;

    unsigned* kmax_u = (unsigned*)d_ws;
    unsigned short* Ph  = (unsigned short*)((char*)d_ws + 256);
    unsigned short* Pl  = Ph + 16384;
    unsigned short* Pfh = Pl + 16384;
    unsigned short* Pfl = Pfh + 16384;
    float* states = (float*)((char*)d_ws + 256 + 131072);
    size_t fixed = 256 + 131072;

    int CH, nch;
    size_t need128 = fixed + (size_t)64 * 32 * SLOT_F * 4;
    if (ws_size >= need128){ CH = 128; nch = 32; }
    else                  { CH = 992; nch = 5;  }

    // optional kf persistence region: 64 bh x 124 tiles x 8192 u32
    unsigned* kfg = nullptr;
    if (CH == 128){
        size_t states_bytes = (size_t)64 * nch * SLOT_F * 4;
        size_t kfg_off = fixed + states_bytes;
        size_t kfg_bytes = (size_t)64 * 124 * 8192 * 4;
        if (ws_size >= kfg_off + kfg_bytes)
            kfg = (unsigned*)((char*)d_ws + kfg_off);
    }

    hipMemsetAsync(d_ws, 0, 4, stream);
    hipLaunchKernelGGL(init_p_kernel, dim3(64), dim3(256), 0, stream, proj, Ph, Pl, Pfh, Pfl);
    hipLaunchKernelGGL(kmax_kernel, dim3(8192), dim3(256), 0, stream, k, Ph, kmax_u);
    hipLaunchKernelGGL(b_kernel, dim3(nch, 64), dim3(512), 0, stream, k, v, Ph, Pl, kmax_u, states, kfg, CH, nch);
    hipLaunchKernelGGL(scan_kernel, dim3(65, 64), dim3(256), 0, stream, states, nch);
    hipLaunchKernelGGL(d_kernel, dim3(nch, 64), dim3(512), 0, stream, q, k, v, Pfh, Pfl, kmax_u, states, kfg, out, CH, nch);
}

// Round 11
// 638.886 us; speedup vs baseline: 1.3543x; 1.3543x over previous
//
#include <hip/hip_runtime.h>
#include <math.h>

// Performer FAVOR+ causal linear attention, MI355X.
// B=4 H=16 S=4096 D=64 M=256 features, COND=128 non-causal prefix.
// v12 = exact revert to v10 (session best, 636.8us total / d=377.9us):
// v7 d_kernel (kfT tile, P-frag registers, q/k prefetch, 7-barrier schedule)
// + v9 b_kernel (b128 swizzled kf stores) + T5 setprio on role-split phases.
// v11's kf-persistence regressed (d 377->613): producer-pattern kfg loads are
// a 128B-stride gather (64 transactions/instr) and at 2 waves/SIMD that
// latency is unhideable. v8 (phase merge) spilled; v9 (deferred P7) grew the
// carried dep chain. d_kernel is latency-bound at a register-pinned
// 2 waves/SIMD (128 arch + 64 acc); further gains need a 4-wave re-partition.
// ws: [0..4) kmax (mapped uint), [256..) Ph bf16[256][64], Pl bf16[256][64],
//     Pfm_h/Pfm_l frag-major bf16 planes (32KB each),
//     then chunk states [64][nslot][256*64 + 256] f32.

#define S_TOT 4096
#define CONDL 128
#define SLOT_F 16640
#define RATIO 0.0625f
#define DNORM 0.35355339059327378f
#define KEPS  1e-4f
#define AEPS  1e-6f

typedef __attribute__((ext_vector_type(8))) short bf16x8;
typedef __attribute__((ext_vector_type(2))) unsigned uint2v;
typedef __attribute__((ext_vector_type(4))) float f32x4;

#define MFMA16(a,b,c) __builtin_amdgcn_mfma_f32_16x16x32_bf16(a,b,c,0,0,0)

static __device__ __forceinline__ unsigned cvtpk(float a, float b){
    unsigned r;
    asm("v_cvt_pk_bf16_f32 %0, %1, %2" : "=v"(r) : "v"(a), "v"(b));
    return r;
}
static __device__ __forceinline__ float lo16f(unsigned u){ return __uint_as_float(u << 16); }
static __device__ __forceinline__ float hi16f(unsigned u){ return __uint_as_float(u & 0xffff0000u); }

static __device__ __forceinline__ unsigned short f2bh(float x){
    unsigned u = __float_as_uint(x);
    u += 0x7fffu + ((u >> 16) & 1u);
    return (unsigned short)(u >> 16);
}
static __device__ __forceinline__ float bh2f(unsigned short h){
    return __uint_as_float((unsigned)h << 16);
}
// pack hi/lo bf16 of x into one dword (hi in low16, residual-lo in high16)
static __device__ __forceinline__ unsigned packhl(float x){
    unsigned u1 = cvtpk(x, x);
    float r = x - lo16f(u1);
    return cvtpk(x, r);
}
// two uint4 (halves k=[0..15],[16..31] of this lane's 4+4 elems) -> hi/lo frags
static __device__ __forceinline__ void unpk(const uint4 a, const uint4 b, bf16x8& h, bf16x8& l){
    h[0]=(short)a.x; h[1]=(short)a.y; h[2]=(short)a.z; h[3]=(short)a.w;
    h[4]=(short)b.x; h[5]=(short)b.y; h[6]=(short)b.z; h[7]=(short)b.w;
    l[0]=(short)(a.x>>16); l[1]=(short)(a.y>>16); l[2]=(short)(a.z>>16); l[3]=(short)(a.w>>16);
    l[4]=(short)(b.x>>16); l[5]=(short)(b.y>>16); l[6]=(short)(b.z>>16); l[7]=(short)(b.w>>16);
}
static __device__ __forceinline__ unsigned mapf(float x){
    unsigned u = __float_as_uint(x);
    return (u & 0x80000000u) ? ~u : (u | 0x80000000u);
}
static __device__ __forceinline__ float unmapf(unsigned u){
    return __uint_as_float((u & 0x80000000u) ? (u ^ 0x80000000u) : ~u);
}

// Convert a pre-loaded 32x64 f32 tile row-quad into frag-major hi/lo bf16
// planes + row diag (cooperative across 512 threads).
static __device__ __forceinline__ void conv_store(float4 x4, int tid,
        short (*Xh)[64][8], short (*Xl)[64][8], float* __restrict__ diag_)
{
    int row = tid >> 4;
    int c4  = (tid & 15) * 4;
    float x0 = x4.x*DNORM, x1 = x4.y*DNORM, x2 = x4.z*DNORM, x3 = x4.w*DNORM;
    float ss = x0*x0 + x1*x1 + x2*x2 + x3*x3;
    ss += __shfl_xor(ss, 1, 64);
    ss += __shfl_xor(ss, 2, 64);
    ss += __shfl_xor(ss, 4, 64);
    ss += __shfl_xor(ss, 8, 64);
    if ((tid & 15) == 0) diag_[row] = 0.5f * ss;
    int rt = row >> 4, lr = row & 15;
    int kk = c4 >> 5, c5 = c4 & 31;
    int fg, j0;
    if (c5 < 16){ fg = c5 >> 2; j0 = 0; } else { fg = (c5 - 16) >> 2; j0 = 4; }
    int f = kk*2 + rt;
    unsigned a01 = cvtpk(x0, x1), a23 = cvtpk(x2, x3);
    unsigned b01 = cvtpk(x0 - lo16f(a01), x1 - hi16f(a01));
    unsigned b23 = cvtpk(x2 - lo16f(a23), x3 - hi16f(a23));
    uint2v hv, lv;
    hv[0] = a01; hv[1] = a23;
    lv[0] = b01; lv[1] = b23;
    *(uint2v*)&Xh[f][fg*16 + lr][j0] = hv;
    *(uint2v*)&Xl[f][fg*16 + lr][j0] = lv;
}

static __device__ __forceinline__ void conv_write(const float* __restrict__ Xg, long r0,
        int tid, short (*Xh)[64][8], short (*Xl)[64][8], float* __restrict__ diag_)
{
    int row = tid >> 4;
    int c4  = (tid & 15) * 4;
    float4 x4 = *(const float4*)(Xg + (r0 + row)*64 + c4);
    conv_store(x4, tid, Xh, Xl, diag_);
}

// ---- old-style P fragment load (Ph/Pl flat [m][d]) -- used by b_kernel ----
static __device__ __forceinline__ void load_pfrags(const unsigned short* __restrict__ Ph,
        const unsigned short* __restrict__ Pl, int w, int l15, int g,
        bf16x8 (&Pfh)[2][2], bf16x8 (&Pfl)[2][2])
{
#pragma unroll
    for (int mt=0; mt<2; mt++)
#pragma unroll
      for (int kk=0; kk<2; kk++){
        const unsigned short* ph = Ph + (w*32 + mt*16 + l15)*64 + kk*32 + g*4;
        const unsigned short* pl = Pl + (w*32 + mt*16 + l15)*64 + kk*32 + g*4;
        bf16x8 fh, fl;
#pragma unroll
        for (int j=0;j<4;j++){
            fh[j]=(short)ph[j]; fh[4+j]=(short)ph[16+j];
            fl[j]=(short)pl[j]; fl[4+j]=(short)pl[16+j];
        }
        Pfh[mt][kk]=fh; Pfl[mt][kk]=fl;
      }
}

// frag-major P load (coalesced b128) -- used by d_kernel, held in registers
static __device__ __forceinline__ void load_pfrags_fm(const unsigned short* __restrict__ Pfh,
        const unsigned short* __restrict__ Pfl, int w, int lane,
        bf16x8 (&Ph_r)[2][2], bf16x8 (&Pl_r)[2][2])
{
#pragma unroll
    for (int kk=0; kk<2; kk++)
#pragma unroll
      for (int mt=0; mt<2; mt++){
        int f = w*4 + kk*2 + mt;
        Ph_r[mt][kk] = *(const bf16x8*)(Pfh + (f*64 + lane)*8);
        Pl_r[mt][kk] = *(const bf16x8*)(Pfl + (f*64 + lane)*8);
      }
}

// dd GEMM from shared frags, register P-frags
static __device__ __forceinline__ void dd_frags(const short (*Xh)[64][8], const short (*Xl)[64][8],
        int lane, const bf16x8 (&Pfh)[2][2], const bf16x8 (&Pfl)[2][2], f32x4 (&acc)[2][2])
{
#pragma unroll
    for (int rt=0;rt<2;rt++)
#pragma unroll
      for (int mt=0;mt<2;mt++) acc[rt][mt] = f32x4{0.f,0.f,0.f,0.f};
#pragma unroll
    for (int kk=0;kk<2;kk++)
#pragma unroll
      for (int rt=0;rt<2;rt++){
        bf16x8 xh = *(const bf16x8*)&Xh[kk*2+rt][lane][0];
        bf16x8 xl = *(const bf16x8*)&Xl[kk*2+rt][lane][0];
#pragma unroll
        for (int mt=0;mt<2;mt++){
            acc[rt][mt] = MFMA16(xh, Pfh[mt][kk], acc[rt][mt]);
            acc[rt][mt] = MFMA16(xh, Pfl[mt][kk], acc[rt][mt]);
            acc[rt][mt] = MFMA16(xl, Pfh[mt][kk], acc[rt][mt]);
        }
      }
}

// build hi/lo bf16 B-frag for one kt directly from f32 values (C-layout regs)
static __device__ __forceinline__ void sfrag(const f32x4 a, const f32x4 b, bf16x8& h, bf16x8& l){
    union U { bf16x8 v; unsigned u[4]; } H, L;
    H.u[0] = cvtpk(a[0], a[1]); H.u[1] = cvtpk(a[2], a[3]);
    H.u[2] = cvtpk(b[0], b[1]); H.u[3] = cvtpk(b[2], b[3]);
    L.u[0] = cvtpk(a[0] - lo16f(H.u[0]), a[1] - hi16f(H.u[0]));
    L.u[1] = cvtpk(a[2] - lo16f(H.u[1]), a[3] - hi16f(H.u[1]));
    L.u[2] = cvtpk(b[0] - lo16f(H.u[2]), b[1] - hi16f(H.u[2]));
    L.u[3] = cvtpk(b[2] - lo16f(H.u[3]), b[3] - hi16f(H.u[3]));
    h = H.v; l = L.v;
}

// inter partials over this wave's feature half (ft = rt*4 + ktl), both row-tiles
static __device__ __forceinline__ void inter_half(const unsigned* __restrict__ qf_,
        const f32x4 (&S)[8], int rt, int l15, int g, int xsw,
        f32x4 &Cp0, f32x4 &Cp1)
{
#pragma unroll
    for (int ktl=0; ktl<4; ktl++){
        int ft = rt*4 + ktl;
        bf16x8 sh, sl; sfrag(S[2*ktl], S[2*ktl+1], sh, sl);
        {
            int rowb = l15*256;                 // row-tile 0
            uint4 q0 = *(const uint4*)&qf_[rowb + ((ft*32 + g*4) ^ xsw)];
            uint4 q1 = *(const uint4*)&qf_[rowb + ((ft*32 + 16 + g*4) ^ xsw)];
            bf16x8 qh, ql; unpk(q0, q1, qh, ql);
            Cp0 = MFMA16(qh, sh, Cp0);
            Cp0 = MFMA16(qh, sl, Cp0);
            Cp0 = MFMA16(ql, sh, Cp0);
        }
        {
            int rowb = (16 + l15)*256;          // row-tile 1
            uint4 q0 = *(const uint4*)&qf_[rowb + ((ft*32 + g*4) ^ xsw)];
            uint4 q1 = *(const uint4*)&qf_[rowb + ((ft*32 + 16 + g*4) ^ xsw)];
            bf16x8 qh, ql; unpk(q0, q1, qh, ql);
            Cp1 = MFMA16(qh, sh, Cp1);
            Cp1 = MFMA16(qh, sl, Cp1);
            Cp1 = MFMA16(ql, sh, Cp1);
        }
    }
}

// ---------------- init: P -> bf16 hi/lo (flat + frag-major) ----------------
__global__ __launch_bounds__(256) void init_p_kernel(const float* __restrict__ proj,
        unsigned short* __restrict__ Ph, unsigned short* __restrict__ Pl,
        unsigned short* __restrict__ Pfh, unsigned short* __restrict__ Pfl){
    int i = blockIdx.x*256 + threadIdx.x;   // 16384
    float x = proj[i];
    unsigned short h = f2bh(x);
    unsigned short l = f2bh(x - bh2f(h));
    Ph[i] = h;
    Pl[i] = l;
    // frag-major: i = m*64 + d
    int m = i >> 6, d = i & 63;
    int w = m >> 5, mt = (m >> 4) & 1, l15 = m & 15;
    int kk = d >> 5, r5 = d & 31;
    int half = r5 >> 4, g = (r5 & 15) >> 2, jj = r5 & 3;
    int f = w*4 + kk*2 + mt, lane = g*16 + l15, j = half*4 + jj;
    int o = (f*64 + lane)*8 + j;
    Pfh[o] = h; Pfl[o] = l;
}

// ---------------- kmax: global max of k's data_dash (hi-only is safe) ----------------
__global__ __launch_bounds__(256) void kmax_kernel(const float* __restrict__ k,
        const unsigned short* __restrict__ Ph, unsigned* __restrict__ kmax_u){
    __shared__ float red[4];
    int tid = threadIdx.x;
    int lane = tid & 63, w = tid >> 6;
    int l15 = lane & 15, g = lane >> 4;
    long r0 = (long)blockIdx.x * 32;
    bf16x8 xh[2][2];  // [kk][rt]
#pragma unroll
    for (int kk=0;kk<2;kk++)
#pragma unroll
      for (int rt=0;rt<2;rt++){
        const float* rp = k + (r0 + rt*16 + l15)*64 + kk*32 + g*4;
        float4 a = *(const float4*)rp;
        float4 b = *(const float4*)(rp + 16);
        float xs[8] = {a.x,a.y,a.z,a.w,b.x,b.y,b.z,b.w};
#pragma unroll
        for (int j=0;j<8;j++) xh[kk][rt][j] = (short)f2bh(xs[j]*DNORM);
      }
    float mx = -1e30f;
#pragma unroll
    for (int mtl=0; mtl<4; mtl++){
        int mtile = w*4 + mtl;
        bf16x8 pf[2];
#pragma unroll
        for (int kk=0;kk<2;kk++){
            const unsigned short* ph = Ph + (mtile*16 + l15)*64 + kk*32 + g*4;
#pragma unroll
            for (int j=0;j<4;j++){ pf[kk][j]=(short)ph[j]; pf[kk][4+j]=(short)ph[16+j]; }
        }
        f32x4 acc[2] = {f32x4{0.f,0.f,0.f,0.f}, f32x4{0.f,0.f,0.f,0.f}};
#pragma unroll
        for (int kk=0;kk<2;kk++)
#pragma unroll
          for (int rt=0;rt<2;rt++)
            acc[rt] = MFMA16(xh[kk][rt], pf[kk], acc[rt]);
#pragma unroll
        for (int rt=0;rt<2;rt++)
#pragma unroll
          for (int i=0;i<4;i++) mx = fmaxf(mx, acc[rt][i]);
    }
#pragma unroll
    for (int d=1; d<64; d<<=1) mx = fmaxf(mx, __shfl_xor(mx, d, 64));
    if (lane == 0) red[w] = mx;
    __syncthreads();
    if (tid == 0){
        float m2 = fmaxf(fmaxf(red[0],red[1]), fmaxf(red[2],red[3]));
        atomicMax(kmax_u, mapf(m2));
    }
}

// ---------------- B: per-chunk states S = Kf^T V, z = sum Kf ----------------
__global__ __launch_bounds__(512, 2) void b_kernel(const float* __restrict__ k,
        const float* __restrict__ v,
        const unsigned short* __restrict__ Ph, const unsigned short* __restrict__ Pl,
        const unsigned* __restrict__ kmax_u, float* __restrict__ states,
        int CH, int nch){
    __shared__ short Xh[4][64][8], Xl[4][64][8];
    __shared__ unsigned kf_[256*32];     // [m][t] swizzled: m*32 + (t ^ ((m&7)<<2))
    __shared__ unsigned Vt_u[64][36];    // [e][t] packed hi/lo
    __shared__ float diagk_[32];
    int tid = threadIdx.x;
    int lane = tid & 63, w = tid >> 6;
    int l15 = lane & 15, g = lane >> 4;
    int cx = blockIdx.x, bh = blockIdx.y;
    int o = (cx == 0) ? 0 : CONDL + (cx-1)*CH;
    int nsub = ((cx == 0) ? CONDL : CH) >> 5;
    long rowbase = (long)bh * S_TOT + o;
    float kmax = unmapf(*kmax_u);
    int xsw = (l15 & 7) << 2;
    bf16x8 Pfh[2][2], Pfl[2][2];
    load_pfrags(Ph, Pl, w, l15, g, Pfh, Pfl);
    f32x4 Sacc[2][4];   // [mt][et]
#pragma unroll
    for (int mt=0;mt<2;mt++)
#pragma unroll
      for (int et=0;et<4;et++) Sacc[mt][et] = f32x4{0.f,0.f,0.f,0.f};
    float zacc[2] = {0.f, 0.f};

    for (int st = 0; st < nsub; st++){
        long r0 = rowbase + st*32;
        // P0: cooperative k conversion + diag + V staging
        conv_write(k, r0, tid, Xh, Xl, diagk_);
        {
            int t = tid >> 4, e4 = (tid & 15)*4;
            float4 v4 = *(const float4*)(v + (r0 + t)*64 + e4);
            Vt_u[e4+0][t] = packhl(v4.x);
            Vt_u[e4+1][t] = packhl(v4.y);
            Vt_u[e4+2][t] = packhl(v4.z);
            Vt_u[e4+3][t] = packhl(v4.w);
        }
        __syncthreads();
        // P1: dd + kf finalize (b128 swizzled stores, v5 pattern)
        f32x4 dk[2][2];
        dd_frags(Xh, Xl, lane, Pfh, Pfl, dk);
        float zd0 = 0.f, zd1 = 0.f;
#pragma unroll
        for (int rr=0;rr<2;rr++){
            float dg0 = diagk_[rr*16 + g*4 + 0];
            float dg1 = diagk_[rr*16 + g*4 + 1];
            float dg2 = diagk_[rr*16 + g*4 + 2];
            float dg3 = diagk_[rr*16 + g*4 + 3];
#pragma unroll
            for (int mt=0;mt<2;mt++){
                float k0 = RATIO * (__expf(dk[rr][mt][0] - dg0 - kmax) + KEPS);
                float k1 = RATIO * (__expf(dk[rr][mt][1] - dg1 - kmax) + KEPS);
                float k2 = RATIO * (__expf(dk[rr][mt][2] - dg2 - kmax) + KEPS);
                float k3 = RATIO * (__expf(dk[rr][mt][3] - dg3 - kmax) + KEPS);
                if (mt == 0) zd0 += k0+k1+k2+k3; else zd1 += k0+k1+k2+k3;
                uint4 kw;
                kw.x = packhl(k0); kw.y = packhl(k1);
                kw.z = packhl(k2); kw.w = packhl(k3);
                int m = w*32 + mt*16 + l15;
                *(uint4*)&kf_[m*32 + ((rr*16 + g*4) ^ xsw)] = kw;
            }
        }
        zd0 += __shfl_xor(zd0, 16, 64); zd0 += __shfl_xor(zd0, 32, 64);
        zd1 += __shfl_xor(zd1, 16, 64); zd1 += __shfl_xor(zd1, 32, 64);
        zacc[0] += zd0; zacc[1] += zd1;
        __syncthreads();
        // P2: state delta MFMAs
#pragma unroll
        for (int mt=0;mt<2;mt++){
            int m = (w*2 + mt)*16 + l15;
            uint4 kp0 = *(const uint4*)&kf_[m*32 + ((g*4) ^ xsw)];
            uint4 kp1 = *(const uint4*)&kf_[m*32 + ((16 + g*4) ^ xsw)];
            bf16x8 kh, kl; unpk(kp0, kp1, kh, kl);
#pragma unroll
            for (int et=0;et<4;et++){
                const uint4* vp0 = (const uint4*)&Vt_u[et*16 + l15][g*4];
                const uint4* vp1 = (const uint4*)&Vt_u[et*16 + l15][16 + g*4];
                bf16x8 vh, vl; unpk(*vp0, *vp1, vh, vl);
                Sacc[mt][et] = MFMA16(kh, vh, Sacc[mt][et]);
                Sacc[mt][et] = MFMA16(kh, vl, Sacc[mt][et]);
                Sacc[mt][et] = MFMA16(kl, vh, Sacc[mt][et]);
            }
        }
        __syncthreads();
    }
    // write state slot
    float* Sg = states + ((long)(bh*nch + cx)) * SLOT_F;
#pragma unroll
    for (int mt=0;mt<2;mt++)
#pragma unroll
      for (int et=0;et<4;et++)
#pragma unroll
        for (int i=0;i<4;i++)
            Sg[((w*2+mt)*16 + g*4 + i)*64 + et*16 + l15] = Sacc[mt][et][i];
    if (g == 0){
        Sg[16384 + w*32 + l15]      = zacc[0];
        Sg[16384 + w*32 + 16 + l15] = zacc[1];
    }
}

// ---------------- C: exclusive scan over chunk slots ----------------
__global__ __launch_bounds__(256) void scan_kernel(float* __restrict__ states, int nch){
    int idx = blockIdx.x*256 + threadIdx.x;
    if (idx >= SLOT_F) return;
    float* base = states + (long)blockIdx.y * nch * SLOT_F + idx;
    float prev = 0.f;
    for (int c = 0; c < nch; c++){
        float t = base[(long)c * SLOT_F];
        base[(long)c * SLOT_F] = prev;
        prev += t;
    }
}

// ---------------- D: outputs (split reg state, kfT tile, 106.75KB LDS) ----------------
__global__ __launch_bounds__(512, 1) void d_kernel(const float* __restrict__ q,
        const float* __restrict__ k, const float* __restrict__ v,
        const unsigned short* __restrict__ Pfh, const unsigned short* __restrict__ Pfl,
        const unsigned* __restrict__ kmax_u, const float* __restrict__ states,
        float* __restrict__ out, int CH, int nch){
    // LDS map (uints), total = 26,688 uints = 106,752 B (1 block/CU):
    //  [0,8192)      qf  [32][256]  row*256 + (m ^ ((row&7)<<2)), packed hi/lo
    //  [8192,16384)  kf  [256][32]  m*32 + (t ^ ((m&7)<<2)), packed hi/lo
    //                  head overlay (live P0-P2 only): dgq[32] f32, rmax[32] u32
    //  [16384,24576) kfT [32][256]  t*256 + (m ^ ((t&7)<<2))  (A-prod B-operand)
    //  [24576,26624) X frags (P0-P3) / A[32][32] + xch (P4-P7)
    //  [26624,26656) den f32[32]
    //  [26656,26688) dgk f32[32]
    __shared__ __attribute__((aligned(16))) unsigned lds_[26688];
    unsigned* qf_  = lds_;
    unsigned* kf_  = lds_ + 8192;
    unsigned* kfT_ = lds_ + 16384;
    unsigned* XA_  = lds_ + 24576;
    float*   den_ = (float*)(lds_ + 26624);
    float*   dgk_ = (float*)(lds_ + 26656);
    float*   dgq_ = (float*)kf_;
    unsigned* rmax_ = kf_ + 32;
    unsigned* A_ = XA_;
    float*   xch_ = (float*)(XA_ + 1024);
    short (*Xh)[64][8] = (short (*)[64][8])XA_;
    short (*Xl)[64][8] = (short (*)[64][8])(XA_ + 1024);

    int tid = threadIdx.x;
    int lane = tid & 63, w = tid >> 6;
    int l15 = lane & 15, g = lane >> 4;
    int et = w & 3, rt = w >> 2;
    bool owner = (rt == 0);     // owners: A at P4, inter at P6, output rows 0..15
    int cx = blockIdx.x, bh = blockIdx.y;
    bool causal = (cx > 0);
    int o = causal ? (CONDL + (cx-1)*CH) : 0;
    int nsub = (causal ? CH : CONDL) >> 5;
    float epsv = causal ? AEPS : 0.f;
    int slot = causal ? cx : 1;
    const float* Sg = states + ((long)(bh*nch + slot)) * SLOT_F;
    long rowbase = (long)bh * S_TOT + o;
    float kmax = unmapf(*kmax_u);
    int xsw = (l15 & 7) << 2;   // row/m/t & 7 == l15 & 7 for all our frag rows

    // P-fragments in registers (coalesced frag-major load, once)
    bf16x8 Ph_r[2][2], Pl_r[2][2];
    load_pfrags_fm(Pfh, Pfl, w, lane, Ph_r, Pl_r);

    // split state -> registers: wave (rt,et) holds features rt*128..+127:
    // S[Mtl][i] = S_mat[(rt*8+Mtl)*16 + g*4 + i][et*16 + l15]
    f32x4 S[8];
#pragma unroll
    for (int Mtl=0; Mtl<8; Mtl++){
#pragma unroll
        for (int i=0;i<4;i++)
            S[Mtl][i] = Sg[((rt*8 + Mtl)*16 + g*4 + i)*64 + et*16 + l15];
    }
    float z0 = Sg[16384 + w*32 + l15];
    float z1 = Sg[16384 + w*32 + 16 + l15];

    // prefetch pointers (per-thread fixed offsets within a 32-row subtile)
    const float* qptr = q + rowbase*64 + (tid >> 4)*64 + (tid & 15)*4;
    const float* kptr = k + rowbase*64 + (tid >> 4)*64 + (tid & 15)*4;
    float4 qpre = *(const float4*)qptr;

    for (int st = 0; st < nsub; st++){
        long r0 = rowbase + st*32;
        // ---- P0: k prefetch issue; q conversion + init ----
        float4 kpre;
        if (causal) kpre = *(const float4*)(kptr + st*2048);
        conv_store(qpre, tid, Xh, Xl, dgq_);
        if (tid < 32){ den_[tid] = 0.f; rmax_[tid] = 0u; }
        __syncthreads();                      // B1
        // ---- P1: dd_q + rowmax atomics ----
        f32x4 dq[2][2];
        dd_frags(Xh, Xl, lane, Ph_r, Pl_r, dq);
#pragma unroll
        for (int rr=0;rr<2;rr++)
#pragma unroll
          for (int i=0;i<4;i++){
            float mx = fmaxf(dq[rr][0][i], dq[rr][1][i]);
            mx = fmaxf(mx, __shfl_xor(mx, 1, 64));
            mx = fmaxf(mx, __shfl_xor(mx, 2, 64));
            mx = fmaxf(mx, __shfl_xor(mx, 4, 64));
            mx = fmaxf(mx, __shfl_xor(mx, 8, 64));
            if (l15 == 0) atomicMax(&rmax_[rr*16 + g*4 + i], mapf(mx));
          }
        __syncthreads();                      // B2
        // ---- P2: qf finalize + den(z) || k conversion (prefetched) ----
        {
#pragma unroll
            for (int rr=0;rr<2;rr++)
#pragma unroll
              for (int i=0;i<4;i++){
                int row = rr*16 + g*4 + i;
                float dgv = dgq_[row];
                float rm = unmapf(rmax_[row]);
                float s1p = 0.f, s2p = 0.f;
#pragma unroll
                for (int mt=0;mt<2;mt++){
                    float qv = RATIO * (__expf(dq[rr][mt][i] - dgv - rm) + KEPS);
                    s1p += qv;
                    s2p += qv * (mt ? z1 : z0);
                    int m = w*32 + mt*16 + l15;
                    qf_[row*256 + (m ^ ((row & 7) << 2))] = packhl(qv);
                }
#pragma unroll
                for (int d2=1; d2<16; d2<<=1){
                    s1p += __shfl_xor(s1p, d2, 64);
                    s2p += __shfl_xor(s2p, d2, 64);
                }
                if (l15 == 0) atomicAdd(&den_[row], s2p + epsv * s1p);
              }
        }
        if (causal) conv_store(kpre, tid, Xh, Xl, dgk_);
        __syncthreads();                      // B3
        // ---- P3: dd_k + kf/kfT finalize (b128/b32 stores) + z update ----
        if (causal){
            f32x4 dk[2][2];
            dd_frags(Xh, Xl, lane, Ph_r, Pl_r, dk);
            float zd0 = 0.f, zd1 = 0.f;
#pragma unroll
            for (int rr=0;rr<2;rr++){
                float dg0 = dgk_[rr*16 + g*4 + 0];
                float dg1 = dgk_[rr*16 + g*4 + 1];
                float dg2 = dgk_[rr*16 + g*4 + 2];
                float dg3 = dgk_[rr*16 + g*4 + 3];
#pragma unroll
                for (int mt=0;mt<2;mt++){
                    float k0 = RATIO * (__expf(dk[rr][mt][0] - dg0 - kmax) + KEPS);
                    float k1 = RATIO * (__expf(dk[rr][mt][1] - dg1 - kmax) + KEPS);
                    float k2 = RATIO * (__expf(dk[rr][mt][2] - dg2 - kmax) + KEPS);
                    float k3 = RATIO * (__expf(dk[rr][mt][3] - dg3 - kmax) + KEPS);
                    if (mt == 0) zd0 += k0+k1+k2+k3; else zd1 += k0+k1+k2+k3;
                    uint4 kw;
                    kw.x = packhl(k0); kw.y = packhl(k1);
                    kw.z = packhl(k2); kw.w = packhl(k3);
                    int m = w*32 + mt*16 + l15;
                    *(uint4*)&kf_[m*32 + ((rr*16 + g*4) ^ xsw)] = kw;
                    // kfT: same values, transposed tile (qf-identical pattern)
                    int t0r = rr*16 + g*4;
                    kfT_[(t0r+0)*256 + (m ^ ((((g*4)+0) & 7) << 2))] = kw.x;
                    kfT_[(t0r+1)*256 + (m ^ ((((g*4)+1) & 7) << 2))] = kw.y;
                    kfT_[(t0r+2)*256 + (m ^ ((((g*4)+2) & 7) << 2))] = kw.z;
                    kfT_[(t0r+3)*256 + (m ^ ((((g*4)+3) & 7) << 2))] = kw.w;
                }
            }
            zd0 += __shfl_xor(zd0, 16, 64); zd0 += __shfl_xor(zd0, 32, 64);
            zd1 += __shfl_xor(zd1, 16, 64); zd1 += __shfl_xor(zd1, 32, 64);
            z0 += zd0; z1 += zd1;
        }
        __syncthreads();                      // B4
        // ---- P4: q prefetch (st+1); owners: A-product; rt=1: inter + slot ----
        if (st + 1 < nsub) qpre = *(const float4*)(qptr + (st+1)*2048);
        float vv[8];
        if (causal){
            const float* vb = v + r0*64 + et*16 + l15;
#pragma unroll
            for (int p2=0;p2<2;p2++)
#pragma unroll
              for (int j=0;j<4;j++)
                vv[p2*4+j] = vb[(p2*16 + g*4 + j)*64];
        }
        f32x4 Cp0{0.f,0.f,0.f,0.f}, Cp1{0.f,0.f,0.f,0.f};
        if (owner){
            if (causal){
                int ar = et >> 1, tt = et & 1;
                int t = tt*16 + l15;
                int tb = t*256;
                f32x4 c{0.f,0.f,0.f,0.f};
                int rowb = (ar*16 + l15)*256;
                __builtin_amdgcn_s_setprio(1);
#pragma unroll
                for (int kt=0;kt<8;kt++){
                    uint4 q0 = *(const uint4*)&qf_[rowb + ((kt*32 + g*4) ^ xsw)];
                    uint4 q1 = *(const uint4*)&qf_[rowb + ((kt*32 + 16 + g*4) ^ xsw)];
                    bf16x8 qh, ql; unpk(q0, q1, qh, ql);
                    uint4 kt0 = *(const uint4*)&kfT_[tb + ((kt*32 + g*4) ^ xsw)];
                    uint4 kt1 = *(const uint4*)&kfT_[tb + ((kt*32 + 16 + g*4) ^ xsw)];
                    bf16x8 kh, kl; unpk(kt0, kt1, kh, kl);
                    c = MFMA16(qh, kh, c);
                    c = MFMA16(qh, kl, c);
                    c = MFMA16(ql, kh, c);
                }
                __builtin_amdgcn_s_setprio(0);
#pragma unroll
                for (int i=0;i<4;i++){
                    int r = ar*16 + g*4 + i;
                    float a = (t <= r) ? c[i] : 0.f;
                    A_[r*32 + (t ^ ((r & 7) << 2))] = packhl(a);
                    float p = a;
                    p += __shfl_xor(p, 1, 64);
                    p += __shfl_xor(p, 2, 64);
                    p += __shfl_xor(p, 4, 64);
                    p += __shfl_xor(p, 8, 64);
                    if (l15 == 0) atomicAdd(&den_[r], p);
                }
            }
        } else {
            __builtin_amdgcn_s_setprio(1);
            inter_half(qf_, S, rt, l15, g, xsw, Cp0, Cp1);
            __builtin_amdgcn_s_setprio(0);
            // away partial (row-tile 0) -> slot et; keep Cp1 (our quadrant)
            *(float4*)&xch_[(et*64 + lane)*4] = float4{Cp0[0],Cp0[1],Cp0[2],Cp0[3]};
        }
        __syncthreads();                      // B5
        // ---- P6: owners: inter + partner-add + slot write; all: delta + intra ----
        if (owner){
            __builtin_amdgcn_s_setprio(1);
            inter_half(qf_, S, rt, l15, g, xsw, Cp0, Cp1);
            __builtin_amdgcn_s_setprio(0);
            float4 pp = *(const float4*)&xch_[(et*64 + lane)*4];
            Cp0[0] += pp.x; Cp0[1] += pp.y; Cp0[2] += pp.z; Cp0[3] += pp.w;
            // away partial (row-tile 1) for partner
            *(float4*)&xch_[(et*64 + lane)*4] = float4{Cp1[0],Cp1[1],Cp1[2],Cp1[3]};
        }
        if (causal){
            f32x4 va{vv[0], vv[1], vv[2], vv[3]};
            f32x4 vb2{vv[4], vv[5], vv[6], vv[7]};
            bf16x8 vh, vl; sfrag(va, vb2, vh, vl);
            // delta over own feature half: S += Kf^T V
            __builtin_amdgcn_s_setprio(1);
#pragma unroll
            for (int Mtl=0;Mtl<8;Mtl++){
                int mb = ((rt*8 + Mtl)*16 + l15)*32;
                uint4 k0 = *(const uint4*)&kf_[mb + ((g*4) ^ xsw)];
                uint4 k1 = *(const uint4*)&kf_[mb + ((16 + g*4) ^ xsw)];
                bf16x8 kh, kl; unpk(k0, k1, kh, kl);
                S[Mtl] = MFMA16(kh, vh, S[Mtl]);
                S[Mtl] = MFMA16(kh, vl, S[Mtl]);
                S[Mtl] = MFMA16(kl, vh, S[Mtl]);
            }
            __builtin_amdgcn_s_setprio(0);
            // intra: A @ V for this wave's output row-tile (rt)
            int rb = (rt*16 + l15)*32;
            uint4 a0 = *(const uint4*)&A_[rb + ((g*4) ^ xsw)];
            uint4 a1 = *(const uint4*)&A_[rb + ((16 + g*4) ^ xsw)];
            bf16x8 ah, al; unpk(a0, a1, ah, al);
            f32x4& Ct = owner ? Cp0 : Cp1;
            Ct = MFMA16(ah, vh, Ct);
            Ct = MFMA16(ah, vl, Ct);
            Ct = MFMA16(al, vh, Ct);
        }
        if (owner){
#pragma unroll
            for (int i=0;i<4;i++){
                int row = g*4 + i;
                out[(r0 + row)*64 + et*16 + l15] = Cp0[i] / den_[row];
            }
        }
        __syncthreads();                      // B6
        // ---- P7: rt=1 waves: partner-add + output rows 16..31 ----
        if (!owner){
            float4 pp = *(const float4*)&xch_[(et*64 + lane)*4];
            Cp1[0] += pp.x; Cp1[1] += pp.y; Cp1[2] += pp.z; Cp1[3] += pp.w;
#pragma unroll
            for (int i=0;i<4;i++){
                int row = 16 + g*4 + i;
                out[(r0 + row)*64 + et*16 + l15] = Cp1[i] / den_[row];
            }
        }
        __syncthreads();                      // B7 (end)
    }
}

extern "C" void kernel_launch(void* const* d_in, const int* in_sizes, int n_in,
                              void* d_out, int out_size, void* d_ws, size_t ws_size,
                              hipStream_t stream) {
    const float* q = (const float*)d_in[0];
    const float* k = (const float*)d_in[1];
    const float* v = (const float*)d_in[2];
    const float* proj = (const float*)d_in[3];
    float* out = (float*)d_out;

    unsigned* kmax_u = (unsigned*)d_ws;
    unsigned short* Ph  = (unsigned short*)((char*)d_ws + 256);
    unsigned short* Pl  = Ph + 16384;
    unsigned short* Pfh = Pl + 16384;
    unsigned short* Pfl = Pfh + 16384;
    float* states = (float*)((char*)d_ws + 256 + 131072);
    size_t fixed = 256 + 131072;

    int CH, nch;
    size_t need128 = fixed + (size_t)64 * 32 * SLOT_F * 4;
    if (ws_size >= need128){ CH = 128; nch = 32; }
    else                  { CH = 992; nch = 5;  }

    hipMemsetAsync(d_ws, 0, 4, stream);
    hipLaunchKernelGGL(init_p_kernel, dim3(64), dim3(256), 0, stream, proj, Ph, Pl, Pfh, Pfl);
    hipLaunchKernelGGL(kmax_kernel, dim3(8192), dim3(256), 0, stream, k, Ph, kmax_u);
    hipLaunchKernelGGL(b_kernel, dim3(nch, 64), dim3(512), 0, stream, k, v, Ph, Pl, kmax_u, states, CH, nch);
    hipLaunchKernelGGL(scan_kernel, dim3(65, 64), dim3(256), 0, stream, states, nch);
    hipLaunchKernelGGL(d_kernel, dim3(nch, 64), dim3(512), 0, stream, q, k, v, Pfh, Pfl, kmax_u, states, out, CH, nch);
}

// Round 12
// 594.048 us; speedup vs baseline: 1.4565x; 1.0755x over previous
//
#include <hip/hip_runtime.h>
#include <math.h>

// Performer FAVOR+ causal linear attention, MI355X.
// B=4 H=16 S=4096 D=64 M=256 features, COND=128 non-causal prefix.
// v13 = v12 (session best: 636.8us) + ONE bounded b_kernel experiment:
// b's P-fragments move from registers (32 VGPRs) to per-dd streaming loads
// from the frag-major global planes (dd_frags_g -- the v5-verified pattern;
// P = 64KB L2-hot shared by all blocks). Frees 32 regs: if b's allocation
// lands <=128 total (the (512,2) min-2-blocks budget), b doubles to
// 2 blocks/CU (LDS 45.5KB x2 fits) and its 3-barrier stall chain gains a
// second resident block. Worst case: ~16 L2 loads/subtile, <=5us regression.
// d_kernel untouched (latency-bound at register-pinned 8 waves/CU; rounds
// 5-10 showed every d-side restructure spills/lengthens/neutral).
// ws: [0..4) kmax (mapped uint), [256..) Ph bf16[256][64], Pl bf16[256][64],
//     Pfm_h/Pfm_l frag-major bf16 planes (32KB each),
//     then chunk states [64][nslot][256*64 + 256] f32.

#define S_TOT 4096
#define CONDL 128
#define SLOT_F 16640
#define RATIO 0.0625f
#define DNORM 0.35355339059327378f
#define KEPS  1e-4f
#define AEPS  1e-6f

typedef __attribute__((ext_vector_type(8))) short bf16x8;
typedef __attribute__((ext_vector_type(2))) unsigned uint2v;
typedef __attribute__((ext_vector_type(4))) float f32x4;

#define MFMA16(a,b,c) __builtin_amdgcn_mfma_f32_16x16x32_bf16(a,b,c,0,0,0)

static __device__ __forceinline__ unsigned cvtpk(float a, float b){
    unsigned r;
    asm("v_cvt_pk_bf16_f32 %0, %1, %2" : "=v"(r) : "v"(a), "v"(b));
    return r;
}
static __device__ __forceinline__ float lo16f(unsigned u){ return __uint_as_float(u << 16); }
static __device__ __forceinline__ float hi16f(unsigned u){ return __uint_as_float(u & 0xffff0000u); }

static __device__ __forceinline__ unsigned short f2bh(float x){
    unsigned u = __float_as_uint(x);
    u += 0x7fffu + ((u >> 16) & 1u);
    return (unsigned short)(u >> 16);
}
static __device__ __forceinline__ float bh2f(unsigned short h){
    return __uint_as_float((unsigned)h << 16);
}
// pack hi/lo bf16 of x into one dword (hi in low16, residual-lo in high16)
static __device__ __forceinline__ unsigned packhl(float x){
    unsigned u1 = cvtpk(x, x);
    float r = x - lo16f(u1);
    return cvtpk(x, r);
}
// two uint4 (halves k=[0..15],[16..31] of this lane's 4+4 elems) -> hi/lo frags
static __device__ __forceinline__ void unpk(const uint4 a, const uint4 b, bf16x8& h, bf16x8& l){
    h[0]=(short)a.x; h[1]=(short)a.y; h[2]=(short)a.z; h[3]=(short)a.w;
    h[4]=(short)b.x; h[5]=(short)b.y; h[6]=(short)b.z; h[7]=(short)b.w;
    l[0]=(short)(a.x>>16); l[1]=(short)(a.y>>16); l[2]=(short)(a.z>>16); l[3]=(short)(a.w>>16);
    l[4]=(short)(b.x>>16); l[5]=(short)(b.y>>16); l[6]=(short)(b.z>>16); l[7]=(short)(b.w>>16);
}
static __device__ __forceinline__ unsigned mapf(float x){
    unsigned u = __float_as_uint(x);
    return (u & 0x80000000u) ? ~u : (u | 0x80000000u);
}
static __device__ __forceinline__ float unmapf(unsigned u){
    return __uint_as_float((u & 0x80000000u) ? (u ^ 0x80000000u) : ~u);
}

// Convert a pre-loaded 32x64 f32 tile row-quad into frag-major hi/lo bf16
// planes + row diag (cooperative across 512 threads).
static __device__ __forceinline__ void conv_store(float4 x4, int tid,
        short (*Xh)[64][8], short (*Xl)[64][8], float* __restrict__ diag_)
{
    int row = tid >> 4;
    int c4  = (tid & 15) * 4;
    float x0 = x4.x*DNORM, x1 = x4.y*DNORM, x2 = x4.z*DNORM, x3 = x4.w*DNORM;
    float ss = x0*x0 + x1*x1 + x2*x2 + x3*x3;
    ss += __shfl_xor(ss, 1, 64);
    ss += __shfl_xor(ss, 2, 64);
    ss += __shfl_xor(ss, 4, 64);
    ss += __shfl_xor(ss, 8, 64);
    if ((tid & 15) == 0) diag_[row] = 0.5f * ss;
    int rt = row >> 4, lr = row & 15;
    int kk = c4 >> 5, c5 = c4 & 31;
    int fg, j0;
    if (c5 < 16){ fg = c5 >> 2; j0 = 0; } else { fg = (c5 - 16) >> 2; j0 = 4; }
    int f = kk*2 + rt;
    unsigned a01 = cvtpk(x0, x1), a23 = cvtpk(x2, x3);
    unsigned b01 = cvtpk(x0 - lo16f(a01), x1 - hi16f(a01));
    unsigned b23 = cvtpk(x2 - lo16f(a23), x3 - hi16f(a23));
    uint2v hv, lv;
    hv[0] = a01; hv[1] = a23;
    lv[0] = b01; lv[1] = b23;
    *(uint2v*)&Xh[f][fg*16 + lr][j0] = hv;
    *(uint2v*)&Xl[f][fg*16 + lr][j0] = lv;
}

static __device__ __forceinline__ void conv_write(const float* __restrict__ Xg, long r0,
        int tid, short (*Xh)[64][8], short (*Xl)[64][8], float* __restrict__ diag_)
{
    int row = tid >> 4;
    int c4  = (tid & 15) * 4;
    float4 x4 = *(const float4*)(Xg + (r0 + row)*64 + c4);
    conv_store(x4, tid, Xh, Xl, diag_);
}

// frag-major P load (coalesced b128) -- d_kernel, held in registers
static __device__ __forceinline__ void load_pfrags_fm(const unsigned short* __restrict__ Pfh,
        const unsigned short* __restrict__ Pfl, int w, int lane,
        bf16x8 (&Ph_r)[2][2], bf16x8 (&Pl_r)[2][2])
{
#pragma unroll
    for (int kk=0; kk<2; kk++)
#pragma unroll
      for (int mt=0; mt<2; mt++){
        int f = w*4 + kk*2 + mt;
        Ph_r[mt][kk] = *(const bf16x8*)(Pfh + (f*64 + lane)*8);
        Pl_r[mt][kk] = *(const bf16x8*)(Pfl + (f*64 + lane)*8);
      }
}

// dd GEMM from shared frags, register P-frags
static __device__ __forceinline__ void dd_frags(const short (*Xh)[64][8], const short (*Xl)[64][8],
        int lane, const bf16x8 (&Pfh)[2][2], const bf16x8 (&Pfl)[2][2], f32x4 (&acc)[2][2])
{
#pragma unroll
    for (int rt=0;rt<2;rt++)
#pragma unroll
      for (int mt=0;mt<2;mt++) acc[rt][mt] = f32x4{0.f,0.f,0.f,0.f};
#pragma unroll
    for (int kk=0;kk<2;kk++)
#pragma unroll
      for (int rt=0;rt<2;rt++){
        bf16x8 xh = *(const bf16x8*)&Xh[kk*2+rt][lane][0];
        bf16x8 xl = *(const bf16x8*)&Xl[kk*2+rt][lane][0];
#pragma unroll
        for (int mt=0;mt<2;mt++){
            acc[rt][mt] = MFMA16(xh, Pfh[mt][kk], acc[rt][mt]);
            acc[rt][mt] = MFMA16(xh, Pfl[mt][kk], acc[rt][mt]);
            acc[rt][mt] = MFMA16(xl, Pfh[mt][kk], acc[rt][mt]);
        }
      }
}

// dd GEMM, P-frags streamed from frag-major global planes (b_kernel path)
static __device__ __forceinline__ void dd_frags_g(const short (*Xh)[64][8], const short (*Xl)[64][8],
        int lane, int w, const unsigned short* __restrict__ Pfh, const unsigned short* __restrict__ Pfl,
        f32x4 (&acc)[2][2])
{
#pragma unroll
    for (int rr=0;rr<2;rr++)
#pragma unroll
      for (int mt=0;mt<2;mt++) acc[rr][mt] = f32x4{0.f,0.f,0.f,0.f};
#pragma unroll
    for (int kk=0;kk<2;kk++){
        bf16x8 ph[2], pl[2];
#pragma unroll
        for (int mt=0;mt<2;mt++){
            int f = w*4 + kk*2 + mt;
            ph[mt] = *(const bf16x8*)(Pfh + (f*64 + lane)*8);
            pl[mt] = *(const bf16x8*)(Pfl + (f*64 + lane)*8);
        }
#pragma unroll
        for (int rr=0;rr<2;rr++){
            bf16x8 xh = *(const bf16x8*)&Xh[kk*2+rr][lane][0];
            bf16x8 xl = *(const bf16x8*)&Xl[kk*2+rr][lane][0];
#pragma unroll
            for (int mt=0;mt<2;mt++){
                acc[rr][mt] = MFMA16(xh, ph[mt], acc[rr][mt]);
                acc[rr][mt] = MFMA16(xh, pl[mt], acc[rr][mt]);
                acc[rr][mt] = MFMA16(xl, ph[mt], acc[rr][mt]);
            }
        }
    }
}

// build hi/lo bf16 B-frag for one kt directly from f32 values (C-layout regs)
static __device__ __forceinline__ void sfrag(const f32x4 a, const f32x4 b, bf16x8& h, bf16x8& l){
    union U { bf16x8 v; unsigned u[4]; } H, L;
    H.u[0] = cvtpk(a[0], a[1]); H.u[1] = cvtpk(a[2], a[3]);
    H.u[2] = cvtpk(b[0], b[1]); H.u[3] = cvtpk(b[2], b[3]);
    L.u[0] = cvtpk(a[0] - lo16f(H.u[0]), a[1] - hi16f(H.u[0]));
    L.u[1] = cvtpk(a[2] - lo16f(H.u[1]), a[3] - hi16f(H.u[1]));
    L.u[2] = cvtpk(b[0] - lo16f(H.u[2]), b[1] - hi16f(H.u[2]));
    L.u[3] = cvtpk(b[2] - lo16f(H.u[3]), b[3] - hi16f(H.u[3]));
    h = H.v; l = L.v;
}

// inter partials over this wave's feature half (ft = rt*4 + ktl), both row-tiles
static __device__ __forceinline__ void inter_half(const unsigned* __restrict__ qf_,
        const f32x4 (&S)[8], int rt, int l15, int g, int xsw,
        f32x4 &Cp0, f32x4 &Cp1)
{
#pragma unroll
    for (int ktl=0; ktl<4; ktl++){
        int ft = rt*4 + ktl;
        bf16x8 sh, sl; sfrag(S[2*ktl], S[2*ktl+1], sh, sl);
        {
            int rowb = l15*256;                 // row-tile 0
            uint4 q0 = *(const uint4*)&qf_[rowb + ((ft*32 + g*4) ^ xsw)];
            uint4 q1 = *(const uint4*)&qf_[rowb + ((ft*32 + 16 + g*4) ^ xsw)];
            bf16x8 qh, ql; unpk(q0, q1, qh, ql);
            Cp0 = MFMA16(qh, sh, Cp0);
            Cp0 = MFMA16(qh, sl, Cp0);
            Cp0 = MFMA16(ql, sh, Cp0);
        }
        {
            int rowb = (16 + l15)*256;          // row-tile 1
            uint4 q0 = *(const uint4*)&qf_[rowb + ((ft*32 + g*4) ^ xsw)];
            uint4 q1 = *(const uint4*)&qf_[rowb + ((ft*32 + 16 + g*4) ^ xsw)];
            bf16x8 qh, ql; unpk(q0, q1, qh, ql);
            Cp1 = MFMA16(qh, sh, Cp1);
            Cp1 = MFMA16(qh, sl, Cp1);
            Cp1 = MFMA16(ql, sh, Cp1);
        }
    }
}

// ---------------- init: P -> bf16 hi/lo (flat + frag-major) ----------------
__global__ __launch_bounds__(256) void init_p_kernel(const float* __restrict__ proj,
        unsigned short* __restrict__ Ph, unsigned short* __restrict__ Pl,
        unsigned short* __restrict__ Pfh, unsigned short* __restrict__ Pfl){
    int i = blockIdx.x*256 + threadIdx.x;   // 16384
    float x = proj[i];
    unsigned short h = f2bh(x);
    unsigned short l = f2bh(x - bh2f(h));
    Ph[i] = h;
    Pl[i] = l;
    // frag-major: i = m*64 + d
    int m = i >> 6, d = i & 63;
    int w = m >> 5, mt = (m >> 4) & 1, l15 = m & 15;
    int kk = d >> 5, r5 = d & 31;
    int half = r5 >> 4, g = (r5 & 15) >> 2, jj = r5 & 3;
    int f = w*4 + kk*2 + mt, lane = g*16 + l15, j = half*4 + jj;
    int o = (f*64 + lane)*8 + j;
    Pfh[o] = h; Pfl[o] = l;
}

// ---------------- kmax: global max of k's data_dash (hi-only is safe) ----------------
__global__ __launch_bounds__(256) void kmax_kernel(const float* __restrict__ k,
        const unsigned short* __restrict__ Ph, unsigned* __restrict__ kmax_u){
    __shared__ float red[4];
    int tid = threadIdx.x;
    int lane = tid & 63, w = tid >> 6;
    int l15 = lane & 15, g = lane >> 4;
    long r0 = (long)blockIdx.x * 32;
    bf16x8 xh[2][2];  // [kk][rt]
#pragma unroll
    for (int kk=0;kk<2;kk++)
#pragma unroll
      for (int rt=0;rt<2;rt++){
        const float* rp = k + (r0 + rt*16 + l15)*64 + kk*32 + g*4;
        float4 a = *(const float4*)rp;
        float4 b = *(const float4*)(rp + 16);
        float xs[8] = {a.x,a.y,a.z,a.w,b.x,b.y,b.z,b.w};
#pragma unroll
        for (int j=0;j<8;j++) xh[kk][rt][j] = (short)f2bh(xs[j]*DNORM);
      }
    float mx = -1e30f;
#pragma unroll
    for (int mtl=0; mtl<4; mtl++){
        int mtile = w*4 + mtl;
        bf16x8 pf[2];
#pragma unroll
        for (int kk=0;kk<2;kk++){
            const unsigned short* ph = Ph + (mtile*16 + l15)*64 + kk*32 + g*4;
#pragma unroll
            for (int j=0;j<4;j++){ pf[kk][j]=(short)ph[j]; pf[kk][4+j]=(short)ph[16+j]; }
        }
        f32x4 acc[2] = {f32x4{0.f,0.f,0.f,0.f}, f32x4{0.f,0.f,0.f,0.f}};
#pragma unroll
        for (int kk=0;kk<2;kk++)
#pragma unroll
          for (int rt=0;rt<2;rt++)
            acc[rt] = MFMA16(xh[kk][rt], pf[kk], acc[rt]);
#pragma unroll
        for (int rt=0;rt<2;rt++)
#pragma unroll
          for (int i=0;i<4;i++) mx = fmaxf(mx, acc[rt][i]);
    }
#pragma unroll
    for (int d=1; d<64; d<<=1) mx = fmaxf(mx, __shfl_xor(mx, d, 64));
    if (lane == 0) red[w] = mx;
    __syncthreads();
    if (tid == 0){
        float m2 = fmaxf(fmaxf(red[0],red[1]), fmaxf(red[2],red[3]));
        atomicMax(kmax_u, mapf(m2));
    }
}

// ---------------- B: per-chunk states S = Kf^T V, z = sum Kf ----------------
__global__ __launch_bounds__(512, 2) void b_kernel(const float* __restrict__ k,
        const float* __restrict__ v,
        const unsigned short* __restrict__ Pfh, const unsigned short* __restrict__ Pfl,
        const unsigned* __restrict__ kmax_u, float* __restrict__ states,
        int CH, int nch){
    __shared__ short Xh[4][64][8], Xl[4][64][8];
    __shared__ unsigned kf_[256*32];     // [m][t] swizzled: m*32 + (t ^ ((m&7)<<2))
    __shared__ unsigned Vt_u[64][36];    // [e][t] packed hi/lo
    __shared__ float diagk_[32];
    int tid = threadIdx.x;
    int lane = tid & 63, w = tid >> 6;
    int l15 = lane & 15, g = lane >> 4;
    int cx = blockIdx.x, bh = blockIdx.y;
    int o = (cx == 0) ? 0 : CONDL + (cx-1)*CH;
    int nsub = ((cx == 0) ? CONDL : CH) >> 5;
    long rowbase = (long)bh * S_TOT + o;
    float kmax = unmapf(*kmax_u);
    int xsw = (l15 & 7) << 2;
    f32x4 Sacc[2][4];   // [mt][et]
#pragma unroll
    for (int mt=0;mt<2;mt++)
#pragma unroll
      for (int et=0;et<4;et++) Sacc[mt][et] = f32x4{0.f,0.f,0.f,0.f};
    float zacc[2] = {0.f, 0.f};

    for (int st = 0; st < nsub; st++){
        long r0 = rowbase + st*32;
        // P0: cooperative k conversion + diag + V staging
        conv_write(k, r0, tid, Xh, Xl, diagk_);
        {
            int t = tid >> 4, e4 = (tid & 15)*4;
            float4 v4 = *(const float4*)(v + (r0 + t)*64 + e4);
            Vt_u[e4+0][t] = packhl(v4.x);
            Vt_u[e4+1][t] = packhl(v4.y);
            Vt_u[e4+2][t] = packhl(v4.z);
            Vt_u[e4+3][t] = packhl(v4.w);
        }
        __syncthreads();
        // P1: dd (P-frags streamed from L2-hot global) + kf finalize
        f32x4 dk[2][2];
        dd_frags_g(Xh, Xl, lane, w, Pfh, Pfl, dk);
        float zd0 = 0.f, zd1 = 0.f;
#pragma unroll
        for (int rr=0;rr<2;rr++){
            float dg0 = diagk_[rr*16 + g*4 + 0];
            float dg1 = diagk_[rr*16 + g*4 + 1];
            float dg2 = diagk_[rr*16 + g*4 + 2];
            float dg3 = diagk_[rr*16 + g*4 + 3];
#pragma unroll
            for (int mt=0;mt<2;mt++){
                float k0 = RATIO * (__expf(dk[rr][mt][0] - dg0 - kmax) + KEPS);
                float k1 = RATIO * (__expf(dk[rr][mt][1] - dg1 - kmax) + KEPS);
                float k2 = RATIO * (__expf(dk[rr][mt][2] - dg2 - kmax) + KEPS);
                float k3 = RATIO * (__expf(dk[rr][mt][3] - dg3 - kmax) + KEPS);
                if (mt == 0) zd0 += k0+k1+k2+k3; else zd1 += k0+k1+k2+k3;
                uint4 kw;
                kw.x = packhl(k0); kw.y = packhl(k1);
                kw.z = packhl(k2); kw.w = packhl(k3);
                int m = w*32 + mt*16 + l15;
                *(uint4*)&kf_[m*32 + ((rr*16 + g*4) ^ xsw)] = kw;
            }
        }
        zd0 += __shfl_xor(zd0, 16, 64); zd0 += __shfl_xor(zd0, 32, 64);
        zd1 += __shfl_xor(zd1, 16, 64); zd1 += __shfl_xor(zd1, 32, 64);
        zacc[0] += zd0; zacc[1] += zd1;
        __syncthreads();
        // P2: state delta MFMAs
#pragma unroll
        for (int mt=0;mt<2;mt++){
            int m = (w*2 + mt)*16 + l15;
            uint4 kp0 = *(const uint4*)&kf_[m*32 + ((g*4) ^ xsw)];
            uint4 kp1 = *(const uint4*)&kf_[m*32 + ((16 + g*4) ^ xsw)];
            bf16x8 kh, kl; unpk(kp0, kp1, kh, kl);
#pragma unroll
            for (int et=0;et<4;et++){
                const uint4* vp0 = (const uint4*)&Vt_u[et*16 + l15][g*4];
                const uint4* vp1 = (const uint4*)&Vt_u[et*16 + l15][16 + g*4];
                bf16x8 vh, vl; unpk(*vp0, *vp1, vh, vl);
                Sacc[mt][et] = MFMA16(kh, vh, Sacc[mt][et]);
                Sacc[mt][et] = MFMA16(kh, vl, Sacc[mt][et]);
                Sacc[mt][et] = MFMA16(kl, vh, Sacc[mt][et]);
            }
        }
        __syncthreads();
    }
    // write state slot
    float* Sg = states + ((long)(bh*nch + cx)) * SLOT_F;
#pragma unroll
    for (int mt=0;mt<2;mt++)
#pragma unroll
      for (int et=0;et<4;et++)
#pragma unroll
        for (int i=0;i<4;i++)
            Sg[((w*2+mt)*16 + g*4 + i)*64 + et*16 + l15] = Sacc[mt][et][i];
    if (g == 0){
        Sg[16384 + w*32 + l15]      = zacc[0];
        Sg[16384 + w*32 + 16 + l15] = zacc[1];
    }
}

// ---------------- C: exclusive scan over chunk slots ----------------
__global__ __launch_bounds__(256) void scan_kernel(float* __restrict__ states, int nch){
    int idx = blockIdx.x*256 + threadIdx.x;
    if (idx >= SLOT_F) return;
    float* base = states + (long)blockIdx.y * nch * SLOT_F + idx;
    float prev = 0.f;
    for (int c = 0; c < nch; c++){
        float t = base[(long)c * SLOT_F];
        base[(long)c * SLOT_F] = prev;
        prev += t;
    }
}

// ---------------- D: outputs (split reg state, kfT tile, 106.75KB LDS) ----------------
__global__ __launch_bounds__(512, 1) void d_kernel(const float* __restrict__ q,
        const float* __restrict__ k, const float* __restrict__ v,
        const unsigned short* __restrict__ Pfh, const unsigned short* __restrict__ Pfl,
        const unsigned* __restrict__ kmax_u, const float* __restrict__ states,
        float* __restrict__ out, int CH, int nch){
    // LDS map (uints), total = 26,688 uints = 106,752 B (1 block/CU):
    //  [0,8192)      qf  [32][256]  row*256 + (m ^ ((row&7)<<2)), packed hi/lo
    //  [8192,16384)  kf  [256][32]  m*32 + (t ^ ((m&7)<<2)), packed hi/lo
    //                  head overlay (live P0-P2 only): dgq[32] f32, rmax[32] u32
    //  [16384,24576) kfT [32][256]  t*256 + (m ^ ((t&7)<<2))  (A-prod B-operand)
    //  [24576,26624) X frags (P0-P3) / A[32][32] + xch (P4-P7)
    //  [26624,26656) den f32[32]
    //  [26656,26688) dgk f32[32]
    __shared__ __attribute__((aligned(16))) unsigned lds_[26688];
    unsigned* qf_  = lds_;
    unsigned* kf_  = lds_ + 8192;
    unsigned* kfT_ = lds_ + 16384;
    unsigned* XA_  = lds_ + 24576;
    float*   den_ = (float*)(lds_ + 26624);
    float*   dgk_ = (float*)(lds_ + 26656);
    float*   dgq_ = (float*)kf_;
    unsigned* rmax_ = kf_ + 32;
    unsigned* A_ = XA_;
    float*   xch_ = (float*)(XA_ + 1024);
    short (*Xh)[64][8] = (short (*)[64][8])XA_;
    short (*Xl)[64][8] = (short (*)[64][8])(XA_ + 1024);

    int tid = threadIdx.x;
    int lane = tid & 63, w = tid >> 6;
    int l15 = lane & 15, g = lane >> 4;
    int et = w & 3, rt = w >> 2;
    bool owner = (rt == 0);     // owners: A at P4, inter at P6, output rows 0..15
    int cx = blockIdx.x, bh = blockIdx.y;
    bool causal = (cx > 0);
    int o = causal ? (CONDL + (cx-1)*CH) : 0;
    int nsub = (causal ? CH : CONDL) >> 5;
    float epsv = causal ? AEPS : 0.f;
    int slot = causal ? cx : 1;
    const float* Sg = states + ((long)(bh*nch + slot)) * SLOT_F;
    long rowbase = (long)bh * S_TOT + o;
    float kmax = unmapf(*kmax_u);
    int xsw = (l15 & 7) << 2;   // row/m/t & 7 == l15 & 7 for all our frag rows

    // P-fragments in registers (coalesced frag-major load, once)
    bf16x8 Ph_r[2][2], Pl_r[2][2];
    load_pfrags_fm(Pfh, Pfl, w, lane, Ph_r, Pl_r);

    // split state -> registers: wave (rt,et) holds features rt*128..+127:
    // S[Mtl][i] = S_mat[(rt*8+Mtl)*16 + g*4 + i][et*16 + l15]
    f32x4 S[8];
#pragma unroll
    for (int Mtl=0; Mtl<8; Mtl++){
#pragma unroll
        for (int i=0;i<4;i++)
            S[Mtl][i] = Sg[((rt*8 + Mtl)*16 + g*4 + i)*64 + et*16 + l15];
    }
    float z0 = Sg[16384 + w*32 + l15];
    float z1 = Sg[16384 + w*32 + 16 + l15];

    // prefetch pointers (per-thread fixed offsets within a 32-row subtile)
    const float* qptr = q + rowbase*64 + (tid >> 4)*64 + (tid & 15)*4;
    const float* kptr = k + rowbase*64 + (tid >> 4)*64 + (tid & 15)*4;
    float4 qpre = *(const float4*)qptr;

    for (int st = 0; st < nsub; st++){
        long r0 = rowbase + st*32;
        // ---- P0: k prefetch issue; q conversion + init ----
        float4 kpre;
        if (causal) kpre = *(const float4*)(kptr + st*2048);
        conv_store(qpre, tid, Xh, Xl, dgq_);
        if (tid < 32){ den_[tid] = 0.f; rmax_[tid] = 0u; }
        __syncthreads();                      // B1
        // ---- P1: dd_q + rowmax atomics ----
        f32x4 dq[2][2];
        dd_frags(Xh, Xl, lane, Ph_r, Pl_r, dq);
#pragma unroll
        for (int rr=0;rr<2;rr++)
#pragma unroll
          for (int i=0;i<4;i++){
            float mx = fmaxf(dq[rr][0][i], dq[rr][1][i]);
            mx = fmaxf(mx, __shfl_xor(mx, 1, 64));
            mx = fmaxf(mx, __shfl_xor(mx, 2, 64));
            mx = fmaxf(mx, __shfl_xor(mx, 4, 64));
            mx = fmaxf(mx, __shfl_xor(mx, 8, 64));
            if (l15 == 0) atomicMax(&rmax_[rr*16 + g*4 + i], mapf(mx));
          }
        __syncthreads();                      // B2
        // ---- P2: qf finalize + den(z) || k conversion (prefetched) ----
        {
#pragma unroll
            for (int rr=0;rr<2;rr++)
#pragma unroll
              for (int i=0;i<4;i++){
                int row = rr*16 + g*4 + i;
                float dgv = dgq_[row];
                float rm = unmapf(rmax_[row]);
                float s1p = 0.f, s2p = 0.f;
#pragma unroll
                for (int mt=0;mt<2;mt++){
                    float qv = RATIO * (__expf(dq[rr][mt][i] - dgv - rm) + KEPS);
                    s1p += qv;
                    s2p += qv * (mt ? z1 : z0);
                    int m = w*32 + mt*16 + l15;
                    qf_[row*256 + (m ^ ((row & 7) << 2))] = packhl(qv);
                }
#pragma unroll
                for (int d2=1; d2<16; d2<<=1){
                    s1p += __shfl_xor(s1p, d2, 64);
                    s2p += __shfl_xor(s2p, d2, 64);
                }
                if (l15 == 0) atomicAdd(&den_[row], s2p + epsv * s1p);
              }
        }
        if (causal) conv_store(kpre, tid, Xh, Xl, dgk_);
        __syncthreads();                      // B3
        // ---- P3: dd_k + kf/kfT finalize (b128/b32 stores) + z update ----
        if (causal){
            f32x4 dk[2][2];
            dd_frags(Xh, Xl, lane, Ph_r, Pl_r, dk);
            float zd0 = 0.f, zd1 = 0.f;
#pragma unroll
            for (int rr=0;rr<2;rr++){
                float dg0 = dgk_[rr*16 + g*4 + 0];
                float dg1 = dgk_[rr*16 + g*4 + 1];
                float dg2 = dgk_[rr*16 + g*4 + 2];
                float dg3 = dgk_[rr*16 + g*4 + 3];
#pragma unroll
                for (int mt=0;mt<2;mt++){
                    float k0 = RATIO * (__expf(dk[rr][mt][0] - dg0 - kmax) + KEPS);
                    float k1 = RATIO * (__expf(dk[rr][mt][1] - dg1 - kmax) + KEPS);
                    float k2 = RATIO * (__expf(dk[rr][mt][2] - dg2 - kmax) + KEPS);
                    float k3 = RATIO * (__expf(dk[rr][mt][3] - dg3 - kmax) + KEPS);
                    if (mt == 0) zd0 += k0+k1+k2+k3; else zd1 += k0+k1+k2+k3;
                    uint4 kw;
                    kw.x = packhl(k0); kw.y = packhl(k1);
                    kw.z = packhl(k2); kw.w = packhl(k3);
                    int m = w*32 + mt*16 + l15;
                    *(uint4*)&kf_[m*32 + ((rr*16 + g*4) ^ xsw)] = kw;
                    // kfT: same values, transposed tile (qf-identical pattern)
                    int t0r = rr*16 + g*4;
                    kfT_[(t0r+0)*256 + (m ^ ((((g*4)+0) & 7) << 2))] = kw.x;
                    kfT_[(t0r+1)*256 + (m ^ ((((g*4)+1) & 7) << 2))] = kw.y;
                    kfT_[(t0r+2)*256 + (m ^ ((((g*4)+2) & 7) << 2))] = kw.z;
                    kfT_[(t0r+3)*256 + (m ^ ((((g*4)+3) & 7) << 2))] = kw.w;
                }
            }
            zd0 += __shfl_xor(zd0, 16, 64); zd0 += __shfl_xor(zd0, 32, 64);
            zd1 += __shfl_xor(zd1, 16, 64); zd1 += __shfl_xor(zd1, 32, 64);
            z0 += zd0; z1 += zd1;
        }
        __syncthreads();                      // B4
        // ---- P4: q prefetch (st+1); owners: A-product; rt=1: inter + slot ----
        if (st + 1 < nsub) qpre = *(const float4*)(qptr + (st+1)*2048);
        float vv[8];
        if (causal){
            const float* vb = v + r0*64 + et*16 + l15;
#pragma unroll
            for (int p2=0;p2<2;p2++)
#pragma unroll
              for (int j=0;j<4;j++)
                vv[p2*4+j] = vb[(p2*16 + g*4 + j)*64];
        }
        f32x4 Cp0{0.f,0.f,0.f,0.f}, Cp1{0.f,0.f,0.f,0.f};
        if (owner){
            if (causal){
                int ar = et >> 1, tt = et & 1;
                int t = tt*16 + l15;
                int tb = t*256;
                f32x4 c{0.f,0.f,0.f,0.f};
                int rowb = (ar*16 + l15)*256;
                __builtin_amdgcn_s_setprio(1);
#pragma unroll
                for (int kt=0;kt<8;kt++){
                    uint4 q0 = *(const uint4*)&qf_[rowb + ((kt*32 + g*4) ^ xsw)];
                    uint4 q1 = *(const uint4*)&qf_[rowb + ((kt*32 + 16 + g*4) ^ xsw)];
                    bf16x8 qh, ql; unpk(q0, q1, qh, ql);
                    uint4 kt0 = *(const uint4*)&kfT_[tb + ((kt*32 + g*4) ^ xsw)];
                    uint4 kt1 = *(const uint4*)&kfT_[tb + ((kt*32 + 16 + g*4) ^ xsw)];
                    bf16x8 kh, kl; unpk(kt0, kt1, kh, kl);
                    c = MFMA16(qh, kh, c);
                    c = MFMA16(qh, kl, c);
                    c = MFMA16(ql, kh, c);
                }
                __builtin_amdgcn_s_setprio(0);
#pragma unroll
                for (int i=0;i<4;i++){
                    int r = ar*16 + g*4 + i;
                    float a = (t <= r) ? c[i] : 0.f;
                    A_[r*32 + (t ^ ((r & 7) << 2))] = packhl(a);
                    float p = a;
                    p += __shfl_xor(p, 1, 64);
                    p += __shfl_xor(p, 2, 64);
                    p += __shfl_xor(p, 4, 64);
                    p += __shfl_xor(p, 8, 64);
                    if (l15 == 0) atomicAdd(&den_[r], p);
                }
            }
        } else {
            __builtin_amdgcn_s_setprio(1);
            inter_half(qf_, S, rt, l15, g, xsw, Cp0, Cp1);
            __builtin_amdgcn_s_setprio(0);
            // away partial (row-tile 0) -> slot et; keep Cp1 (our quadrant)
            *(float4*)&xch_[(et*64 + lane)*4] = float4{Cp0[0],Cp0[1],Cp0[2],Cp0[3]};
        }
        __syncthreads();                      // B5
        // ---- P6: owners: inter + partner-add + slot write; all: delta + intra ----
        if (owner){
            __builtin_amdgcn_s_setprio(1);
            inter_half(qf_, S, rt, l15, g, xsw, Cp0, Cp1);
            __builtin_amdgcn_s_setprio(0);
            float4 pp = *(const float4*)&xch_[(et*64 + lane)*4];
            Cp0[0] += pp.x; Cp0[1] += pp.y; Cp0[2] += pp.z; Cp0[3] += pp.w;
            // away partial (row-tile 1) for partner
            *(float4*)&xch_[(et*64 + lane)*4] = float4{Cp1[0],Cp1[1],Cp1[2],Cp1[3]};
        }
        if (causal){
            f32x4 va{vv[0], vv[1], vv[2], vv[3]};
            f32x4 vb2{vv[4], vv[5], vv[6], vv[7]};
            bf16x8 vh, vl; sfrag(va, vb2, vh, vl);
            // delta over own feature half: S += Kf^T V
            __builtin_amdgcn_s_setprio(1);
#pragma unroll
            for (int Mtl=0;Mtl<8;Mtl++){
                int mb = ((rt*8 + Mtl)*16 + l15)*32;
                uint4 k0 = *(const uint4*)&kf_[mb + ((g*4) ^ xsw)];
                uint4 k1 = *(const uint4*)&kf_[mb + ((16 + g*4) ^ xsw)];
                bf16x8 kh, kl; unpk(k0, k1, kh, kl);
                S[Mtl] = MFMA16(kh, vh, S[Mtl]);
                S[Mtl] = MFMA16(kh, vl, S[Mtl]);
                S[Mtl] = MFMA16(kl, vh, S[Mtl]);
            }
            __builtin_amdgcn_s_setprio(0);
            // intra: A @ V for this wave's output row-tile (rt)
            int rb = (rt*16 + l15)*32;
            uint4 a0 = *(const uint4*)&A_[rb + ((g*4) ^ xsw)];
            uint4 a1 = *(const uint4*)&A_[rb + ((16 + g*4) ^ xsw)];
            bf16x8 ah, al; unpk(a0, a1, ah, al);
            f32x4& Ct = owner ? Cp0 : Cp1;
            Ct = MFMA16(ah, vh, Ct);
            Ct = MFMA16(ah, vl, Ct);
            Ct = MFMA16(al, vh, Ct);
        }
        if (owner){
#pragma unroll
            for (int i=0;i<4;i++){
                int row = g*4 + i;
                out[(r0 + row)*64 + et*16 + l15] = Cp0[i] / den_[row];
            }
        }
        __syncthreads();                      // B6
        // ---- P7: rt=1 waves: partner-add + output rows 16..31 ----
        if (!owner){
            float4 pp = *(const float4*)&xch_[(et*64 + lane)*4];
            Cp1[0] += pp.x; Cp1[1] += pp.y; Cp1[2] += pp.z; Cp1[3] += pp.w;
#pragma unroll
            for (int i=0;i<4;i++){
                int row = 16 + g*4 + i;
                out[(r0 + row)*64 + et*16 + l15] = Cp1[i] / den_[row];
            }
        }
        __syncthreads();                      // B7 (end)
    }
}

extern "C" void kernel_launch(void* const* d_in, const int* in_sizes, int n_in,
                              void* d_out, int out_size, void* d_ws, size_t ws_size,
                              hipStream_t stream) {
    const float* q = (const float*)d_in[0];
    const float* k = (const float*)d_in[1];
    const float* v = (const float*)d_in[2];
    const float* proj = (const float*)d_in[3];
    float* out = (float*)d_out;

    unsigned* kmax_u = (unsigned*)d_ws;
    unsigned short* Ph  = (unsigned short*)((char*)d_ws + 256);
    unsigned short* Pl  = Ph + 16384;
    unsigned short* Pfh = Pl + 16384;
    unsigned short* Pfl = Pfh + 16384;
    float* states = (float*)((char*)d_ws + 256 + 131072);
    size_t fixed = 256 + 131072;

    int CH, nch;
    size_t need128 = fixed + (size_t)64 * 32 * SLOT_F * 4;
    if (ws_size >= need128){ CH = 128; nch = 32; }
    else                  { CH = 992; nch = 5;  }

    hipMemsetAsync(d_ws, 0, 4, stream);
    hipLaunchKernelGGL(init_p_kernel, dim3(64), dim3(256), 0, stream, proj, Ph, Pl, Pfh, Pfl);
    hipLaunchKernelGGL(kmax_kernel, dim3(8192), dim3(256), 0, stream, k, Ph, kmax_u);
    hipLaunchKernelGGL(b_kernel, dim3(nch, 64), dim3(512), 0, stream, k, v, Pfh, Pfl, kmax_u, states, CH, nch);
    hipLaunchKernelGGL(scan_kernel, dim3(65, 64), dim3(256), 0, stream, states, nch);
    hipLaunchKernelGGL(d_kernel, dim3(nch, 64), dim3(512), 0, stream, q, k, v, Pfh, Pfl, kmax_u, states, out, CH, nch);
}

// Round 13
// 588.145 us; speedup vs baseline: 1.4711x; 1.0100x over previous
//
#include <hip/hip_runtime.h>
#include <math.h>

// Performer FAVOR+ causal linear attention, MI355X.
// B=4 H=16 S=4096 D=64 M=256 features, COND=128 non-causal prefix.
// v14 = v13 (594us: b streams P-frags from L2 -> 2 blocks/CU) + two bounded
// polish items on the small kernels:
//  1) kmax: P fragment loads via frag-major planes (8 coalesced b128/wave
//     instead of 32 scalar ushort gathers). Mapping: m=mtile*16+l15 =>
//     f=(mtile>>1)*4+kk*2+(mtile&1), lane/element order = init_p layout.
//     Ph/Pl flat planes now unused everywhere -> init_p stops writing them.
//  2) scan: 32 strided loads hoisted into registers (static unroll) so the
//     dependent read->store->add chain becomes {32 in-flight loads; stores}.
// d_kernel untouched (structurally pinned at 8 waves/CU: 128 arch + 64 acc
// regs, 107KB LDS; rounds 5-11 exhausted the d-side levers).
// ws: [0..4) kmax (mapped uint), [256..) [unused 64KB legacy Ph/Pl region],
//     Pfm_h/Pfm_l frag-major bf16 planes (32KB each),
//     then chunk states [64][nslot][256*64 + 256] f32.

#define S_TOT 4096
#define CONDL 128
#define SLOT_F 16640
#define RATIO 0.0625f
#define DNORM 0.35355339059327378f
#define KEPS  1e-4f
#define AEPS  1e-6f

typedef __attribute__((ext_vector_type(8))) short bf16x8;
typedef __attribute__((ext_vector_type(2))) unsigned uint2v;
typedef __attribute__((ext_vector_type(4))) float f32x4;

#define MFMA16(a,b,c) __builtin_amdgcn_mfma_f32_16x16x32_bf16(a,b,c,0,0,0)

static __device__ __forceinline__ unsigned cvtpk(float a, float b){
    unsigned r;
    asm("v_cvt_pk_bf16_f32 %0, %1, %2" : "=v"(r) : "v"(a), "v"(b));
    return r;
}
static __device__ __forceinline__ float lo16f(unsigned u){ return __uint_as_float(u << 16); }
static __device__ __forceinline__ float hi16f(unsigned u){ return __uint_as_float(u & 0xffff0000u); }

static __device__ __forceinline__ unsigned short f2bh(float x){
    unsigned u = __float_as_uint(x);
    u += 0x7fffu + ((u >> 16) & 1u);
    return (unsigned short)(u >> 16);
}
static __device__ __forceinline__ float bh2f(unsigned short h){
    return __uint_as_float((unsigned)h << 16);
}
// pack hi/lo bf16 of x into one dword (hi in low16, residual-lo in high16)
static __device__ __forceinline__ unsigned packhl(float x){
    unsigned u1 = cvtpk(x, x);
    float r = x - lo16f(u1);
    return cvtpk(x, r);
}
// two uint4 (halves k=[0..15],[16..31] of this lane's 4+4 elems) -> hi/lo frags
static __device__ __forceinline__ void unpk(const uint4 a, const uint4 b, bf16x8& h, bf16x8& l){
    h[0]=(short)a.x; h[1]=(short)a.y; h[2]=(short)a.z; h[3]=(short)a.w;
    h[4]=(short)b.x; h[5]=(short)b.y; h[6]=(short)b.z; h[7]=(short)b.w;
    l[0]=(short)(a.x>>16); l[1]=(short)(a.y>>16); l[2]=(short)(a.z>>16); l[3]=(short)(a.w>>16);
    l[4]=(short)(b.x>>16); l[5]=(short)(b.y>>16); l[6]=(short)(b.z>>16); l[7]=(short)(b.w>>16);
}
static __device__ __forceinline__ unsigned mapf(float x){
    unsigned u = __float_as_uint(x);
    return (u & 0x80000000u) ? ~u : (u | 0x80000000u);
}
static __device__ __forceinline__ float unmapf(unsigned u){
    return __uint_as_float((u & 0x80000000u) ? (u ^ 0x80000000u) : ~u);
}

// Convert a pre-loaded 32x64 f32 tile row-quad into frag-major hi/lo bf16
// planes + row diag (cooperative across 512 threads).
static __device__ __forceinline__ void conv_store(float4 x4, int tid,
        short (*Xh)[64][8], short (*Xl)[64][8], float* __restrict__ diag_)
{
    int row = tid >> 4;
    int c4  = (tid & 15) * 4;
    float x0 = x4.x*DNORM, x1 = x4.y*DNORM, x2 = x4.z*DNORM, x3 = x4.w*DNORM;
    float ss = x0*x0 + x1*x1 + x2*x2 + x3*x3;
    ss += __shfl_xor(ss, 1, 64);
    ss += __shfl_xor(ss, 2, 64);
    ss += __shfl_xor(ss, 4, 64);
    ss += __shfl_xor(ss, 8, 64);
    if ((tid & 15) == 0) diag_[row] = 0.5f * ss;
    int rt = row >> 4, lr = row & 15;
    int kk = c4 >> 5, c5 = c4 & 31;
    int fg, j0;
    if (c5 < 16){ fg = c5 >> 2; j0 = 0; } else { fg = (c5 - 16) >> 2; j0 = 4; }
    int f = kk*2 + rt;
    unsigned a01 = cvtpk(x0, x1), a23 = cvtpk(x2, x3);
    unsigned b01 = cvtpk(x0 - lo16f(a01), x1 - hi16f(a01));
    unsigned b23 = cvtpk(x2 - lo16f(a23), x3 - hi16f(a23));
    uint2v hv, lv;
    hv[0] = a01; hv[1] = a23;
    lv[0] = b01; lv[1] = b23;
    *(uint2v*)&Xh[f][fg*16 + lr][j0] = hv;
    *(uint2v*)&Xl[f][fg*16 + lr][j0] = lv;
}

static __device__ __forceinline__ void conv_write(const float* __restrict__ Xg, long r0,
        int tid, short (*Xh)[64][8], short (*Xl)[64][8], float* __restrict__ diag_)
{
    int row = tid >> 4;
    int c4  = (tid & 15) * 4;
    float4 x4 = *(const float4*)(Xg + (r0 + row)*64 + c4);
    conv_store(x4, tid, Xh, Xl, diag_);
}

// frag-major P load (coalesced b128) -- d_kernel, held in registers
static __device__ __forceinline__ void load_pfrags_fm(const unsigned short* __restrict__ Pfh,
        const unsigned short* __restrict__ Pfl, int w, int lane,
        bf16x8 (&Ph_r)[2][2], bf16x8 (&Pl_r)[2][2])
{
#pragma unroll
    for (int kk=0; kk<2; kk++)
#pragma unroll
      for (int mt=0; mt<2; mt++){
        int f = w*4 + kk*2 + mt;
        Ph_r[mt][kk] = *(const bf16x8*)(Pfh + (f*64 + lane)*8);
        Pl_r[mt][kk] = *(const bf16x8*)(Pfl + (f*64 + lane)*8);
      }
}

// dd GEMM from shared frags, register P-frags
static __device__ __forceinline__ void dd_frags(const short (*Xh)[64][8], const short (*Xl)[64][8],
        int lane, const bf16x8 (&Pfh)[2][2], const bf16x8 (&Pfl)[2][2], f32x4 (&acc)[2][2])
{
#pragma unroll
    for (int rt=0;rt<2;rt++)
#pragma unroll
      for (int mt=0;mt<2;mt++) acc[rt][mt] = f32x4{0.f,0.f,0.f,0.f};
#pragma unroll
    for (int kk=0;kk<2;kk++)
#pragma unroll
      for (int rt=0;rt<2;rt++){
        bf16x8 xh = *(const bf16x8*)&Xh[kk*2+rt][lane][0];
        bf16x8 xl = *(const bf16x8*)&Xl[kk*2+rt][lane][0];
#pragma unroll
        for (int mt=0;mt<2;mt++){
            acc[rt][mt] = MFMA16(xh, Pfh[mt][kk], acc[rt][mt]);
            acc[rt][mt] = MFMA16(xh, Pfl[mt][kk], acc[rt][mt]);
            acc[rt][mt] = MFMA16(xl, Pfh[mt][kk], acc[rt][mt]);
        }
      }
}

// dd GEMM, P-frags streamed from frag-major global planes (b_kernel path)
static __device__ __forceinline__ void dd_frags_g(const short (*Xh)[64][8], const short (*Xl)[64][8],
        int lane, int w, const unsigned short* __restrict__ Pfh, const unsigned short* __restrict__ Pfl,
        f32x4 (&acc)[2][2])
{
#pragma unroll
    for (int rr=0;rr<2;rr++)
#pragma unroll
      for (int mt=0;mt<2;mt++) acc[rr][mt] = f32x4{0.f,0.f,0.f,0.f};
#pragma unroll
    for (int kk=0;kk<2;kk++){
        bf16x8 ph[2], pl[2];
#pragma unroll
        for (int mt=0;mt<2;mt++){
            int f = w*4 + kk*2 + mt;
            ph[mt] = *(const bf16x8*)(Pfh + (f*64 + lane)*8);
            pl[mt] = *(const bf16x8*)(Pfl + (f*64 + lane)*8);
        }
#pragma unroll
        for (int rr=0;rr<2;rr++){
            bf16x8 xh = *(const bf16x8*)&Xh[kk*2+rr][lane][0];
            bf16x8 xl = *(const bf16x8*)&Xl[kk*2+rr][lane][0];
#pragma unroll
            for (int mt=0;mt<2;mt++){
                acc[rr][mt] = MFMA16(xh, ph[mt], acc[rr][mt]);
                acc[rr][mt] = MFMA16(xh, pl[mt], acc[rr][mt]);
                acc[rr][mt] = MFMA16(xl, ph[mt], acc[rr][mt]);
            }
        }
    }
}

// build hi/lo bf16 B-frag for one kt directly from f32 values (C-layout regs)
static __device__ __forceinline__ void sfrag(const f32x4 a, const f32x4 b, bf16x8& h, bf16x8& l){
    union U { bf16x8 v; unsigned u[4]; } H, L;
    H.u[0] = cvtpk(a[0], a[1]); H.u[1] = cvtpk(a[2], a[3]);
    H.u[2] = cvtpk(b[0], b[1]); H.u[3] = cvtpk(b[2], b[3]);
    L.u[0] = cvtpk(a[0] - lo16f(H.u[0]), a[1] - hi16f(H.u[0]));
    L.u[1] = cvtpk(a[2] - lo16f(H.u[1]), a[3] - hi16f(H.u[1]));
    L.u[2] = cvtpk(b[0] - lo16f(H.u[2]), b[1] - hi16f(H.u[2]));
    L.u[3] = cvtpk(b[2] - lo16f(H.u[3]), b[3] - hi16f(H.u[3]));
    h = H.v; l = L.v;
}

// inter partials over this wave's feature half (ft = rt*4 + ktl), both row-tiles
static __device__ __forceinline__ void inter_half(const unsigned* __restrict__ qf_,
        const f32x4 (&S)[8], int rt, int l15, int g, int xsw,
        f32x4 &Cp0, f32x4 &Cp1)
{
#pragma unroll
    for (int ktl=0; ktl<4; ktl++){
        int ft = rt*4 + ktl;
        bf16x8 sh, sl; sfrag(S[2*ktl], S[2*ktl+1], sh, sl);
        {
            int rowb = l15*256;                 // row-tile 0
            uint4 q0 = *(const uint4*)&qf_[rowb + ((ft*32 + g*4) ^ xsw)];
            uint4 q1 = *(const uint4*)&qf_[rowb + ((ft*32 + 16 + g*4) ^ xsw)];
            bf16x8 qh, ql; unpk(q0, q1, qh, ql);
            Cp0 = MFMA16(qh, sh, Cp0);
            Cp0 = MFMA16(qh, sl, Cp0);
            Cp0 = MFMA16(ql, sh, Cp0);
        }
        {
            int rowb = (16 + l15)*256;          // row-tile 1
            uint4 q0 = *(const uint4*)&qf_[rowb + ((ft*32 + g*4) ^ xsw)];
            uint4 q1 = *(const uint4*)&qf_[rowb + ((ft*32 + 16 + g*4) ^ xsw)];
            bf16x8 qh, ql; unpk(q0, q1, qh, ql);
            Cp1 = MFMA16(qh, sh, Cp1);
            Cp1 = MFMA16(qh, sl, Cp1);
            Cp1 = MFMA16(ql, sh, Cp1);
        }
    }
}

// ---------------- init: P -> bf16 hi/lo frag-major planes ----------------
__global__ __launch_bounds__(256) void init_p_kernel(const float* __restrict__ proj,
        unsigned short* __restrict__ Pfh, unsigned short* __restrict__ Pfl){
    int i = blockIdx.x*256 + threadIdx.x;   // 16384
    float x = proj[i];
    unsigned short h = f2bh(x);
    unsigned short l = f2bh(x - bh2f(h));
    // frag-major: i = m*64 + d
    int m = i >> 6, d = i & 63;
    int w = m >> 5, mt = (m >> 4) & 1, l15 = m & 15;
    int kk = d >> 5, r5 = d & 31;
    int half = r5 >> 4, g = (r5 & 15) >> 2, jj = r5 & 3;
    int f = w*4 + kk*2 + mt, lane = g*16 + l15, j = half*4 + jj;
    int o = (f*64 + lane)*8 + j;
    Pfh[o] = h; Pfl[o] = l;
}

// ---------------- kmax: global max of k's data_dash (hi-only is safe) ----------------
__global__ __launch_bounds__(256) void kmax_kernel(const float* __restrict__ k,
        const unsigned short* __restrict__ Pfh, unsigned* __restrict__ kmax_u){
    __shared__ float red[4];
    int tid = threadIdx.x;
    int lane = tid & 63, w = tid >> 6;
    int l15 = lane & 15, g = lane >> 4;
    long r0 = (long)blockIdx.x * 32;
    bf16x8 xh[2][2];  // [kk][rt]
#pragma unroll
    for (int kk=0;kk<2;kk++)
#pragma unroll
      for (int rt=0;rt<2;rt++){
        const float* rp = k + (r0 + rt*16 + l15)*64 + kk*32 + g*4;
        float4 a = *(const float4*)rp;
        float4 b = *(const float4*)(rp + 16);
        float xs[8] = {a.x,a.y,a.z,a.w,b.x,b.y,b.z,b.w};
#pragma unroll
        for (int j=0;j<8;j++) xh[kk][rt][j] = (short)f2bh(xs[j]*DNORM);
      }
    float mx = -1e30f;
#pragma unroll
    for (int mtl=0; mtl<4; mtl++){
        int mtile = w*4 + mtl;
        bf16x8 pf[2];
#pragma unroll
        for (int kk=0;kk<2;kk++){
            // frag-major: m = mtile*16+l15 -> f = (mtile>>1)*4 + kk*2 + (mtile&1)
            int f = (mtile >> 1)*4 + kk*2 + (mtile & 1);
            pf[kk] = *(const bf16x8*)(Pfh + (f*64 + lane)*8);
        }
        f32x4 acc[2] = {f32x4{0.f,0.f,0.f,0.f}, f32x4{0.f,0.f,0.f,0.f}};
#pragma unroll
        for (int kk=0;kk<2;kk++)
#pragma unroll
          for (int rt=0;rt<2;rt++)
            acc[rt] = MFMA16(xh[kk][rt], pf[kk], acc[rt]);
#pragma unroll
        for (int rt=0;rt<2;rt++)
#pragma unroll
          for (int i=0;i<4;i++) mx = fmaxf(mx, acc[rt][i]);
    }
#pragma unroll
    for (int d=1; d<64; d<<=1) mx = fmaxf(mx, __shfl_xor(mx, d, 64));
    if (lane == 0) red[w] = mx;
    __syncthreads();
    if (tid == 0){
        float m2 = fmaxf(fmaxf(red[0],red[1]), fmaxf(red[2],red[3]));
        atomicMax(kmax_u, mapf(m2));
    }
}

// ---------------- B: per-chunk states S = Kf^T V, z = sum Kf ----------------
__global__ __launch_bounds__(512, 2) void b_kernel(const float* __restrict__ k,
        const float* __restrict__ v,
        const unsigned short* __restrict__ Pfh, const unsigned short* __restrict__ Pfl,
        const unsigned* __restrict__ kmax_u, float* __restrict__ states,
        int CH, int nch){
    __shared__ short Xh[4][64][8], Xl[4][64][8];
    __shared__ unsigned kf_[256*32];     // [m][t] swizzled: m*32 + (t ^ ((m&7)<<2))
    __shared__ unsigned Vt_u[64][36];    // [e][t] packed hi/lo
    __shared__ float diagk_[32];
    int tid = threadIdx.x;
    int lane = tid & 63, w = tid >> 6;
    int l15 = lane & 15, g = lane >> 4;
    int cx = blockIdx.x, bh = blockIdx.y;
    int o = (cx == 0) ? 0 : CONDL + (cx-1)*CH;
    int nsub = ((cx == 0) ? CONDL : CH) >> 5;
    long rowbase = (long)bh * S_TOT + o;
    float kmax = unmapf(*kmax_u);
    int xsw = (l15 & 7) << 2;
    f32x4 Sacc[2][4];   // [mt][et]
#pragma unroll
    for (int mt=0;mt<2;mt++)
#pragma unroll
      for (int et=0;et<4;et++) Sacc[mt][et] = f32x4{0.f,0.f,0.f,0.f};
    float zacc[2] = {0.f, 0.f};

    for (int st = 0; st < nsub; st++){
        long r0 = rowbase + st*32;
        // P0: cooperative k conversion + diag + V staging
        conv_write(k, r0, tid, Xh, Xl, diagk_);
        {
            int t = tid >> 4, e4 = (tid & 15)*4;
            float4 v4 = *(const float4*)(v + (r0 + t)*64 + e4);
            Vt_u[e4+0][t] = packhl(v4.x);
            Vt_u[e4+1][t] = packhl(v4.y);
            Vt_u[e4+2][t] = packhl(v4.z);
            Vt_u[e4+3][t] = packhl(v4.w);
        }
        __syncthreads();
        // P1: dd (P-frags streamed from L2-hot global) + kf finalize
        f32x4 dk[2][2];
        dd_frags_g(Xh, Xl, lane, w, Pfh, Pfl, dk);
        float zd0 = 0.f, zd1 = 0.f;
#pragma unroll
        for (int rr=0;rr<2;rr++){
            float dg0 = diagk_[rr*16 + g*4 + 0];
            float dg1 = diagk_[rr*16 + g*4 + 1];
            float dg2 = diagk_[rr*16 + g*4 + 2];
            float dg3 = diagk_[rr*16 + g*4 + 3];
#pragma unroll
            for (int mt=0;mt<2;mt++){
                float k0 = RATIO * (__expf(dk[rr][mt][0] - dg0 - kmax) + KEPS);
                float k1 = RATIO * (__expf(dk[rr][mt][1] - dg1 - kmax) + KEPS);
                float k2 = RATIO * (__expf(dk[rr][mt][2] - dg2 - kmax) + KEPS);
                float k3 = RATIO * (__expf(dk[rr][mt][3] - dg3 - kmax) + KEPS);
                if (mt == 0) zd0 += k0+k1+k2+k3; else zd1 += k0+k1+k2+k3;
                uint4 kw;
                kw.x = packhl(k0); kw.y = packhl(k1);
                kw.z = packhl(k2); kw.w = packhl(k3);
                int m = w*32 + mt*16 + l15;
                *(uint4*)&kf_[m*32 + ((rr*16 + g*4) ^ xsw)] = kw;
            }
        }
        zd0 += __shfl_xor(zd0, 16, 64); zd0 += __shfl_xor(zd0, 32, 64);
        zd1 += __shfl_xor(zd1, 16, 64); zd1 += __shfl_xor(zd1, 32, 64);
        zacc[0] += zd0; zacc[1] += zd1;
        __syncthreads();
        // P2: state delta MFMAs
#pragma unroll
        for (int mt=0;mt<2;mt++){
            int m = (w*2 + mt)*16 + l15;
            uint4 kp0 = *(const uint4*)&kf_[m*32 + ((g*4) ^ xsw)];
            uint4 kp1 = *(const uint4*)&kf_[m*32 + ((16 + g*4) ^ xsw)];
            bf16x8 kh, kl; unpk(kp0, kp1, kh, kl);
#pragma unroll
            for (int et=0;et<4;et++){
                const uint4* vp0 = (const uint4*)&Vt_u[et*16 + l15][g*4];
                const uint4* vp1 = (const uint4*)&Vt_u[et*16 + l15][16 + g*4];
                bf16x8 vh, vl; unpk(*vp0, *vp1, vh, vl);
                Sacc[mt][et] = MFMA16(kh, vh, Sacc[mt][et]);
                Sacc[mt][et] = MFMA16(kh, vl, Sacc[mt][et]);
                Sacc[mt][et] = MFMA16(kl, vh, Sacc[mt][et]);
            }
        }
        __syncthreads();
    }
    // write state slot
    float* Sg = states + ((long)(bh*nch + cx)) * SLOT_F;
#pragma unroll
    for (int mt=0;mt<2;mt++)
#pragma unroll
      for (int et=0;et<4;et++)
#pragma unroll
        for (int i=0;i<4;i++)
            Sg[((w*2+mt)*16 + g*4 + i)*64 + et*16 + l15] = Sacc[mt][et][i];
    if (g == 0){
        Sg[16384 + w*32 + l15]      = zacc[0];
        Sg[16384 + w*32 + 16 + l15] = zacc[1];
    }
}

// ---------------- C: exclusive scan over chunk slots ----------------
__global__ __launch_bounds__(256) void scan_kernel(float* __restrict__ states, int nch){
    int idx = blockIdx.x*256 + threadIdx.x;
    if (idx >= SLOT_F) return;
    float* base = states + (long)blockIdx.y * nch * SLOT_F + idx;
    if (nch == 32){
        // hoist all 32 strided loads into registers (all in flight), then store
        float vals[32];
#pragma unroll
        for (int c = 0; c < 32; c++) vals[c] = base[(long)c * SLOT_F];
        float prev = 0.f;
#pragma unroll
        for (int c = 0; c < 32; c++){
            base[(long)c * SLOT_F] = prev;
            prev += vals[c];
        }
    } else {
        float prev = 0.f;
        for (int c = 0; c < nch; c++){
            float t = base[(long)c * SLOT_F];
            base[(long)c * SLOT_F] = prev;
            prev += t;
        }
    }
}

// ---------------- D: outputs (split reg state, kfT tile, 106.75KB LDS) ----------------
__global__ __launch_bounds__(512, 1) void d_kernel(const float* __restrict__ q,
        const float* __restrict__ k, const float* __restrict__ v,
        const unsigned short* __restrict__ Pfh, const unsigned short* __restrict__ Pfl,
        const unsigned* __restrict__ kmax_u, const float* __restrict__ states,
        float* __restrict__ out, int CH, int nch){
    // LDS map (uints), total = 26,688 uints = 106,752 B (1 block/CU):
    //  [0,8192)      qf  [32][256]  row*256 + (m ^ ((row&7)<<2)), packed hi/lo
    //  [8192,16384)  kf  [256][32]  m*32 + (t ^ ((m&7)<<2)), packed hi/lo
    //                  head overlay (live P0-P2 only): dgq[32] f32, rmax[32] u32
    //  [16384,24576) kfT [32][256]  t*256 + (m ^ ((t&7)<<2))  (A-prod B-operand)
    //  [24576,26624) X frags (P0-P3) / A[32][32] + xch (P4-P7)
    //  [26624,26656) den f32[32]
    //  [26656,26688) dgk f32[32]
    __shared__ __attribute__((aligned(16))) unsigned lds_[26688];
    unsigned* qf_  = lds_;
    unsigned* kf_  = lds_ + 8192;
    unsigned* kfT_ = lds_ + 16384;
    unsigned* XA_  = lds_ + 24576;
    float*   den_ = (float*)(lds_ + 26624);
    float*   dgk_ = (float*)(lds_ + 26656);
    float*   dgq_ = (float*)kf_;
    unsigned* rmax_ = kf_ + 32;
    unsigned* A_ = XA_;
    float*   xch_ = (float*)(XA_ + 1024);
    short (*Xh)[64][8] = (short (*)[64][8])XA_;
    short (*Xl)[64][8] = (short (*)[64][8])(XA_ + 1024);

    int tid = threadIdx.x;
    int lane = tid & 63, w = tid >> 6;
    int l15 = lane & 15, g = lane >> 4;
    int et = w & 3, rt = w >> 2;
    bool owner = (rt == 0);     // owners: A at P4, inter at P6, output rows 0..15
    int cx = blockIdx.x, bh = blockIdx.y;
    bool causal = (cx > 0);
    int o = causal ? (CONDL + (cx-1)*CH) : 0;
    int nsub = (causal ? CH : CONDL) >> 5;
    float epsv = causal ? AEPS : 0.f;
    int slot = causal ? cx : 1;
    const float* Sg = states + ((long)(bh*nch + slot)) * SLOT_F;
    long rowbase = (long)bh * S_TOT + o;
    float kmax = unmapf(*kmax_u);
    int xsw = (l15 & 7) << 2;   // row/m/t & 7 == l15 & 7 for all our frag rows

    // P-fragments in registers (coalesced frag-major load, once)
    bf16x8 Ph_r[2][2], Pl_r[2][2];
    load_pfrags_fm(Pfh, Pfl, w, lane, Ph_r, Pl_r);

    // split state -> registers: wave (rt,et) holds features rt*128..+127:
    // S[Mtl][i] = S_mat[(rt*8+Mtl)*16 + g*4 + i][et*16 + l15]
    f32x4 S[8];
#pragma unroll
    for (int Mtl=0; Mtl<8; Mtl++){
#pragma unroll
        for (int i=0;i<4;i++)
            S[Mtl][i] = Sg[((rt*8 + Mtl)*16 + g*4 + i)*64 + et*16 + l15];
    }
    float z0 = Sg[16384 + w*32 + l15];
    float z1 = Sg[16384 + w*32 + 16 + l15];

    // prefetch pointers (per-thread fixed offsets within a 32-row subtile)
    const float* qptr = q + rowbase*64 + (tid >> 4)*64 + (tid & 15)*4;
    const float* kptr = k + rowbase*64 + (tid >> 4)*64 + (tid & 15)*4;
    float4 qpre = *(const float4*)qptr;

    for (int st = 0; st < nsub; st++){
        long r0 = rowbase + st*32;
        // ---- P0: k prefetch issue; q conversion + init ----
        float4 kpre;
        if (causal) kpre = *(const float4*)(kptr + st*2048);
        conv_store(qpre, tid, Xh, Xl, dgq_);
        if (tid < 32){ den_[tid] = 0.f; rmax_[tid] = 0u; }
        __syncthreads();                      // B1
        // ---- P1: dd_q + rowmax atomics ----
        f32x4 dq[2][2];
        dd_frags(Xh, Xl, lane, Ph_r, Pl_r, dq);
#pragma unroll
        for (int rr=0;rr<2;rr++)
#pragma unroll
          for (int i=0;i<4;i++){
            float mx = fmaxf(dq[rr][0][i], dq[rr][1][i]);
            mx = fmaxf(mx, __shfl_xor(mx, 1, 64));
            mx = fmaxf(mx, __shfl_xor(mx, 2, 64));
            mx = fmaxf(mx, __shfl_xor(mx, 4, 64));
            mx = fmaxf(mx, __shfl_xor(mx, 8, 64));
            if (l15 == 0) atomicMax(&rmax_[rr*16 + g*4 + i], mapf(mx));
          }
        __syncthreads();                      // B2
        // ---- P2: qf finalize + den(z) || k conversion (prefetched) ----
        {
#pragma unroll
            for (int rr=0;rr<2;rr++)
#pragma unroll
              for (int i=0;i<4;i++){
                int row = rr*16 + g*4 + i;
                float dgv = dgq_[row];
                float rm = unmapf(rmax_[row]);
                float s1p = 0.f, s2p = 0.f;
#pragma unroll
                for (int mt=0;mt<2;mt++){
                    float qv = RATIO * (__expf(dq[rr][mt][i] - dgv - rm) + KEPS);
                    s1p += qv;
                    s2p += qv * (mt ? z1 : z0);
                    int m = w*32 + mt*16 + l15;
                    qf_[row*256 + (m ^ ((row & 7) << 2))] = packhl(qv);
                }
#pragma unroll
                for (int d2=1; d2<16; d2<<=1){
                    s1p += __shfl_xor(s1p, d2, 64);
                    s2p += __shfl_xor(s2p, d2, 64);
                }
                if (l15 == 0) atomicAdd(&den_[row], s2p + epsv * s1p);
              }
        }
        if (causal) conv_store(kpre, tid, Xh, Xl, dgk_);
        __syncthreads();                      // B3
        // ---- P3: dd_k + kf/kfT finalize (b128/b32 stores) + z update ----
        if (causal){
            f32x4 dk[2][2];
            dd_frags(Xh, Xl, lane, Ph_r, Pl_r, dk);
            float zd0 = 0.f, zd1 = 0.f;
#pragma unroll
            for (int rr=0;rr<2;rr++){
                float dg0 = dgk_[rr*16 + g*4 + 0];
                float dg1 = dgk_[rr*16 + g*4 + 1];
                float dg2 = dgk_[rr*16 + g*4 + 2];
                float dg3 = dgk_[rr*16 + g*4 + 3];
#pragma unroll
                for (int mt=0;mt<2;mt++){
                    float k0 = RATIO * (__expf(dk[rr][mt][0] - dg0 - kmax) + KEPS);
                    float k1 = RATIO * (__expf(dk[rr][mt][1] - dg1 - kmax) + KEPS);
                    float k2 = RATIO * (__expf(dk[rr][mt][2] - dg2 - kmax) + KEPS);
                    float k3 = RATIO * (__expf(dk[rr][mt][3] - dg3 - kmax) + KEPS);
                    if (mt == 0) zd0 += k0+k1+k2+k3; else zd1 += k0+k1+k2+k3;
                    uint4 kw;
                    kw.x = packhl(k0); kw.y = packhl(k1);
                    kw.z = packhl(k2); kw.w = packhl(k3);
                    int m = w*32 + mt*16 + l15;
                    *(uint4*)&kf_[m*32 + ((rr*16 + g*4) ^ xsw)] = kw;
                    // kfT: same values, transposed tile (qf-identical pattern)
                    int t0r = rr*16 + g*4;
                    kfT_[(t0r+0)*256 + (m ^ ((((g*4)+0) & 7) << 2))] = kw.x;
                    kfT_[(t0r+1)*256 + (m ^ ((((g*4)+1) & 7) << 2))] = kw.y;
                    kfT_[(t0r+2)*256 + (m ^ ((((g*4)+2) & 7) << 2))] = kw.z;
                    kfT_[(t0r+3)*256 + (m ^ ((((g*4)+3) & 7) << 2))] = kw.w;
                }
            }
            zd0 += __shfl_xor(zd0, 16, 64); zd0 += __shfl_xor(zd0, 32, 64);
            zd1 += __shfl_xor(zd1, 16, 64); zd1 += __shfl_xor(zd1, 32, 64);
            z0 += zd0; z1 += zd1;
        }
        __syncthreads();                      // B4
        // ---- P4: q prefetch (st+1); owners: A-product; rt=1: inter + slot ----
        if (st + 1 < nsub) qpre = *(const float4*)(qptr + (st+1)*2048);
        float vv[8];
        if (causal){
            const float* vb = v + r0*64 + et*16 + l15;
#pragma unroll
            for (int p2=0;p2<2;p2++)
#pragma unroll
              for (int j=0;j<4;j++)
                vv[p2*4+j] = vb[(p2*16 + g*4 + j)*64];
        }
        f32x4 Cp0{0.f,0.f,0.f,0.f}, Cp1{0.f,0.f,0.f,0.f};
        if (owner){
            if (causal){
                int ar = et >> 1, tt = et & 1;
                int t = tt*16 + l15;
                int tb = t*256;
                f32x4 c{0.f,0.f,0.f,0.f};
                int rowb = (ar*16 + l15)*256;
                __builtin_amdgcn_s_setprio(1);
#pragma unroll
                for (int kt=0;kt<8;kt++){
                    uint4 q0 = *(const uint4*)&qf_[rowb + ((kt*32 + g*4) ^ xsw)];
                    uint4 q1 = *(const uint4*)&qf_[rowb + ((kt*32 + 16 + g*4) ^ xsw)];
                    bf16x8 qh, ql; unpk(q0, q1, qh, ql);
                    uint4 kt0 = *(const uint4*)&kfT_[tb + ((kt*32 + g*4) ^ xsw)];
                    uint4 kt1 = *(const uint4*)&kfT_[tb + ((kt*32 + 16 + g*4) ^ xsw)];
                    bf16x8 kh, kl; unpk(kt0, kt1, kh, kl);
                    c = MFMA16(qh, kh, c);
                    c = MFMA16(qh, kl, c);
                    c = MFMA16(ql, kh, c);
                }
                __builtin_amdgcn_s_setprio(0);
#pragma unroll
                for (int i=0;i<4;i++){
                    int r = ar*16 + g*4 + i;
                    float a = (t <= r) ? c[i] : 0.f;
                    A_[r*32 + (t ^ ((r & 7) << 2))] = packhl(a);
                    float p = a;
                    p += __shfl_xor(p, 1, 64);
                    p += __shfl_xor(p, 2, 64);
                    p += __shfl_xor(p, 4, 64);
                    p += __shfl_xor(p, 8, 64);
                    if (l15 == 0) atomicAdd(&den_[r], p);
                }
            }
        } else {
            __builtin_amdgcn_s_setprio(1);
            inter_half(qf_, S, rt, l15, g, xsw, Cp0, Cp1);
            __builtin_amdgcn_s_setprio(0);
            // away partial (row-tile 0) -> slot et; keep Cp1 (our quadrant)
            *(float4*)&xch_[(et*64 + lane)*4] = float4{Cp0[0],Cp0[1],Cp0[2],Cp0[3]};
        }
        __syncthreads();                      // B5
        // ---- P6: owners: inter + partner-add + slot write; all: delta + intra ----
        if (owner){
            __builtin_amdgcn_s_setprio(1);
            inter_half(qf_, S, rt, l15, g, xsw, Cp0, Cp1);
            __builtin_amdgcn_s_setprio(0);
            float4 pp = *(const float4*)&xch_[(et*64 + lane)*4];
            Cp0[0] += pp.x; Cp0[1] += pp.y; Cp0[2] += pp.z; Cp0[3] += pp.w;
            // away partial (row-tile 1) for partner
            *(float4*)&xch_[(et*64 + lane)*4] = float4{Cp1[0],Cp1[1],Cp1[2],Cp1[3]};
        }
        if (causal){
            f32x4 va{vv[0], vv[1], vv[2], vv[3]};
            f32x4 vb2{vv[4], vv[5], vv[6], vv[7]};
            bf16x8 vh, vl; sfrag(va, vb2, vh, vl);
            // delta over own feature half: S += Kf^T V
            __builtin_amdgcn_s_setprio(1);
#pragma unroll
            for (int Mtl=0;Mtl<8;Mtl++){
                int mb = ((rt*8 + Mtl)*16 + l15)*32;
                uint4 k0 = *(const uint4*)&kf_[mb + ((g*4) ^ xsw)];
                uint4 k1 = *(const uint4*)&kf_[mb + ((16 + g*4) ^ xsw)];
                bf16x8 kh, kl; unpk(k0, k1, kh, kl);
                S[Mtl] = MFMA16(kh, vh, S[Mtl]);
                S[Mtl] = MFMA16(kh, vl, S[Mtl]);
                S[Mtl] = MFMA16(kl, vh, S[Mtl]);
            }
            __builtin_amdgcn_s_setprio(0);
            // intra: A @ V for this wave's output row-tile (rt)
            int rb = (rt*16 + l15)*32;
            uint4 a0 = *(const uint4*)&A_[rb + ((g*4) ^ xsw)];
            uint4 a1 = *(const uint4*)&A_[rb + ((16 + g*4) ^ xsw)];
            bf16x8 ah, al; unpk(a0, a1, ah, al);
            f32x4& Ct = owner ? Cp0 : Cp1;
            Ct = MFMA16(ah, vh, Ct);
            Ct = MFMA16(ah, vl, Ct);
            Ct = MFMA16(al, vh, Ct);
        }
        if (owner){
#pragma unroll
            for (int i=0;i<4;i++){
                int row = g*4 + i;
                out[(r0 + row)*64 + et*16 + l15] = Cp0[i] / den_[row];
            }
        }
        __syncthreads();                      // B6
        // ---- P7: rt=1 waves: partner-add + output rows 16..31 ----
        if (!owner){
            float4 pp = *(const float4*)&xch_[(et*64 + lane)*4];
            Cp1[0] += pp.x; Cp1[1] += pp.y; Cp1[2] += pp.z; Cp1[3] += pp.w;
#pragma unroll
            for (int i=0;i<4;i++){
                int row = 16 + g*4 + i;
                out[(r0 + row)*64 + et*16 + l15] = Cp1[i] / den_[row];
            }
        }
        __syncthreads();                      // B7 (end)
    }
}

extern "C" void kernel_launch(void* const* d_in, const int* in_sizes, int n_in,
                              void* d_out, int out_size, void* d_ws, size_t ws_size,
                              hipStream_t stream) {
    const float* q = (const float*)d_in[0];
    const float* k = (const float*)d_in[1];
    const float* v = (const float*)d_in[2];
    const float* proj = (const float*)d_in[3];
    float* out = (float*)d_out;

    unsigned* kmax_u = (unsigned*)d_ws;
    // legacy flat Ph/Pl region at [256, 256+64KB) left unused
    unsigned short* Pfh = (unsigned short*)((char*)d_ws + 256 + 65536);
    unsigned short* Pfl = Pfh + 16384;
    float* states = (float*)((char*)d_ws + 256 + 131072);
    size_t fixed = 256 + 131072;

    int CH, nch;
    size_t need128 = fixed + (size_t)64 * 32 * SLOT_F * 4;
    if (ws_size >= need128){ CH = 128; nch = 32; }
    else                  { CH = 992; nch = 5;  }

    hipMemsetAsync(d_ws, 0, 4, stream);
    hipLaunchKernelGGL(init_p_kernel, dim3(64), dim3(256), 0, stream, proj, Pfh, Pfl);
    hipLaunchKernelGGL(kmax_kernel, dim3(8192), dim3(256), 0, stream, k, Pfh, kmax_u);
    hipLaunchKernelGGL(b_kernel, dim3(nch, 64), dim3(512), 0, stream, k, v, Pfh, Pfl, kmax_u, states, CH, nch);
    hipLaunchKernelGGL(scan_kernel, dim3(65, 64), dim3(256), 0, stream, states, nch);
    hipLaunchKernelGGL(d_kernel, dim3(nch, 64), dim3(512), 0, stream, q, k, v, Pfh, Pfl, kmax_u, states, out, CH, nch);
}

// Round 14
// 580.293 us; speedup vs baseline: 1.4910x; 1.0135x over previous
//
#include <hip/hip_runtime.h>
#include <math.h>

// Performer FAVOR+ causal linear attention, MI355X.
// B=4 H=16 S=4096 D=64 M=256 features, COND=128 non-causal prefix.
// v15 = v14 (588us) + T14 issue-early prefetch in b_kernel: k/v loads for
// subtile st+1 issue at the top of P2 (24 delta-MFMAs cover HBM latency),
// consumed at next P0 (conv_store + register-staged V). Removes the serial
// HBM stall at each P0 head. +8 VGPRs (two float4 carries) -- v13 freed 32,
// live set ~100-110, so the 128-reg 2-blocks/CU budget should still hold.
// d/kmax/scan/init byte-identical to v14.
// ws: [0..4) kmax (mapped uint), [256..) [unused 64KB legacy Ph/Pl region],
//     Pfm_h/Pfm_l frag-major bf16 planes (32KB each),
//     then chunk states [64][nslot][256*64 + 256] f32.

#define S_TOT 4096
#define CONDL 128
#define SLOT_F 16640
#define RATIO 0.0625f
#define DNORM 0.35355339059327378f
#define KEPS  1e-4f
#define AEPS  1e-6f

typedef __attribute__((ext_vector_type(8))) short bf16x8;
typedef __attribute__((ext_vector_type(2))) unsigned uint2v;
typedef __attribute__((ext_vector_type(4))) float f32x4;

#define MFMA16(a,b,c) __builtin_amdgcn_mfma_f32_16x16x32_bf16(a,b,c,0,0,0)

static __device__ __forceinline__ unsigned cvtpk(float a, float b){
    unsigned r;
    asm("v_cvt_pk_bf16_f32 %0, %1, %2" : "=v"(r) : "v"(a), "v"(b));
    return r;
}
static __device__ __forceinline__ float lo16f(unsigned u){ return __uint_as_float(u << 16); }
static __device__ __forceinline__ float hi16f(unsigned u){ return __uint_as_float(u & 0xffff0000u); }

static __device__ __forceinline__ unsigned short f2bh(float x){
    unsigned u = __float_as_uint(x);
    u += 0x7fffu + ((u >> 16) & 1u);
    return (unsigned short)(u >> 16);
}
static __device__ __forceinline__ float bh2f(unsigned short h){
    return __uint_as_float((unsigned)h << 16);
}
// pack hi/lo bf16 of x into one dword (hi in low16, residual-lo in high16)
static __device__ __forceinline__ unsigned packhl(float x){
    unsigned u1 = cvtpk(x, x);
    float r = x - lo16f(u1);
    return cvtpk(x, r);
}
// two uint4 (halves k=[0..15],[16..31] of this lane's 4+4 elems) -> hi/lo frags
static __device__ __forceinline__ void unpk(const uint4 a, const uint4 b, bf16x8& h, bf16x8& l){
    h[0]=(short)a.x; h[1]=(short)a.y; h[2]=(short)a.z; h[3]=(short)a.w;
    h[4]=(short)b.x; h[5]=(short)b.y; h[6]=(short)b.z; h[7]=(short)b.w;
    l[0]=(short)(a.x>>16); l[1]=(short)(a.y>>16); l[2]=(short)(a.z>>16); l[3]=(short)(a.w>>16);
    l[4]=(short)(b.x>>16); l[5]=(short)(b.y>>16); l[6]=(short)(b.z>>16); l[7]=(short)(b.w>>16);
}
static __device__ __forceinline__ unsigned mapf(float x){
    unsigned u = __float_as_uint(x);
    return (u & 0x80000000u) ? ~u : (u | 0x80000000u);
}
static __device__ __forceinline__ float unmapf(unsigned u){
    return __uint_as_float((u & 0x80000000u) ? (u ^ 0x80000000u) : ~u);
}

// Convert a pre-loaded 32x64 f32 tile row-quad into frag-major hi/lo bf16
// planes + row diag (cooperative across 512 threads).
static __device__ __forceinline__ void conv_store(float4 x4, int tid,
        short (*Xh)[64][8], short (*Xl)[64][8], float* __restrict__ diag_)
{
    int row = tid >> 4;
    int c4  = (tid & 15) * 4;
    float x0 = x4.x*DNORM, x1 = x4.y*DNORM, x2 = x4.z*DNORM, x3 = x4.w*DNORM;
    float ss = x0*x0 + x1*x1 + x2*x2 + x3*x3;
    ss += __shfl_xor(ss, 1, 64);
    ss += __shfl_xor(ss, 2, 64);
    ss += __shfl_xor(ss, 4, 64);
    ss += __shfl_xor(ss, 8, 64);
    if ((tid & 15) == 0) diag_[row] = 0.5f * ss;
    int rt = row >> 4, lr = row & 15;
    int kk = c4 >> 5, c5 = c4 & 31;
    int fg, j0;
    if (c5 < 16){ fg = c5 >> 2; j0 = 0; } else { fg = (c5 - 16) >> 2; j0 = 4; }
    int f = kk*2 + rt;
    unsigned a01 = cvtpk(x0, x1), a23 = cvtpk(x2, x3);
    unsigned b01 = cvtpk(x0 - lo16f(a01), x1 - hi16f(a01));
    unsigned b23 = cvtpk(x2 - lo16f(a23), x3 - hi16f(a23));
    uint2v hv, lv;
    hv[0] = a01; hv[1] = a23;
    lv[0] = b01; lv[1] = b23;
    *(uint2v*)&Xh[f][fg*16 + lr][j0] = hv;
    *(uint2v*)&Xl[f][fg*16 + lr][j0] = lv;
}

static __device__ __forceinline__ void conv_write(const float* __restrict__ Xg, long r0,
        int tid, short (*Xh)[64][8], short (*Xl)[64][8], float* __restrict__ diag_)
{
    int row = tid >> 4;
    int c4  = (tid & 15) * 4;
    float4 x4 = *(const float4*)(Xg + (r0 + row)*64 + c4);
    conv_store(x4, tid, Xh, Xl, diag_);
}

// frag-major P load (coalesced b128) -- d_kernel, held in registers
static __device__ __forceinline__ void load_pfrags_fm(const unsigned short* __restrict__ Pfh,
        const unsigned short* __restrict__ Pfl, int w, int lane,
        bf16x8 (&Ph_r)[2][2], bf16x8 (&Pl_r)[2][2])
{
#pragma unroll
    for (int kk=0; kk<2; kk++)
#pragma unroll
      for (int mt=0; mt<2; mt++){
        int f = w*4 + kk*2 + mt;
        Ph_r[mt][kk] = *(const bf16x8*)(Pfh + (f*64 + lane)*8);
        Pl_r[mt][kk] = *(const bf16x8*)(Pfl + (f*64 + lane)*8);
      }
}

// dd GEMM from shared frags, register P-frags
static __device__ __forceinline__ void dd_frags(const short (*Xh)[64][8], const short (*Xl)[64][8],
        int lane, const bf16x8 (&Pfh)[2][2], const bf16x8 (&Pfl)[2][2], f32x4 (&acc)[2][2])
{
#pragma unroll
    for (int rt=0;rt<2;rt++)
#pragma unroll
      for (int mt=0;mt<2;mt++) acc[rt][mt] = f32x4{0.f,0.f,0.f,0.f};
#pragma unroll
    for (int kk=0;kk<2;kk++)
#pragma unroll
      for (int rt=0;rt<2;rt++){
        bf16x8 xh = *(const bf16x8*)&Xh[kk*2+rt][lane][0];
        bf16x8 xl = *(const bf16x8*)&Xl[kk*2+rt][lane][0];
#pragma unroll
        for (int mt=0;mt<2;mt++){
            acc[rt][mt] = MFMA16(xh, Pfh[mt][kk], acc[rt][mt]);
            acc[rt][mt] = MFMA16(xh, Pfl[mt][kk], acc[rt][mt]);
            acc[rt][mt] = MFMA16(xl, Pfh[mt][kk], acc[rt][mt]);
        }
      }
}

// dd GEMM, P-frags streamed from frag-major global planes (b_kernel path)
static __device__ __forceinline__ void dd_frags_g(const short (*Xh)[64][8], const short (*Xl)[64][8],
        int lane, int w, const unsigned short* __restrict__ Pfh, const unsigned short* __restrict__ Pfl,
        f32x4 (&acc)[2][2])
{
#pragma unroll
    for (int rr=0;rr<2;rr++)
#pragma unroll
      for (int mt=0;mt<2;mt++) acc[rr][mt] = f32x4{0.f,0.f,0.f,0.f};
#pragma unroll
    for (int kk=0;kk<2;kk++){
        bf16x8 ph[2], pl[2];
#pragma unroll
        for (int mt=0;mt<2;mt++){
            int f = w*4 + kk*2 + mt;
            ph[mt] = *(const bf16x8*)(Pfh + (f*64 + lane)*8);
            pl[mt] = *(const bf16x8*)(Pfl + (f*64 + lane)*8);
        }
#pragma unroll
        for (int rr=0;rr<2;rr++){
            bf16x8 xh = *(const bf16x8*)&Xh[kk*2+rr][lane][0];
            bf16x8 xl = *(const bf16x8*)&Xl[kk*2+rr][lane][0];
#pragma unroll
            for (int mt=0;mt<2;mt++){
                acc[rr][mt] = MFMA16(xh, ph[mt], acc[rr][mt]);
                acc[rr][mt] = MFMA16(xh, pl[mt], acc[rr][mt]);
                acc[rr][mt] = MFMA16(xl, ph[mt], acc[rr][mt]);
            }
        }
    }
}

// build hi/lo bf16 B-frag for one kt directly from f32 values (C-layout regs)
static __device__ __forceinline__ void sfrag(const f32x4 a, const f32x4 b, bf16x8& h, bf16x8& l){
    union U { bf16x8 v; unsigned u[4]; } H, L;
    H.u[0] = cvtpk(a[0], a[1]); H.u[1] = cvtpk(a[2], a[3]);
    H.u[2] = cvtpk(b[0], b[1]); H.u[3] = cvtpk(b[2], b[3]);
    L.u[0] = cvtpk(a[0] - lo16f(H.u[0]), a[1] - hi16f(H.u[0]));
    L.u[1] = cvtpk(a[2] - lo16f(H.u[1]), a[3] - hi16f(H.u[1]));
    L.u[2] = cvtpk(b[0] - lo16f(H.u[2]), b[1] - hi16f(H.u[2]));
    L.u[3] = cvtpk(b[2] - lo16f(H.u[3]), b[3] - hi16f(H.u[3]));
    h = H.v; l = L.v;
}

// inter partials over this wave's feature half (ft = rt*4 + ktl), both row-tiles
static __device__ __forceinline__ void inter_half(const unsigned* __restrict__ qf_,
        const f32x4 (&S)[8], int rt, int l15, int g, int xsw,
        f32x4 &Cp0, f32x4 &Cp1)
{
#pragma unroll
    for (int ktl=0; ktl<4; ktl++){
        int ft = rt*4 + ktl;
        bf16x8 sh, sl; sfrag(S[2*ktl], S[2*ktl+1], sh, sl);
        {
            int rowb = l15*256;                 // row-tile 0
            uint4 q0 = *(const uint4*)&qf_[rowb + ((ft*32 + g*4) ^ xsw)];
            uint4 q1 = *(const uint4*)&qf_[rowb + ((ft*32 + 16 + g*4) ^ xsw)];
            bf16x8 qh, ql; unpk(q0, q1, qh, ql);
            Cp0 = MFMA16(qh, sh, Cp0);
            Cp0 = MFMA16(qh, sl, Cp0);
            Cp0 = MFMA16(ql, sh, Cp0);
        }
        {
            int rowb = (16 + l15)*256;          // row-tile 1
            uint4 q0 = *(const uint4*)&qf_[rowb + ((ft*32 + g*4) ^ xsw)];
            uint4 q1 = *(const uint4*)&qf_[rowb + ((ft*32 + 16 + g*4) ^ xsw)];
            bf16x8 qh, ql; unpk(q0, q1, qh, ql);
            Cp1 = MFMA16(qh, sh, Cp1);
            Cp1 = MFMA16(qh, sl, Cp1);
            Cp1 = MFMA16(ql, sh, Cp1);
        }
    }
}

// ---------------- init: P -> bf16 hi/lo frag-major planes ----------------
__global__ __launch_bounds__(256) void init_p_kernel(const float* __restrict__ proj,
        unsigned short* __restrict__ Pfh, unsigned short* __restrict__ Pfl){
    int i = blockIdx.x*256 + threadIdx.x;   // 16384
    float x = proj[i];
    unsigned short h = f2bh(x);
    unsigned short l = f2bh(x - bh2f(h));
    // frag-major: i = m*64 + d
    int m = i >> 6, d = i & 63;
    int w = m >> 5, mt = (m >> 4) & 1, l15 = m & 15;
    int kk = d >> 5, r5 = d & 31;
    int half = r5 >> 4, g = (r5 & 15) >> 2, jj = r5 & 3;
    int f = w*4 + kk*2 + mt, lane = g*16 + l15, j = half*4 + jj;
    int o = (f*64 + lane)*8 + j;
    Pfh[o] = h; Pfl[o] = l;
}

// ---------------- kmax: global max of k's data_dash (hi-only is safe) ----------------
__global__ __launch_bounds__(256) void kmax_kernel(const float* __restrict__ k,
        const unsigned short* __restrict__ Pfh, unsigned* __restrict__ kmax_u){
    __shared__ float red[4];
    int tid = threadIdx.x;
    int lane = tid & 63, w = tid >> 6;
    int l15 = lane & 15, g = lane >> 4;
    long r0 = (long)blockIdx.x * 32;
    bf16x8 xh[2][2];  // [kk][rt]
#pragma unroll
    for (int kk=0;kk<2;kk++)
#pragma unroll
      for (int rt=0;rt<2;rt++){
        const float* rp = k + (r0 + rt*16 + l15)*64 + kk*32 + g*4;
        float4 a = *(const float4*)rp;
        float4 b = *(const float4*)(rp + 16);
        float xs[8] = {a.x,a.y,a.z,a.w,b.x,b.y,b.z,b.w};
#pragma unroll
        for (int j=0;j<8;j++) xh[kk][rt][j] = (short)f2bh(xs[j]*DNORM);
      }
    float mx = -1e30f;
#pragma unroll
    for (int mtl=0; mtl<4; mtl++){
        int mtile = w*4 + mtl;
        bf16x8 pf[2];
#pragma unroll
        for (int kk=0;kk<2;kk++){
            // frag-major: m = mtile*16+l15 -> f = (mtile>>1)*4 + kk*2 + (mtile&1)
            int f = (mtile >> 1)*4 + kk*2 + (mtile & 1);
            pf[kk] = *(const bf16x8*)(Pfh + (f*64 + lane)*8);
        }
        f32x4 acc[2] = {f32x4{0.f,0.f,0.f,0.f}, f32x4{0.f,0.f,0.f,0.f}};
#pragma unroll
        for (int kk=0;kk<2;kk++)
#pragma unroll
          for (int rt=0;rt<2;rt++)
            acc[rt] = MFMA16(xh[kk][rt], pf[kk], acc[rt]);
#pragma unroll
        for (int rt=0;rt<2;rt++)
#pragma unroll
          for (int i=0;i<4;i++) mx = fmaxf(mx, acc[rt][i]);
    }
#pragma unroll
    for (int d=1; d<64; d<<=1) mx = fmaxf(mx, __shfl_xor(mx, d, 64));
    if (lane == 0) red[w] = mx;
    __syncthreads();
    if (tid == 0){
        float m2 = fmaxf(fmaxf(red[0],red[1]), fmaxf(red[2],red[3]));
        atomicMax(kmax_u, mapf(m2));
    }
}

// ---------------- B: per-chunk states S = Kf^T V, z = sum Kf ----------------
__global__ __launch_bounds__(512, 2) void b_kernel(const float* __restrict__ k,
        const float* __restrict__ v,
        const unsigned short* __restrict__ Pfh, const unsigned short* __restrict__ Pfl,
        const unsigned* __restrict__ kmax_u, float* __restrict__ states,
        int CH, int nch){
    __shared__ short Xh[4][64][8], Xl[4][64][8];
    __shared__ unsigned kf_[256*32];     // [m][t] swizzled: m*32 + (t ^ ((m&7)<<2))
    __shared__ unsigned Vt_u[64][36];    // [e][t] packed hi/lo
    __shared__ float diagk_[32];
    int tid = threadIdx.x;
    int lane = tid & 63, w = tid >> 6;
    int l15 = lane & 15, g = lane >> 4;
    int cx = blockIdx.x, bh = blockIdx.y;
    int o = (cx == 0) ? 0 : CONDL + (cx-1)*CH;
    int nsub = ((cx == 0) ? CONDL : CH) >> 5;
    long rowbase = (long)bh * S_TOT + o;
    float kmax = unmapf(*kmax_u);
    int xsw = (l15 & 7) << 2;
    f32x4 Sacc[2][4];   // [mt][et]
#pragma unroll
    for (int mt=0;mt<2;mt++)
#pragma unroll
      for (int et=0;et<4;et++) Sacc[mt][et] = f32x4{0.f,0.f,0.f,0.f};
    float zacc[2] = {0.f, 0.f};

    // T14 prefetch: per-thread fixed offsets within a 32-row subtile
    const float* kptr = k + rowbase*64 + (tid >> 4)*64 + (tid & 15)*4;
    const float* vptr = v + rowbase*64 + (tid >> 4)*64 + (tid & 15)*4;
    float4 kpre = *(const float4*)kptr;
    float4 vpre = *(const float4*)vptr;

    for (int st = 0; st < nsub; st++){
        long r0 = rowbase + st*32;
        // P0: k conversion (prefetched) + V staging (prefetched)
        conv_store(kpre, tid, Xh, Xl, diagk_);
        {
            int e4 = (tid & 15)*4;
            int t = tid >> 4;
            Vt_u[e4+0][t] = packhl(vpre.x);
            Vt_u[e4+1][t] = packhl(vpre.y);
            Vt_u[e4+2][t] = packhl(vpre.z);
            Vt_u[e4+3][t] = packhl(vpre.w);
        }
        __syncthreads();
        // P1: dd (P-frags streamed from L2-hot global) + kf finalize
        f32x4 dk[2][2];
        dd_frags_g(Xh, Xl, lane, w, Pfh, Pfl, dk);
        float zd0 = 0.f, zd1 = 0.f;
#pragma unroll
        for (int rr=0;rr<2;rr++){
            float dg0 = diagk_[rr*16 + g*4 + 0];
            float dg1 = diagk_[rr*16 + g*4 + 1];
            float dg2 = diagk_[rr*16 + g*4 + 2];
            float dg3 = diagk_[rr*16 + g*4 + 3];
#pragma unroll
            for (int mt=0;mt<2;mt++){
                float k0 = RATIO * (__expf(dk[rr][mt][0] - dg0 - kmax) + KEPS);
                float k1 = RATIO * (__expf(dk[rr][mt][1] - dg1 - kmax) + KEPS);
                float k2 = RATIO * (__expf(dk[rr][mt][2] - dg2 - kmax) + KEPS);
                float k3 = RATIO * (__expf(dk[rr][mt][3] - dg3 - kmax) + KEPS);
                if (mt == 0) zd0 += k0+k1+k2+k3; else zd1 += k0+k1+k2+k3;
                uint4 kw;
                kw.x = packhl(k0); kw.y = packhl(k1);
                kw.z = packhl(k2); kw.w = packhl(k3);
                int m = w*32 + mt*16 + l15;
                *(uint4*)&kf_[m*32 + ((rr*16 + g*4) ^ xsw)] = kw;
            }
        }
        zd0 += __shfl_xor(zd0, 16, 64); zd0 += __shfl_xor(zd0, 32, 64);
        zd1 += __shfl_xor(zd1, 16, 64); zd1 += __shfl_xor(zd1, 32, 64);
        zacc[0] += zd0; zacc[1] += zd1;
        __syncthreads();
        // P2: prefetch st+1 (covered by delta MFMAs); state delta MFMAs
        if (st + 1 < nsub){
            kpre = *(const float4*)(kptr + (st+1)*2048);
            vpre = *(const float4*)(vptr + (st+1)*2048);
        }
#pragma unroll
        for (int mt=0;mt<2;mt++){
            int m = (w*2 + mt)*16 + l15;
            uint4 kp0 = *(const uint4*)&kf_[m*32 + ((g*4) ^ xsw)];
            uint4 kp1 = *(const uint4*)&kf_[m*32 + ((16 + g*4) ^ xsw)];
            bf16x8 kh, kl; unpk(kp0, kp1, kh, kl);
#pragma unroll
            for (int et=0;et<4;et++){
                const uint4* vp0 = (const uint4*)&Vt_u[et*16 + l15][g*4];
                const uint4* vp1 = (const uint4*)&Vt_u[et*16 + l15][16 + g*4];
                bf16x8 vh, vl; unpk(*vp0, *vp1, vh, vl);
                Sacc[mt][et] = MFMA16(kh, vh, Sacc[mt][et]);
                Sacc[mt][et] = MFMA16(kh, vl, Sacc[mt][et]);
                Sacc[mt][et] = MFMA16(kl, vh, Sacc[mt][et]);
            }
        }
        __syncthreads();
    }
    // write state slot
    float* Sg = states + ((long)(bh*nch + cx)) * SLOT_F;
#pragma unroll
    for (int mt=0;mt<2;mt++)
#pragma unroll
      for (int et=0;et<4;et++)
#pragma unroll
        for (int i=0;i<4;i++)
            Sg[((w*2+mt)*16 + g*4 + i)*64 + et*16 + l15] = Sacc[mt][et][i];
    if (g == 0){
        Sg[16384 + w*32 + l15]      = zacc[0];
        Sg[16384 + w*32 + 16 + l15] = zacc[1];
    }
}

// ---------------- C: exclusive scan over chunk slots ----------------
__global__ __launch_bounds__(256) void scan_kernel(float* __restrict__ states, int nch){
    int idx = blockIdx.x*256 + threadIdx.x;
    if (idx >= SLOT_F) return;
    float* base = states + (long)blockIdx.y * nch * SLOT_F + idx;
    if (nch == 32){
        // hoist all 32 strided loads into registers (all in flight), then store
        float vals[32];
#pragma unroll
        for (int c = 0; c < 32; c++) vals[c] = base[(long)c * SLOT_F];
        float prev = 0.f;
#pragma unroll
        for (int c = 0; c < 32; c++){
            base[(long)c * SLOT_F] = prev;
            prev += vals[c];
        }
    } else {
        float prev = 0.f;
        for (int c = 0; c < nch; c++){
            float t = base[(long)c * SLOT_F];
            base[(long)c * SLOT_F] = prev;
            prev += t;
        }
    }
}

// ---------------- D: outputs (split reg state, kfT tile, 106.75KB LDS) ----------------
__global__ __launch_bounds__(512, 1) void d_kernel(const float* __restrict__ q,
        const float* __restrict__ k, const float* __restrict__ v,
        const unsigned short* __restrict__ Pfh, const unsigned short* __restrict__ Pfl,
        const unsigned* __restrict__ kmax_u, const float* __restrict__ states,
        float* __restrict__ out, int CH, int nch){
    // LDS map (uints), total = 26,688 uints = 106,752 B (1 block/CU):
    //  [0,8192)      qf  [32][256]  row*256 + (m ^ ((row&7)<<2)), packed hi/lo
    //  [8192,16384)  kf  [256][32]  m*32 + (t ^ ((m&7)<<2)), packed hi/lo
    //                  head overlay (live P0-P2 only): dgq[32] f32, rmax[32] u32
    //  [16384,24576) kfT [32][256]  t*256 + (m ^ ((t&7)<<2))  (A-prod B-operand)
    //  [24576,26624) X frags (P0-P3) / A[32][32] + xch (P4-P7)
    //  [26624,26656) den f32[32]
    //  [26656,26688) dgk f32[32]
    __shared__ __attribute__((aligned(16))) unsigned lds_[26688];
    unsigned* qf_  = lds_;
    unsigned* kf_  = lds_ + 8192;
    unsigned* kfT_ = lds_ + 16384;
    unsigned* XA_  = lds_ + 24576;
    float*   den_ = (float*)(lds_ + 26624);
    float*   dgk_ = (float*)(lds_ + 26656);
    float*   dgq_ = (float*)kf_;
    unsigned* rmax_ = kf_ + 32;
    unsigned* A_ = XA_;
    float*   xch_ = (float*)(XA_ + 1024);
    short (*Xh)[64][8] = (short (*)[64][8])XA_;
    short (*Xl)[64][8] = (short (*)[64][8])(XA_ + 1024);

    int tid = threadIdx.x;
    int lane = tid & 63, w = tid >> 6;
    int l15 = lane & 15, g = lane >> 4;
    int et = w & 3, rt = w >> 2;
    bool owner = (rt == 0);     // owners: A at P4, inter at P6, output rows 0..15
    int cx = blockIdx.x, bh = blockIdx.y;
    bool causal = (cx > 0);
    int o = causal ? (CONDL + (cx-1)*CH) : 0;
    int nsub = (causal ? CH : CONDL) >> 5;
    float epsv = causal ? AEPS : 0.f;
    int slot = causal ? cx : 1;
    const float* Sg = states + ((long)(bh*nch + slot)) * SLOT_F;
    long rowbase = (long)bh * S_TOT + o;
    float kmax = unmapf(*kmax_u);
    int xsw = (l15 & 7) << 2;   // row/m/t & 7 == l15 & 7 for all our frag rows

    // P-fragments in registers (coalesced frag-major load, once)
    bf16x8 Ph_r[2][2], Pl_r[2][2];
    load_pfrags_fm(Pfh, Pfl, w, lane, Ph_r, Pl_r);

    // split state -> registers: wave (rt,et) holds features rt*128..+127:
    // S[Mtl][i] = S_mat[(rt*8+Mtl)*16 + g*4 + i][et*16 + l15]
    f32x4 S[8];
#pragma unroll
    for (int Mtl=0; Mtl<8; Mtl++){
#pragma unroll
        for (int i=0;i<4;i++)
            S[Mtl][i] = Sg[((rt*8 + Mtl)*16 + g*4 + i)*64 + et*16 + l15];
    }
    float z0 = Sg[16384 + w*32 + l15];
    float z1 = Sg[16384 + w*32 + 16 + l15];

    // prefetch pointers (per-thread fixed offsets within a 32-row subtile)
    const float* qptr = q + rowbase*64 + (tid >> 4)*64 + (tid & 15)*4;
    const float* kptr = k + rowbase*64 + (tid >> 4)*64 + (tid & 15)*4;
    float4 qpre = *(const float4*)qptr;

    for (int st = 0; st < nsub; st++){
        long r0 = rowbase + st*32;
        // ---- P0: k prefetch issue; q conversion + init ----
        float4 kpre;
        if (causal) kpre = *(const float4*)(kptr + st*2048);
        conv_store(qpre, tid, Xh, Xl, dgq_);
        if (tid < 32){ den_[tid] = 0.f; rmax_[tid] = 0u; }
        __syncthreads();                      // B1
        // ---- P1: dd_q + rowmax atomics ----
        f32x4 dq[2][2];
        dd_frags(Xh, Xl, lane, Ph_r, Pl_r, dq);
#pragma unroll
        for (int rr=0;rr<2;rr++)
#pragma unroll
          for (int i=0;i<4;i++){
            float mx = fmaxf(dq[rr][0][i], dq[rr][1][i]);
            mx = fmaxf(mx, __shfl_xor(mx, 1, 64));
            mx = fmaxf(mx, __shfl_xor(mx, 2, 64));
            mx = fmaxf(mx, __shfl_xor(mx, 4, 64));
            mx = fmaxf(mx, __shfl_xor(mx, 8, 64));
            if (l15 == 0) atomicMax(&rmax_[rr*16 + g*4 + i], mapf(mx));
          }
        __syncthreads();                      // B2
        // ---- P2: qf finalize + den(z) || k conversion (prefetched) ----
        {
#pragma unroll
            for (int rr=0;rr<2;rr++)
#pragma unroll
              for (int i=0;i<4;i++){
                int row = rr*16 + g*4 + i;
                float dgv = dgq_[row];
                float rm = unmapf(rmax_[row]);
                float s1p = 0.f, s2p = 0.f;
#pragma unroll
                for (int mt=0;mt<2;mt++){
                    float qv = RATIO * (__expf(dq[rr][mt][i] - dgv - rm) + KEPS);
                    s1p += qv;
                    s2p += qv * (mt ? z1 : z0);
                    int m = w*32 + mt*16 + l15;
                    qf_[row*256 + (m ^ ((row & 7) << 2))] = packhl(qv);
                }
#pragma unroll
                for (int d2=1; d2<16; d2<<=1){
                    s1p += __shfl_xor(s1p, d2, 64);
                    s2p += __shfl_xor(s2p, d2, 64);
                }
                if (l15 == 0) atomicAdd(&den_[row], s2p + epsv * s1p);
              }
        }
        if (causal) conv_store(kpre, tid, Xh, Xl, dgk_);
        __syncthreads();                      // B3
        // ---- P3: dd_k + kf/kfT finalize (b128/b32 stores) + z update ----
        if (causal){
            f32x4 dk[2][2];
            dd_frags(Xh, Xl, lane, Ph_r, Pl_r, dk);
            float zd0 = 0.f, zd1 = 0.f;
#pragma unroll
            for (int rr=0;rr<2;rr++){
                float dg0 = dgk_[rr*16 + g*4 + 0];
                float dg1 = dgk_[rr*16 + g*4 + 1];
                float dg2 = dgk_[rr*16 + g*4 + 2];
                float dg3 = dgk_[rr*16 + g*4 + 3];
#pragma unroll
                for (int mt=0;mt<2;mt++){
                    float k0 = RATIO * (__expf(dk[rr][mt][0] - dg0 - kmax) + KEPS);
                    float k1 = RATIO * (__expf(dk[rr][mt][1] - dg1 - kmax) + KEPS);
                    float k2 = RATIO * (__expf(dk[rr][mt][2] - dg2 - kmax) + KEPS);
                    float k3 = RATIO * (__expf(dk[rr][mt][3] - dg3 - kmax) + KEPS);
                    if (mt == 0) zd0 += k0+k1+k2+k3; else zd1 += k0+k1+k2+k3;
                    uint4 kw;
                    kw.x = packhl(k0); kw.y = packhl(k1);
                    kw.z = packhl(k2); kw.w = packhl(k3);
                    int m = w*32 + mt*16 + l15;
                    *(uint4*)&kf_[m*32 + ((rr*16 + g*4) ^ xsw)] = kw;
                    // kfT: same values, transposed tile (qf-identical pattern)
                    int t0r = rr*16 + g*4;
                    kfT_[(t0r+0)*256 + (m ^ ((((g*4)+0) & 7) << 2))] = kw.x;
                    kfT_[(t0r+1)*256 + (m ^ ((((g*4)+1) & 7) << 2))] = kw.y;
                    kfT_[(t0r+2)*256 + (m ^ ((((g*4)+2) & 7) << 2))] = kw.z;
                    kfT_[(t0r+3)*256 + (m ^ ((((g*4)+3) & 7) << 2))] = kw.w;
                }
            }
            zd0 += __shfl_xor(zd0, 16, 64); zd0 += __shfl_xor(zd0, 32, 64);
            zd1 += __shfl_xor(zd1, 16, 64); zd1 += __shfl_xor(zd1, 32, 64);
            z0 += zd0; z1 += zd1;
        }
        __syncthreads();                      // B4
        // ---- P4: q prefetch (st+1); owners: A-product; rt=1: inter + slot ----
        if (st + 1 < nsub) qpre = *(const float4*)(qptr + (st+1)*2048);
        float vv[8];
        if (causal){
            const float* vb = v + r0*64 + et*16 + l15;
#pragma unroll
            for (int p2=0;p2<2;p2++)
#pragma unroll
              for (int j=0;j<4;j++)
                vv[p2*4+j] = vb[(p2*16 + g*4 + j)*64];
        }
        f32x4 Cp0{0.f,0.f,0.f,0.f}, Cp1{0.f,0.f,0.f,0.f};
        if (owner){
            if (causal){
                int ar = et >> 1, tt = et & 1;
                int t = tt*16 + l15;
                int tb = t*256;
                f32x4 c{0.f,0.f,0.f,0.f};
                int rowb = (ar*16 + l15)*256;
                __builtin_amdgcn_s_setprio(1);
#pragma unroll
                for (int kt=0;kt<8;kt++){
                    uint4 q0 = *(const uint4*)&qf_[rowb + ((kt*32 + g*4) ^ xsw)];
                    uint4 q1 = *(const uint4*)&qf_[rowb + ((kt*32 + 16 + g*4) ^ xsw)];
                    bf16x8 qh, ql; unpk(q0, q1, qh, ql);
                    uint4 kt0 = *(const uint4*)&kfT_[tb + ((kt*32 + g*4) ^ xsw)];
                    uint4 kt1 = *(const uint4*)&kfT_[tb + ((kt*32 + 16 + g*4) ^ xsw)];
                    bf16x8 kh, kl; unpk(kt0, kt1, kh, kl);
                    c = MFMA16(qh, kh, c);
                    c = MFMA16(qh, kl, c);
                    c = MFMA16(ql, kh, c);
                }
                __builtin_amdgcn_s_setprio(0);
#pragma unroll
                for (int i=0;i<4;i++){
                    int r = ar*16 + g*4 + i;
                    float a = (t <= r) ? c[i] : 0.f;
                    A_[r*32 + (t ^ ((r & 7) << 2))] = packhl(a);
                    float p = a;
                    p += __shfl_xor(p, 1, 64);
                    p += __shfl_xor(p, 2, 64);
                    p += __shfl_xor(p, 4, 64);
                    p += __shfl_xor(p, 8, 64);
                    if (l15 == 0) atomicAdd(&den_[r], p);
                }
            }
        } else {
            __builtin_amdgcn_s_setprio(1);
            inter_half(qf_, S, rt, l15, g, xsw, Cp0, Cp1);
            __builtin_amdgcn_s_setprio(0);
            // away partial (row-tile 0) -> slot et; keep Cp1 (our quadrant)
            *(float4*)&xch_[(et*64 + lane)*4] = float4{Cp0[0],Cp0[1],Cp0[2],Cp0[3]};
        }
        __syncthreads();                      // B5
        // ---- P6: owners: inter + partner-add + slot write; all: delta + intra ----
        if (owner){
            __builtin_amdgcn_s_setprio(1);
            inter_half(qf_, S, rt, l15, g, xsw, Cp0, Cp1);
            __builtin_amdgcn_s_setprio(0);
            float4 pp = *(const float4*)&xch_[(et*64 + lane)*4];
            Cp0[0] += pp.x; Cp0[1] += pp.y; Cp0[2] += pp.z; Cp0[3] += pp.w;
            // away partial (row-tile 1) for partner
            *(float4*)&xch_[(et*64 + lane)*4] = float4{Cp1[0],Cp1[1],Cp1[2],Cp1[3]};
        }
        if (causal){
            f32x4 va{vv[0], vv[1], vv[2], vv[3]};
            f32x4 vb2{vv[4], vv[5], vv[6], vv[7]};
            bf16x8 vh, vl; sfrag(va, vb2, vh, vl);
            // delta over own feature half: S += Kf^T V
            __builtin_amdgcn_s_setprio(1);
#pragma unroll
            for (int Mtl=0;Mtl<8;Mtl++){
                int mb = ((rt*8 + Mtl)*16 + l15)*32;
                uint4 k0 = *(const uint4*)&kf_[mb + ((g*4) ^ xsw)];
                uint4 k1 = *(const uint4*)&kf_[mb + ((16 + g*4) ^ xsw)];
                bf16x8 kh, kl; unpk(k0, k1, kh, kl);
                S[Mtl] = MFMA16(kh, vh, S[Mtl]);
                S[Mtl] = MFMA16(kh, vl, S[Mtl]);
                S[Mtl] = MFMA16(kl, vh, S[Mtl]);
            }
            __builtin_amdgcn_s_setprio(0);
            // intra: A @ V for this wave's output row-tile (rt)
            int rb = (rt*16 + l15)*32;
            uint4 a0 = *(const uint4*)&A_[rb + ((g*4) ^ xsw)];
            uint4 a1 = *(const uint4*)&A_[rb + ((16 + g*4) ^ xsw)];
            bf16x8 ah, al; unpk(a0, a1, ah, al);
            f32x4& Ct = owner ? Cp0 : Cp1;
            Ct = MFMA16(ah, vh, Ct);
            Ct = MFMA16(ah, vl, Ct);
            Ct = MFMA16(al, vh, Ct);
        }
        if (owner){
#pragma unroll
            for (int i=0;i<4;i++){
                int row = g*4 + i;
                out[(r0 + row)*64 + et*16 + l15] = Cp0[i] / den_[row];
            }
        }
        __syncthreads();                      // B6
        // ---- P7: rt=1 waves: partner-add + output rows 16..31 ----
        if (!owner){
            float4 pp = *(const float4*)&xch_[(et*64 + lane)*4];
            Cp1[0] += pp.x; Cp1[1] += pp.y; Cp1[2] += pp.z; Cp1[3] += pp.w;
#pragma unroll
            for (int i=0;i<4;i++){
                int row = 16 + g*4 + i;
                out[(r0 + row)*64 + et*16 + l15] = Cp1[i] / den_[row];
            }
        }
        __syncthreads();                      // B7 (end)
    }
}

extern "C" void kernel_launch(void* const* d_in, const int* in_sizes, int n_in,
                              void* d_out, int out_size, void* d_ws, size_t ws_size,
                              hipStream_t stream) {
    const float* q = (const float*)d_in[0];
    const float* k = (const float*)d_in[1];
    const float* v = (const float*)d_in[2];
    const float* proj = (const float*)d_in[3];
    float* out = (float*)d_out;

    unsigned* kmax_u = (unsigned*)d_ws;
    // legacy flat Ph/Pl region at [256, 256+64KB) left unused
    unsigned short* Pfh = (unsigned short*)((char*)d_ws + 256 + 65536);
    unsigned short* Pfl = Pfh + 16384;
    float* states = (float*)((char*)d_ws + 256 + 131072);
    size_t fixed = 256 + 131072;

    int CH, nch;
    size_t need128 = fixed + (size_t)64 * 32 * SLOT_F * 4;
    if (ws_size >= need128){ CH = 128; nch = 32; }
    else                  { CH = 992; nch = 5;  }

    hipMemsetAsync(d_ws, 0, 4, stream);
    hipLaunchKernelGGL(init_p_kernel, dim3(64), dim3(256), 0, stream, proj, Pfh, Pfl);
    hipLaunchKernelGGL(kmax_kernel, dim3(8192), dim3(256), 0, stream, k, Pfh, kmax_u);
    hipLaunchKernelGGL(b_kernel, dim3(nch, 64), dim3(512), 0, stream, k, v, Pfh, Pfl, kmax_u, states, CH, nch);
    hipLaunchKernelGGL(scan_kernel, dim3(65, 64), dim3(256), 0, stream, states, nch);
    hipLaunchKernelGGL(d_kernel, dim3(nch, 64), dim3(512), 0, stream, q, k, v, Pfh, Pfl, kmax_u, states, out, CH, nch);
}

// Round 15
// 577.351 us; speedup vs baseline: 1.4986x; 1.0051x over previous
//
#include <hip/hip_runtime.h>
#include <math.h>

// Performer FAVOR+ causal linear attention, MI355X.
// B=4 H=16 S=4096 D=64 M=256 features, COND=128 non-causal prefix.
// v16 = v15 (580us) + T5 s_setprio(1) around b_kernel's two MFMA clusters
// (dd at P1, delta at P2). b now runs 2 blocks/CU (v13) with blocks at
// DIFFERENT phases -> wave-role diversity, the regime where setprio measured
// +4-7% (multi-block attn); it was neutral only in lockstep single-block
// schedules (v10 d experiment). Everything else byte-identical to v15.
// History: v13 b streams P-frags from L2 (frees 32 regs -> 2 blocks/CU, -45us);
// v14 kmax frag-major loads + scan load-hoist (-6us); v15 b T14 prefetch (-8us).
// d_kernel structurally pinned at 8 waves/CU (128 arch + 64 acc regs, 107KB
// LDS); rounds 5-11 exhausted d-side levers.
// ws: [0..4) kmax (mapped uint), [256..) [unused 64KB legacy Ph/Pl region],
//     Pfm_h/Pfm_l frag-major bf16 planes (32KB each),
//     then chunk states [64][nslot][256*64 + 256] f32.

#define S_TOT 4096
#define CONDL 128
#define SLOT_F 16640
#define RATIO 0.0625f
#define DNORM 0.35355339059327378f
#define KEPS  1e-4f
#define AEPS  1e-6f

typedef __attribute__((ext_vector_type(8))) short bf16x8;
typedef __attribute__((ext_vector_type(2))) unsigned uint2v;
typedef __attribute__((ext_vector_type(4))) float f32x4;

#define MFMA16(a,b,c) __builtin_amdgcn_mfma_f32_16x16x32_bf16(a,b,c,0,0,0)

static __device__ __forceinline__ unsigned cvtpk(float a, float b){
    unsigned r;
    asm("v_cvt_pk_bf16_f32 %0, %1, %2" : "=v"(r) : "v"(a), "v"(b));
    return r;
}
static __device__ __forceinline__ float lo16f(unsigned u){ return __uint_as_float(u << 16); }
static __device__ __forceinline__ float hi16f(unsigned u){ return __uint_as_float(u & 0xffff0000u); }

static __device__ __forceinline__ unsigned short f2bh(float x){
    unsigned u = __float_as_uint(x);
    u += 0x7fffu + ((u >> 16) & 1u);
    return (unsigned short)(u >> 16);
}
static __device__ __forceinline__ float bh2f(unsigned short h){
    return __uint_as_float((unsigned)h << 16);
}
// pack hi/lo bf16 of x into one dword (hi in low16, residual-lo in high16)
static __device__ __forceinline__ unsigned packhl(float x){
    unsigned u1 = cvtpk(x, x);
    float r = x - lo16f(u1);
    return cvtpk(x, r);
}
// two uint4 (halves k=[0..15],[16..31] of this lane's 4+4 elems) -> hi/lo frags
static __device__ __forceinline__ void unpk(const uint4 a, const uint4 b, bf16x8& h, bf16x8& l){
    h[0]=(short)a.x; h[1]=(short)a.y; h[2]=(short)a.z; h[3]=(short)a.w;
    h[4]=(short)b.x; h[5]=(short)b.y; h[6]=(short)b.z; h[7]=(short)b.w;
    l[0]=(short)(a.x>>16); l[1]=(short)(a.y>>16); l[2]=(short)(a.z>>16); l[3]=(short)(a.w>>16);
    l[4]=(short)(b.x>>16); l[5]=(short)(b.y>>16); l[6]=(short)(b.z>>16); l[7]=(short)(b.w>>16);
}
static __device__ __forceinline__ unsigned mapf(float x){
    unsigned u = __float_as_uint(x);
    return (u & 0x80000000u) ? ~u : (u | 0x80000000u);
}
static __device__ __forceinline__ float unmapf(unsigned u){
    return __uint_as_float((u & 0x80000000u) ? (u ^ 0x80000000u) : ~u);
}

// Convert a pre-loaded 32x64 f32 tile row-quad into frag-major hi/lo bf16
// planes + row diag (cooperative across 512 threads).
static __device__ __forceinline__ void conv_store(float4 x4, int tid,
        short (*Xh)[64][8], short (*Xl)[64][8], float* __restrict__ diag_)
{
    int row = tid >> 4;
    int c4  = (tid & 15) * 4;
    float x0 = x4.x*DNORM, x1 = x4.y*DNORM, x2 = x4.z*DNORM, x3 = x4.w*DNORM;
    float ss = x0*x0 + x1*x1 + x2*x2 + x3*x3;
    ss += __shfl_xor(ss, 1, 64);
    ss += __shfl_xor(ss, 2, 64);
    ss += __shfl_xor(ss, 4, 64);
    ss += __shfl_xor(ss, 8, 64);
    if ((tid & 15) == 0) diag_[row] = 0.5f * ss;
    int rt = row >> 4, lr = row & 15;
    int kk = c4 >> 5, c5 = c4 & 31;
    int fg, j0;
    if (c5 < 16){ fg = c5 >> 2; j0 = 0; } else { fg = (c5 - 16) >> 2; j0 = 4; }
    int f = kk*2 + rt;
    unsigned a01 = cvtpk(x0, x1), a23 = cvtpk(x2, x3);
    unsigned b01 = cvtpk(x0 - lo16f(a01), x1 - hi16f(a01));
    unsigned b23 = cvtpk(x2 - lo16f(a23), x3 - hi16f(a23));
    uint2v hv, lv;
    hv[0] = a01; hv[1] = a23;
    lv[0] = b01; lv[1] = b23;
    *(uint2v*)&Xh[f][fg*16 + lr][j0] = hv;
    *(uint2v*)&Xl[f][fg*16 + lr][j0] = lv;
}

static __device__ __forceinline__ void conv_write(const float* __restrict__ Xg, long r0,
        int tid, short (*Xh)[64][8], short (*Xl)[64][8], float* __restrict__ diag_)
{
    int row = tid >> 4;
    int c4  = (tid & 15) * 4;
    float4 x4 = *(const float4*)(Xg + (r0 + row)*64 + c4);
    conv_store(x4, tid, Xh, Xl, diag_);
}

// frag-major P load (coalesced b128) -- d_kernel, held in registers
static __device__ __forceinline__ void load_pfrags_fm(const unsigned short* __restrict__ Pfh,
        const unsigned short* __restrict__ Pfl, int w, int lane,
        bf16x8 (&Ph_r)[2][2], bf16x8 (&Pl_r)[2][2])
{
#pragma unroll
    for (int kk=0; kk<2; kk++)
#pragma unroll
      for (int mt=0; mt<2; mt++){
        int f = w*4 + kk*2 + mt;
        Ph_r[mt][kk] = *(const bf16x8*)(Pfh + (f*64 + lane)*8);
        Pl_r[mt][kk] = *(const bf16x8*)(Pfl + (f*64 + lane)*8);
      }
}

// dd GEMM from shared frags, register P-frags
static __device__ __forceinline__ void dd_frags(const short (*Xh)[64][8], const short (*Xl)[64][8],
        int lane, const bf16x8 (&Pfh)[2][2], const bf16x8 (&Pfl)[2][2], f32x4 (&acc)[2][2])
{
#pragma unroll
    for (int rt=0;rt<2;rt++)
#pragma unroll
      for (int mt=0;mt<2;mt++) acc[rt][mt] = f32x4{0.f,0.f,0.f,0.f};
#pragma unroll
    for (int kk=0;kk<2;kk++)
#pragma unroll
      for (int rt=0;rt<2;rt++){
        bf16x8 xh = *(const bf16x8*)&Xh[kk*2+rt][lane][0];
        bf16x8 xl = *(const bf16x8*)&Xl[kk*2+rt][lane][0];
#pragma unroll
        for (int mt=0;mt<2;mt++){
            acc[rt][mt] = MFMA16(xh, Pfh[mt][kk], acc[rt][mt]);
            acc[rt][mt] = MFMA16(xh, Pfl[mt][kk], acc[rt][mt]);
            acc[rt][mt] = MFMA16(xl, Pfh[mt][kk], acc[rt][mt]);
        }
      }
}

// dd GEMM, P-frags streamed from frag-major global planes (b_kernel path)
static __device__ __forceinline__ void dd_frags_g(const short (*Xh)[64][8], const short (*Xl)[64][8],
        int lane, int w, const unsigned short* __restrict__ Pfh, const unsigned short* __restrict__ Pfl,
        f32x4 (&acc)[2][2])
{
#pragma unroll
    for (int rr=0;rr<2;rr++)
#pragma unroll
      for (int mt=0;mt<2;mt++) acc[rr][mt] = f32x4{0.f,0.f,0.f,0.f};
#pragma unroll
    for (int kk=0;kk<2;kk++){
        bf16x8 ph[2], pl[2];
#pragma unroll
        for (int mt=0;mt<2;mt++){
            int f = w*4 + kk*2 + mt;
            ph[mt] = *(const bf16x8*)(Pfh + (f*64 + lane)*8);
            pl[mt] = *(const bf16x8*)(Pfl + (f*64 + lane)*8);
        }
#pragma unroll
        for (int rr=0;rr<2;rr++){
            bf16x8 xh = *(const bf16x8*)&Xh[kk*2+rr][lane][0];
            bf16x8 xl = *(const bf16x8*)&Xl[kk*2+rr][lane][0];
#pragma unroll
            for (int mt=0;mt<2;mt++){
                acc[rr][mt] = MFMA16(xh, ph[mt], acc[rr][mt]);
                acc[rr][mt] = MFMA16(xh, pl[mt], acc[rr][mt]);
                acc[rr][mt] = MFMA16(xl, ph[mt], acc[rr][mt]);
            }
        }
    }
}

// build hi/lo bf16 B-frag for one kt directly from f32 values (C-layout regs)
static __device__ __forceinline__ void sfrag(const f32x4 a, const f32x4 b, bf16x8& h, bf16x8& l){
    union U { bf16x8 v; unsigned u[4]; } H, L;
    H.u[0] = cvtpk(a[0], a[1]); H.u[1] = cvtpk(a[2], a[3]);
    H.u[2] = cvtpk(b[0], b[1]); H.u[3] = cvtpk(b[2], b[3]);
    L.u[0] = cvtpk(a[0] - lo16f(H.u[0]), a[1] - hi16f(H.u[0]));
    L.u[1] = cvtpk(a[2] - lo16f(H.u[1]), a[3] - hi16f(H.u[1]));
    L.u[2] = cvtpk(b[0] - lo16f(H.u[2]), b[1] - hi16f(H.u[2]));
    L.u[3] = cvtpk(b[2] - lo16f(H.u[3]), b[3] - hi16f(H.u[3]));
    h = H.v; l = L.v;
}

// inter partials over this wave's feature half (ft = rt*4 + ktl), both row-tiles
static __device__ __forceinline__ void inter_half(const unsigned* __restrict__ qf_,
        const f32x4 (&S)[8], int rt, int l15, int g, int xsw,
        f32x4 &Cp0, f32x4 &Cp1)
{
#pragma unroll
    for (int ktl=0; ktl<4; ktl++){
        int ft = rt*4 + ktl;
        bf16x8 sh, sl; sfrag(S[2*ktl], S[2*ktl+1], sh, sl);
        {
            int rowb = l15*256;                 // row-tile 0
            uint4 q0 = *(const uint4*)&qf_[rowb + ((ft*32 + g*4) ^ xsw)];
            uint4 q1 = *(const uint4*)&qf_[rowb + ((ft*32 + 16 + g*4) ^ xsw)];
            bf16x8 qh, ql; unpk(q0, q1, qh, ql);
            Cp0 = MFMA16(qh, sh, Cp0);
            Cp0 = MFMA16(qh, sl, Cp0);
            Cp0 = MFMA16(ql, sh, Cp0);
        }
        {
            int rowb = (16 + l15)*256;          // row-tile 1
            uint4 q0 = *(const uint4*)&qf_[rowb + ((ft*32 + g*4) ^ xsw)];
            uint4 q1 = *(const uint4*)&qf_[rowb + ((ft*32 + 16 + g*4) ^ xsw)];
            bf16x8 qh, ql; unpk(q0, q1, qh, ql);
            Cp1 = MFMA16(qh, sh, Cp1);
            Cp1 = MFMA16(qh, sl, Cp1);
            Cp1 = MFMA16(ql, sh, Cp1);
        }
    }
}

// ---------------- init: P -> bf16 hi/lo frag-major planes ----------------
__global__ __launch_bounds__(256) void init_p_kernel(const float* __restrict__ proj,
        unsigned short* __restrict__ Pfh, unsigned short* __restrict__ Pfl){
    int i = blockIdx.x*256 + threadIdx.x;   // 16384
    float x = proj[i];
    unsigned short h = f2bh(x);
    unsigned short l = f2bh(x - bh2f(h));
    // frag-major: i = m*64 + d
    int m = i >> 6, d = i & 63;
    int w = m >> 5, mt = (m >> 4) & 1, l15 = m & 15;
    int kk = d >> 5, r5 = d & 31;
    int half = r5 >> 4, g = (r5 & 15) >> 2, jj = r5 & 3;
    int f = w*4 + kk*2 + mt, lane = g*16 + l15, j = half*4 + jj;
    int o = (f*64 + lane)*8 + j;
    Pfh[o] = h; Pfl[o] = l;
}

// ---------------- kmax: global max of k's data_dash (hi-only is safe) ----------------
__global__ __launch_bounds__(256) void kmax_kernel(const float* __restrict__ k,
        const unsigned short* __restrict__ Pfh, unsigned* __restrict__ kmax_u){
    __shared__ float red[4];
    int tid = threadIdx.x;
    int lane = tid & 63, w = tid >> 6;
    int l15 = lane & 15, g = lane >> 4;
    long r0 = (long)blockIdx.x * 32;
    bf16x8 xh[2][2];  // [kk][rt]
#pragma unroll
    for (int kk=0;kk<2;kk++)
#pragma unroll
      for (int rt=0;rt<2;rt++){
        const float* rp = k + (r0 + rt*16 + l15)*64 + kk*32 + g*4;
        float4 a = *(const float4*)rp;
        float4 b = *(const float4*)(rp + 16);
        float xs[8] = {a.x,a.y,a.z,a.w,b.x,b.y,b.z,b.w};
#pragma unroll
        for (int j=0;j<8;j++) xh[kk][rt][j] = (short)f2bh(xs[j]*DNORM);
      }
    float mx = -1e30f;
#pragma unroll
    for (int mtl=0; mtl<4; mtl++){
        int mtile = w*4 + mtl;
        bf16x8 pf[2];
#pragma unroll
        for (int kk=0;kk<2;kk++){
            // frag-major: m = mtile*16+l15 -> f = (mtile>>1)*4 + kk*2 + (mtile&1)
            int f = (mtile >> 1)*4 + kk*2 + (mtile & 1);
            pf[kk] = *(const bf16x8*)(Pfh + (f*64 + lane)*8);
        }
        f32x4 acc[2] = {f32x4{0.f,0.f,0.f,0.f}, f32x4{0.f,0.f,0.f,0.f}};
#pragma unroll
        for (int kk=0;kk<2;kk++)
#pragma unroll
          for (int rt=0;rt<2;rt++)
            acc[rt] = MFMA16(xh[kk][rt], pf[kk], acc[rt]);
#pragma unroll
        for (int rt=0;rt<2;rt++)
#pragma unroll
          for (int i=0;i<4;i++) mx = fmaxf(mx, acc[rt][i]);
    }
#pragma unroll
    for (int d=1; d<64; d<<=1) mx = fmaxf(mx, __shfl_xor(mx, d, 64));
    if (lane == 0) red[w] = mx;
    __syncthreads();
    if (tid == 0){
        float m2 = fmaxf(fmaxf(red[0],red[1]), fmaxf(red[2],red[3]));
        atomicMax(kmax_u, mapf(m2));
    }
}

// ---------------- B: per-chunk states S = Kf^T V, z = sum Kf ----------------
__global__ __launch_bounds__(512, 2) void b_kernel(const float* __restrict__ k,
        const float* __restrict__ v,
        const unsigned short* __restrict__ Pfh, const unsigned short* __restrict__ Pfl,
        const unsigned* __restrict__ kmax_u, float* __restrict__ states,
        int CH, int nch){
    __shared__ short Xh[4][64][8], Xl[4][64][8];
    __shared__ unsigned kf_[256*32];     // [m][t] swizzled: m*32 + (t ^ ((m&7)<<2))
    __shared__ unsigned Vt_u[64][36];    // [e][t] packed hi/lo
    __shared__ float diagk_[32];
    int tid = threadIdx.x;
    int lane = tid & 63, w = tid >> 6;
    int l15 = lane & 15, g = lane >> 4;
    int cx = blockIdx.x, bh = blockIdx.y;
    int o = (cx == 0) ? 0 : CONDL + (cx-1)*CH;
    int nsub = ((cx == 0) ? CONDL : CH) >> 5;
    long rowbase = (long)bh * S_TOT + o;
    float kmax = unmapf(*kmax_u);
    int xsw = (l15 & 7) << 2;
    f32x4 Sacc[2][4];   // [mt][et]
#pragma unroll
    for (int mt=0;mt<2;mt++)
#pragma unroll
      for (int et=0;et<4;et++) Sacc[mt][et] = f32x4{0.f,0.f,0.f,0.f};
    float zacc[2] = {0.f, 0.f};

    // T14 prefetch: per-thread fixed offsets within a 32-row subtile
    const float* kptr = k + rowbase*64 + (tid >> 4)*64 + (tid & 15)*4;
    const float* vptr = v + rowbase*64 + (tid >> 4)*64 + (tid & 15)*4;
    float4 kpre = *(const float4*)kptr;
    float4 vpre = *(const float4*)vptr;

    for (int st = 0; st < nsub; st++){
        long r0 = rowbase + st*32;
        // P0: k conversion (prefetched) + V staging (prefetched)
        conv_store(kpre, tid, Xh, Xl, diagk_);
        {
            int e4 = (tid & 15)*4;
            int t = tid >> 4;
            Vt_u[e4+0][t] = packhl(vpre.x);
            Vt_u[e4+1][t] = packhl(vpre.y);
            Vt_u[e4+2][t] = packhl(vpre.z);
            Vt_u[e4+3][t] = packhl(vpre.w);
        }
        __syncthreads();
        // P1: dd (P-frags streamed from L2-hot global) + kf finalize
        f32x4 dk[2][2];
        __builtin_amdgcn_s_setprio(1);
        dd_frags_g(Xh, Xl, lane, w, Pfh, Pfl, dk);
        __builtin_amdgcn_s_setprio(0);
        float zd0 = 0.f, zd1 = 0.f;
#pragma unroll
        for (int rr=0;rr<2;rr++){
            float dg0 = diagk_[rr*16 + g*4 + 0];
            float dg1 = diagk_[rr*16 + g*4 + 1];
            float dg2 = diagk_[rr*16 + g*4 + 2];
            float dg3 = diagk_[rr*16 + g*4 + 3];
#pragma unroll
            for (int mt=0;mt<2;mt++){
                float k0 = RATIO * (__expf(dk[rr][mt][0] - dg0 - kmax) + KEPS);
                float k1 = RATIO * (__expf(dk[rr][mt][1] - dg1 - kmax) + KEPS);
                float k2 = RATIO * (__expf(dk[rr][mt][2] - dg2 - kmax) + KEPS);
                float k3 = RATIO * (__expf(dk[rr][mt][3] - dg3 - kmax) + KEPS);
                if (mt == 0) zd0 += k0+k1+k2+k3; else zd1 += k0+k1+k2+k3;
                uint4 kw;
                kw.x = packhl(k0); kw.y = packhl(k1);
                kw.z = packhl(k2); kw.w = packhl(k3);
                int m = w*32 + mt*16 + l15;
                *(uint4*)&kf_[m*32 + ((rr*16 + g*4) ^ xsw)] = kw;
            }
        }
        zd0 += __shfl_xor(zd0, 16, 64); zd0 += __shfl_xor(zd0, 32, 64);
        zd1 += __shfl_xor(zd1, 16, 64); zd1 += __shfl_xor(zd1, 32, 64);
        zacc[0] += zd0; zacc[1] += zd1;
        __syncthreads();
        // P2: prefetch st+1 (covered by delta MFMAs); state delta MFMAs
        if (st + 1 < nsub){
            kpre = *(const float4*)(kptr + (st+1)*2048);
            vpre = *(const float4*)(vptr + (st+1)*2048);
        }
        __builtin_amdgcn_s_setprio(1);
#pragma unroll
        for (int mt=0;mt<2;mt++){
            int m = (w*2 + mt)*16 + l15;
            uint4 kp0 = *(const uint4*)&kf_[m*32 + ((g*4) ^ xsw)];
            uint4 kp1 = *(const uint4*)&kf_[m*32 + ((16 + g*4) ^ xsw)];
            bf16x8 kh, kl; unpk(kp0, kp1, kh, kl);
#pragma unroll
            for (int et=0;et<4;et++){
                const uint4* vp0 = (const uint4*)&Vt_u[et*16 + l15][g*4];
                const uint4* vp1 = (const uint4*)&Vt_u[et*16 + l15][16 + g*4];
                bf16x8 vh, vl; unpk(*vp0, *vp1, vh, vl);
                Sacc[mt][et] = MFMA16(kh, vh, Sacc[mt][et]);
                Sacc[mt][et] = MFMA16(kh, vl, Sacc[mt][et]);
                Sacc[mt][et] = MFMA16(kl, vh, Sacc[mt][et]);
            }
        }
        __builtin_amdgcn_s_setprio(0);
        __syncthreads();
    }
    // write state slot
    float* Sg = states + ((long)(bh*nch + cx)) * SLOT_F;
#pragma unroll
    for (int mt=0;mt<2;mt++)
#pragma unroll
      for (int et=0;et<4;et++)
#pragma unroll
        for (int i=0;i<4;i++)
            Sg[((w*2+mt)*16 + g*4 + i)*64 + et*16 + l15] = Sacc[mt][et][i];
    if (g == 0){
        Sg[16384 + w*32 + l15]      = zacc[0];
        Sg[16384 + w*32 + 16 + l15] = zacc[1];
    }
}

// ---------------- C: exclusive scan over chunk slots ----------------
__global__ __launch_bounds__(256) void scan_kernel(float* __restrict__ states, int nch){
    int idx = blockIdx.x*256 + threadIdx.x;
    if (idx >= SLOT_F) return;
    float* base = states + (long)blockIdx.y * nch * SLOT_F + idx;
    if (nch == 32){
        // hoist all 32 strided loads into registers (all in flight), then store
        float vals[32];
#pragma unroll
        for (int c = 0; c < 32; c++) vals[c] = base[(long)c * SLOT_F];
        float prev = 0.f;
#pragma unroll
        for (int c = 0; c < 32; c++){
            base[(long)c * SLOT_F] = prev;
            prev += vals[c];
        }
    } else {
        float prev = 0.f;
        for (int c = 0; c < nch; c++){
            float t = base[(long)c * SLOT_F];
            base[(long)c * SLOT_F] = prev;
            prev += t;
        }
    }
}

// ---------------- D: outputs (split reg state, kfT tile, 106.75KB LDS) ----------------
__global__ __launch_bounds__(512, 1) void d_kernel(const float* __restrict__ q,
        const float* __restrict__ k, const float* __restrict__ v,
        const unsigned short* __restrict__ Pfh, const unsigned short* __restrict__ Pfl,
        const unsigned* __restrict__ kmax_u, const float* __restrict__ states,
        float* __restrict__ out, int CH, int nch){
    // LDS map (uints), total = 26,688 uints = 106,752 B (1 block/CU):
    //  [0,8192)      qf  [32][256]  row*256 + (m ^ ((row&7)<<2)), packed hi/lo
    //  [8192,16384)  kf  [256][32]  m*32 + (t ^ ((m&7)<<2)), packed hi/lo
    //                  head overlay (live P0-P2 only): dgq[32] f32, rmax[32] u32
    //  [16384,24576) kfT [32][256]  t*256 + (m ^ ((t&7)<<2))  (A-prod B-operand)
    //  [24576,26624) X frags (P0-P3) / A[32][32] + xch (P4-P7)
    //  [26624,26656) den f32[32]
    //  [26656,26688) dgk f32[32]
    __shared__ __attribute__((aligned(16))) unsigned lds_[26688];
    unsigned* qf_  = lds_;
    unsigned* kf_  = lds_ + 8192;
    unsigned* kfT_ = lds_ + 16384;
    unsigned* XA_  = lds_ + 24576;
    float*   den_ = (float*)(lds_ + 26624);
    float*   dgk_ = (float*)(lds_ + 26656);
    float*   dgq_ = (float*)kf_;
    unsigned* rmax_ = kf_ + 32;
    unsigned* A_ = XA_;
    float*   xch_ = (float*)(XA_ + 1024);
    short (*Xh)[64][8] = (short (*)[64][8])XA_;
    short (*Xl)[64][8] = (short (*)[64][8])(XA_ + 1024);

    int tid = threadIdx.x;
    int lane = tid & 63, w = tid >> 6;
    int l15 = lane & 15, g = lane >> 4;
    int et = w & 3, rt = w >> 2;
    bool owner = (rt == 0);     // owners: A at P4, inter at P6, output rows 0..15
    int cx = blockIdx.x, bh = blockIdx.y;
    bool causal = (cx > 0);
    int o = causal ? (CONDL + (cx-1)*CH) : 0;
    int nsub = (causal ? CH : CONDL) >> 5;
    float epsv = causal ? AEPS : 0.f;
    int slot = causal ? cx : 1;
    const float* Sg = states + ((long)(bh*nch + slot)) * SLOT_F;
    long rowbase = (long)bh * S_TOT + o;
    float kmax = unmapf(*kmax_u);
    int xsw = (l15 & 7) << 2;   // row/m/t & 7 == l15 & 7 for all our frag rows

    // P-fragments in registers (coalesced frag-major load, once)
    bf16x8 Ph_r[2][2], Pl_r[2][2];
    load_pfrags_fm(Pfh, Pfl, w, lane, Ph_r, Pl_r);

    // split state -> registers: wave (rt,et) holds features rt*128..+127:
    // S[Mtl][i] = S_mat[(rt*8+Mtl)*16 + g*4 + i][et*16 + l15]
    f32x4 S[8];
#pragma unroll
    for (int Mtl=0; Mtl<8; Mtl++){
#pragma unroll
        for (int i=0;i<4;i++)
            S[Mtl][i] = Sg[((rt*8 + Mtl)*16 + g*4 + i)*64 + et*16 + l15];
    }
    float z0 = Sg[16384 + w*32 + l15];
    float z1 = Sg[16384 + w*32 + 16 + l15];

    // prefetch pointers (per-thread fixed offsets within a 32-row subtile)
    const float* qptr = q + rowbase*64 + (tid >> 4)*64 + (tid & 15)*4;
    const float* kptr = k + rowbase*64 + (tid >> 4)*64 + (tid & 15)*4;
    float4 qpre = *(const float4*)qptr;

    for (int st = 0; st < nsub; st++){
        long r0 = rowbase + st*32;
        // ---- P0: k prefetch issue; q conversion + init ----
        float4 kpre;
        if (causal) kpre = *(const float4*)(kptr + st*2048);
        conv_store(qpre, tid, Xh, Xl, dgq_);
        if (tid < 32){ den_[tid] = 0.f; rmax_[tid] = 0u; }
        __syncthreads();                      // B1
        // ---- P1: dd_q + rowmax atomics ----
        f32x4 dq[2][2];
        dd_frags(Xh, Xl, lane, Ph_r, Pl_r, dq);
#pragma unroll
        for (int rr=0;rr<2;rr++)
#pragma unroll
          for (int i=0;i<4;i++){
            float mx = fmaxf(dq[rr][0][i], dq[rr][1][i]);
            mx = fmaxf(mx, __shfl_xor(mx, 1, 64));
            mx = fmaxf(mx, __shfl_xor(mx, 2, 64));
            mx = fmaxf(mx, __shfl_xor(mx, 4, 64));
            mx = fmaxf(mx, __shfl_xor(mx, 8, 64));
            if (l15 == 0) atomicMax(&rmax_[rr*16 + g*4 + i], mapf(mx));
          }
        __syncthreads();                      // B2
        // ---- P2: qf finalize + den(z) || k conversion (prefetched) ----
        {
#pragma unroll
            for (int rr=0;rr<2;rr++)
#pragma unroll
              for (int i=0;i<4;i++){
                int row = rr*16 + g*4 + i;
                float dgv = dgq_[row];
                float rm = unmapf(rmax_[row]);
                float s1p = 0.f, s2p = 0.f;
#pragma unroll
                for (int mt=0;mt<2;mt++){
                    float qv = RATIO * (__expf(dq[rr][mt][i] - dgv - rm) + KEPS);
                    s1p += qv;
                    s2p += qv * (mt ? z1 : z0);
                    int m = w*32 + mt*16 + l15;
                    qf_[row*256 + (m ^ ((row & 7) << 2))] = packhl(qv);
                }
#pragma unroll
                for (int d2=1; d2<16; d2<<=1){
                    s1p += __shfl_xor(s1p, d2, 64);
                    s2p += __shfl_xor(s2p, d2, 64);
                }
                if (l15 == 0) atomicAdd(&den_[row], s2p + epsv * s1p);
              }
        }
        if (causal) conv_store(kpre, tid, Xh, Xl, dgk_);
        __syncthreads();                      // B3
        // ---- P3: dd_k + kf/kfT finalize (b128/b32 stores) + z update ----
        if (causal){
            f32x4 dk[2][2];
            dd_frags(Xh, Xl, lane, Ph_r, Pl_r, dk);
            float zd0 = 0.f, zd1 = 0.f;
#pragma unroll
            for (int rr=0;rr<2;rr++){
                float dg0 = dgk_[rr*16 + g*4 + 0];
                float dg1 = dgk_[rr*16 + g*4 + 1];
                float dg2 = dgk_[rr*16 + g*4 + 2];
                float dg3 = dgk_[rr*16 + g*4 + 3];
#pragma unroll
                for (int mt=0;mt<2;mt++){
                    float k0 = RATIO * (__expf(dk[rr][mt][0] - dg0 - kmax) + KEPS);
                    float k1 = RATIO * (__expf(dk[rr][mt][1] - dg1 - kmax) + KEPS);
                    float k2 = RATIO * (__expf(dk[rr][mt][2] - dg2 - kmax) + KEPS);
                    float k3 = RATIO * (__expf(dk[rr][mt][3] - dg3 - kmax) + KEPS);
                    if (mt == 0) zd0 += k0+k1+k2+k3; else zd1 += k0+k1+k2+k3;
                    uint4 kw;
                    kw.x = packhl(k0); kw.y = packhl(k1);
                    kw.z = packhl(k2); kw.w = packhl(k3);
                    int m = w*32 + mt*16 + l15;
                    *(uint4*)&kf_[m*32 + ((rr*16 + g*4) ^ xsw)] = kw;
                    // kfT: same values, transposed tile (qf-identical pattern)
                    int t0r = rr*16 + g*4;
                    kfT_[(t0r+0)*256 + (m ^ ((((g*4)+0) & 7) << 2))] = kw.x;
                    kfT_[(t0r+1)*256 + (m ^ ((((g*4)+1) & 7) << 2))] = kw.y;
                    kfT_[(t0r+2)*256 + (m ^ ((((g*4)+2) & 7) << 2))] = kw.z;
                    kfT_[(t0r+3)*256 + (m ^ ((((g*4)+3) & 7) << 2))] = kw.w;
                }
            }
            zd0 += __shfl_xor(zd0, 16, 64); zd0 += __shfl_xor(zd0, 32, 64);
            zd1 += __shfl_xor(zd1, 16, 64); zd1 += __shfl_xor(zd1, 32, 64);
            z0 += zd0; z1 += zd1;
        }
        __syncthreads();                      // B4
        // ---- P4: q prefetch (st+1); owners: A-product; rt=1: inter + slot ----
        if (st + 1 < nsub) qpre = *(const float4*)(qptr + (st+1)*2048);
        float vv[8];
        if (causal){
            const float* vb = v + r0*64 + et*16 + l15;
#pragma unroll
            for (int p2=0;p2<2;p2++)
#pragma unroll
              for (int j=0;j<4;j++)
                vv[p2*4+j] = vb[(p2*16 + g*4 + j)*64];
        }
        f32x4 Cp0{0.f,0.f,0.f,0.f}, Cp1{0.f,0.f,0.f,0.f};
        if (owner){
            if (causal){
                int ar = et >> 1, tt = et & 1;
                int t = tt*16 + l15;
                int tb = t*256;
                f32x4 c{0.f,0.f,0.f,0.f};
                int rowb = (ar*16 + l15)*256;
                __builtin_amdgcn_s_setprio(1);
#pragma unroll
                for (int kt=0;kt<8;kt++){
                    uint4 q0 = *(const uint4*)&qf_[rowb + ((kt*32 + g*4) ^ xsw)];
                    uint4 q1 = *(const uint4*)&qf_[rowb + ((kt*32 + 16 + g*4) ^ xsw)];
                    bf16x8 qh, ql; unpk(q0, q1, qh, ql);
                    uint4 kt0 = *(const uint4*)&kfT_[tb + ((kt*32 + g*4) ^ xsw)];
                    uint4 kt1 = *(const uint4*)&kfT_[tb + ((kt*32 + 16 + g*4) ^ xsw)];
                    bf16x8 kh, kl; unpk(kt0, kt1, kh, kl);
                    c = MFMA16(qh, kh, c);
                    c = MFMA16(qh, kl, c);
                    c = MFMA16(ql, kh, c);
                }
                __builtin_amdgcn_s_setprio(0);
#pragma unroll
                for (int i=0;i<4;i++){
                    int r = ar*16 + g*4 + i;
                    float a = (t <= r) ? c[i] : 0.f;
                    A_[r*32 + (t ^ ((r & 7) << 2))] = packhl(a);
                    float p = a;
                    p += __shfl_xor(p, 1, 64);
                    p += __shfl_xor(p, 2, 64);
                    p += __shfl_xor(p, 4, 64);
                    p += __shfl_xor(p, 8, 64);
                    if (l15 == 0) atomicAdd(&den_[r], p);
                }
            }
        } else {
            __builtin_amdgcn_s_setprio(1);
            inter_half(qf_, S, rt, l15, g, xsw, Cp0, Cp1);
            __builtin_amdgcn_s_setprio(0);
            // away partial (row-tile 0) -> slot et; keep Cp1 (our quadrant)
            *(float4*)&xch_[(et*64 + lane)*4] = float4{Cp0[0],Cp0[1],Cp0[2],Cp0[3]};
        }
        __syncthreads();                      // B5
        // ---- P6: owners: inter + partner-add + slot write; all: delta + intra ----
        if (owner){
            __builtin_amdgcn_s_setprio(1);
            inter_half(qf_, S, rt, l15, g, xsw, Cp0, Cp1);
            __builtin_amdgcn_s_setprio(0);
            float4 pp = *(const float4*)&xch_[(et*64 + lane)*4];
            Cp0[0] += pp.x; Cp0[1] += pp.y; Cp0[2] += pp.z; Cp0[3] += pp.w;
            // away partial (row-tile 1) for partner
            *(float4*)&xch_[(et*64 + lane)*4] = float4{Cp1[0],Cp1[1],Cp1[2],Cp1[3]};
        }
        if (causal){
            f32x4 va{vv[0], vv[1], vv[2], vv[3]};
            f32x4 vb2{vv[4], vv[5], vv[6], vv[7]};
            bf16x8 vh, vl; sfrag(va, vb2, vh, vl);
            // delta over own feature half: S += Kf^T V
            __builtin_amdgcn_s_setprio(1);
#pragma unroll
            for (int Mtl=0;Mtl<8;Mtl++){
                int mb = ((rt*8 + Mtl)*16 + l15)*32;
                uint4 k0 = *(const uint4*)&kf_[mb + ((g*4) ^ xsw)];
                uint4 k1 = *(const uint4*)&kf_[mb + ((16 + g*4) ^ xsw)];
                bf16x8 kh, kl; unpk(k0, k1, kh, kl);
                S[Mtl] = MFMA16(kh, vh, S[Mtl]);
                S[Mtl] = MFMA16(kh, vl, S[Mtl]);
                S[Mtl] = MFMA16(kl, vh, S[Mtl]);
            }
            __builtin_amdgcn_s_setprio(0);
            // intra: A @ V for this wave's output row-tile (rt)
            int rb = (rt*16 + l15)*32;
            uint4 a0 = *(const uint4*)&A_[rb + ((g*4) ^ xsw)];
            uint4 a1 = *(const uint4*)&A_[rb + ((16 + g*4) ^ xsw)];
            bf16x8 ah, al; unpk(a0, a1, ah, al);
            f32x4& Ct = owner ? Cp0 : Cp1;
            Ct = MFMA16(ah, vh, Ct);
            Ct = MFMA16(ah, vl, Ct);
            Ct = MFMA16(al, vh, Ct);
        }
        if (owner){
#pragma unroll
            for (int i=0;i<4;i++){
                int row = g*4 + i;
                out[(r0 + row)*64 + et*16 + l15] = Cp0[i] / den_[row];
            }
        }
        __syncthreads();                      // B6
        // ---- P7: rt=1 waves: partner-add + output rows 16..31 ----
        if (!owner){
            float4 pp = *(const float4*)&xch_[(et*64 + lane)*4];
            Cp1[0] += pp.x; Cp1[1] += pp.y; Cp1[2] += pp.z; Cp1[3] += pp.w;
#pragma unroll
            for (int i=0;i<4;i++){
                int row = 16 + g*4 + i;
                out[(r0 + row)*64 + et*16 + l15] = Cp1[i] / den_[row];
            }
        }
        __syncthreads();                      // B7 (end)
    }
}

extern "C" void kernel_launch(void* const* d_in, const int* in_sizes, int n_in,
                              void* d_out, int out_size, void* d_ws, size_t ws_size,
                              hipStream_t stream) {
    const float* q = (const float*)d_in[0];
    const float* k = (const float*)d_in[1];
    const float* v = (const float*)d_in[2];
    const float* proj = (const float*)d_in[3];
    float* out = (float*)d_out;

    unsigned* kmax_u = (unsigned*)d_ws;
    // legacy flat Ph/Pl region at [256, 256+64KB) left unused
    unsigned short* Pfh = (unsigned short*)((char*)d_ws + 256 + 65536);
    unsigned short* Pfl = Pfh + 16384;
    float* states = (float*)((char*)d_ws + 256 + 131072);
    size_t fixed = 256 + 131072;

    int CH, nch;
    size_t need128 = fixed + (size_t)64 * 32 * SLOT_F * 4;
    if (ws_size >= need128){ CH = 128; nch = 32; }
    else                  { CH = 992; nch = 5;  }

    hipMemsetAsync(d_ws, 0, 4, stream);
    hipLaunchKernelGGL(init_p_kernel, dim3(64), dim3(256), 0, stream, proj, Pfh, Pfl);
    hipLaunchKernelGGL(kmax_kernel, dim3(8192), dim3(256), 0, stream, k, Pfh, kmax_u);
    hipLaunchKernelGGL(b_kernel, dim3(nch, 64), dim3(512), 0, stream, k, v, Pfh, Pfl, kmax_u, states, CH, nch);
    hipLaunchKernelGGL(scan_kernel, dim3(65, 64), dim3(256), 0, stream, states, nch);
    hipLaunchKernelGGL(d_kernel, dim3(nch, 64), dim3(512), 0, stream, q, k, v, Pfh, Pfl, kmax_u, states, out, CH, nch);
}

// Round 16
// 572.112 us; speedup vs baseline: 1.5123x; 1.0092x over previous
//
#include <hip/hip_runtime.h>
#include <math.h>

// Performer FAVOR+ causal linear attention, MI355X.
// B=4 H=16 S=4096 D=64 M=256 features, COND=128 non-causal prefix.
// v17 = v16 (577us) + b_kernel kf REGISTER PASS-THROUGH: P1's computed kf
// values are exactly the fragments P2 reads back (same thread, same elements:
// rr=0<->kp0, rr=1<->kp1), so the 32KB kf LDS tile, its stores/reads/unpk,
// AND the P1->P2 barrier (which protected only that round-trip) are deleted.
// b: 3 -> 2 barriers/subtile, LDS 49.5 -> 17.5KB. sfrag produces bit-identical
// operands to unpk(packhl(...)). +24 transient regs (ka/kb/khr/klr vs dk
// death); if the 128-reg 2-blocks/CU budget is crossed b regresses (revert).
// History: v13 b streams P-frags (2 blocks/CU, -45us); v14 kmax/scan (-6us);
// v15 b T14 prefetch (-8us); v16 b T5 setprio (-3us).
// d_kernel structurally pinned at 8 waves/CU; rounds 5-11 exhausted d levers.
// ws: [0..4) kmax (mapped uint), [256..) [unused 64KB legacy region],
//     Pfm_h/Pfm_l frag-major bf16 planes (32KB each),
//     then chunk states [64][nslot][256*64 + 256] f32.

#define S_TOT 4096
#define CONDL 128
#define SLOT_F 16640
#define RATIO 0.0625f
#define DNORM 0.35355339059327378f
#define KEPS  1e-4f
#define AEPS  1e-6f

typedef __attribute__((ext_vector_type(8))) short bf16x8;
typedef __attribute__((ext_vector_type(2))) unsigned uint2v;
typedef __attribute__((ext_vector_type(4))) float f32x4;

#define MFMA16(a,b,c) __builtin_amdgcn_mfma_f32_16x16x32_bf16(a,b,c,0,0,0)

static __device__ __forceinline__ unsigned cvtpk(float a, float b){
    unsigned r;
    asm("v_cvt_pk_bf16_f32 %0, %1, %2" : "=v"(r) : "v"(a), "v"(b));
    return r;
}
static __device__ __forceinline__ float lo16f(unsigned u){ return __uint_as_float(u << 16); }
static __device__ __forceinline__ float hi16f(unsigned u){ return __uint_as_float(u & 0xffff0000u); }

static __device__ __forceinline__ unsigned short f2bh(float x){
    unsigned u = __float_as_uint(x);
    u += 0x7fffu + ((u >> 16) & 1u);
    return (unsigned short)(u >> 16);
}
static __device__ __forceinline__ float bh2f(unsigned short h){
    return __uint_as_float((unsigned)h << 16);
}
// pack hi/lo bf16 of x into one dword (hi in low16, residual-lo in high16)
static __device__ __forceinline__ unsigned packhl(float x){
    unsigned u1 = cvtpk(x, x);
    float r = x - lo16f(u1);
    return cvtpk(x, r);
}
// two uint4 (halves k=[0..15],[16..31] of this lane's 4+4 elems) -> hi/lo frags
static __device__ __forceinline__ void unpk(const uint4 a, const uint4 b, bf16x8& h, bf16x8& l){
    h[0]=(short)a.x; h[1]=(short)a.y; h[2]=(short)a.z; h[3]=(short)a.w;
    h[4]=(short)b.x; h[5]=(short)b.y; h[6]=(short)b.z; h[7]=(short)b.w;
    l[0]=(short)(a.x>>16); l[1]=(short)(a.y>>16); l[2]=(short)(a.z>>16); l[3]=(short)(a.w>>16);
    l[4]=(short)(b.x>>16); l[5]=(short)(b.y>>16); l[6]=(short)(b.z>>16); l[7]=(short)(b.w>>16);
}
static __device__ __forceinline__ unsigned mapf(float x){
    unsigned u = __float_as_uint(x);
    return (u & 0x80000000u) ? ~u : (u | 0x80000000u);
}
static __device__ __forceinline__ float unmapf(unsigned u){
    return __uint_as_float((u & 0x80000000u) ? (u ^ 0x80000000u) : ~u);
}

// Convert a pre-loaded 32x64 f32 tile row-quad into frag-major hi/lo bf16
// planes + row diag (cooperative across 512 threads).
static __device__ __forceinline__ void conv_store(float4 x4, int tid,
        short (*Xh)[64][8], short (*Xl)[64][8], float* __restrict__ diag_)
{
    int row = tid >> 4;
    int c4  = (tid & 15) * 4;
    float x0 = x4.x*DNORM, x1 = x4.y*DNORM, x2 = x4.z*DNORM, x3 = x4.w*DNORM;
    float ss = x0*x0 + x1*x1 + x2*x2 + x3*x3;
    ss += __shfl_xor(ss, 1, 64);
    ss += __shfl_xor(ss, 2, 64);
    ss += __shfl_xor(ss, 4, 64);
    ss += __shfl_xor(ss, 8, 64);
    if ((tid & 15) == 0) diag_[row] = 0.5f * ss;
    int rt = row >> 4, lr = row & 15;
    int kk = c4 >> 5, c5 = c4 & 31;
    int fg, j0;
    if (c5 < 16){ fg = c5 >> 2; j0 = 0; } else { fg = (c5 - 16) >> 2; j0 = 4; }
    int f = kk*2 + rt;
    unsigned a01 = cvtpk(x0, x1), a23 = cvtpk(x2, x3);
    unsigned b01 = cvtpk(x0 - lo16f(a01), x1 - hi16f(a01));
    unsigned b23 = cvtpk(x2 - lo16f(a23), x3 - hi16f(a23));
    uint2v hv, lv;
    hv[0] = a01; hv[1] = a23;
    lv[0] = b01; lv[1] = b23;
    *(uint2v*)&Xh[f][fg*16 + lr][j0] = hv;
    *(uint2v*)&Xl[f][fg*16 + lr][j0] = lv;
}

static __device__ __forceinline__ void conv_write(const float* __restrict__ Xg, long r0,
        int tid, short (*Xh)[64][8], short (*Xl)[64][8], float* __restrict__ diag_)
{
    int row = tid >> 4;
    int c4  = (tid & 15) * 4;
    float4 x4 = *(const float4*)(Xg + (r0 + row)*64 + c4);
    conv_store(x4, tid, Xh, Xl, diag_);
}

// frag-major P load (coalesced b128) -- d_kernel, held in registers
static __device__ __forceinline__ void load_pfrags_fm(const unsigned short* __restrict__ Pfh,
        const unsigned short* __restrict__ Pfl, int w, int lane,
        bf16x8 (&Ph_r)[2][2], bf16x8 (&Pl_r)[2][2])
{
#pragma unroll
    for (int kk=0; kk<2; kk++)
#pragma unroll
      for (int mt=0; mt<2; mt++){
        int f = w*4 + kk*2 + mt;
        Ph_r[mt][kk] = *(const bf16x8*)(Pfh + (f*64 + lane)*8);
        Pl_r[mt][kk] = *(const bf16x8*)(Pfl + (f*64 + lane)*8);
      }
}

// dd GEMM from shared frags, register P-frags
static __device__ __forceinline__ void dd_frags(const short (*Xh)[64][8], const short (*Xl)[64][8],
        int lane, const bf16x8 (&Pfh)[2][2], const bf16x8 (&Pfl)[2][2], f32x4 (&acc)[2][2])
{
#pragma unroll
    for (int rt=0;rt<2;rt++)
#pragma unroll
      for (int mt=0;mt<2;mt++) acc[rt][mt] = f32x4{0.f,0.f,0.f,0.f};
#pragma unroll
    for (int kk=0;kk<2;kk++)
#pragma unroll
      for (int rt=0;rt<2;rt++){
        bf16x8 xh = *(const bf16x8*)&Xh[kk*2+rt][lane][0];
        bf16x8 xl = *(const bf16x8*)&Xl[kk*2+rt][lane][0];
#pragma unroll
        for (int mt=0;mt<2;mt++){
            acc[rt][mt] = MFMA16(xh, Pfh[mt][kk], acc[rt][mt]);
            acc[rt][mt] = MFMA16(xh, Pfl[mt][kk], acc[rt][mt]);
            acc[rt][mt] = MFMA16(xl, Pfh[mt][kk], acc[rt][mt]);
        }
      }
}

// dd GEMM, P-frags streamed from frag-major global planes (b_kernel path)
static __device__ __forceinline__ void dd_frags_g(const short (*Xh)[64][8], const short (*Xl)[64][8],
        int lane, int w, const unsigned short* __restrict__ Pfh, const unsigned short* __restrict__ Pfl,
        f32x4 (&acc)[2][2])
{
#pragma unroll
    for (int rr=0;rr<2;rr++)
#pragma unroll
      for (int mt=0;mt<2;mt++) acc[rr][mt] = f32x4{0.f,0.f,0.f,0.f};
#pragma unroll
    for (int kk=0;kk<2;kk++){
        bf16x8 ph[2], pl[2];
#pragma unroll
        for (int mt=0;mt<2;mt++){
            int f = w*4 + kk*2 + mt;
            ph[mt] = *(const bf16x8*)(Pfh + (f*64 + lane)*8);
            pl[mt] = *(const bf16x8*)(Pfl + (f*64 + lane)*8);
        }
#pragma unroll
        for (int rr=0;rr<2;rr++){
            bf16x8 xh = *(const bf16x8*)&Xh[kk*2+rr][lane][0];
            bf16x8 xl = *(const bf16x8*)&Xl[kk*2+rr][lane][0];
#pragma unroll
            for (int mt=0;mt<2;mt++){
                acc[rr][mt] = MFMA16(xh, ph[mt], acc[rr][mt]);
                acc[rr][mt] = MFMA16(xh, pl[mt], acc[rr][mt]);
                acc[rr][mt] = MFMA16(xl, ph[mt], acc[rr][mt]);
            }
        }
    }
}

// build hi/lo bf16 B-frag for one kt directly from f32 values (C-layout regs)
static __device__ __forceinline__ void sfrag(const f32x4 a, const f32x4 b, bf16x8& h, bf16x8& l){
    union U { bf16x8 v; unsigned u[4]; } H, L;
    H.u[0] = cvtpk(a[0], a[1]); H.u[1] = cvtpk(a[2], a[3]);
    H.u[2] = cvtpk(b[0], b[1]); H.u[3] = cvtpk(b[2], b[3]);
    L.u[0] = cvtpk(a[0] - lo16f(H.u[0]), a[1] - hi16f(H.u[0]));
    L.u[1] = cvtpk(a[2] - lo16f(H.u[1]), a[3] - hi16f(H.u[1]));
    L.u[2] = cvtpk(b[0] - lo16f(H.u[2]), b[1] - hi16f(H.u[2]));
    L.u[3] = cvtpk(b[2] - lo16f(H.u[3]), b[3] - hi16f(H.u[3]));
    h = H.v; l = L.v;
}

// inter partials over this wave's feature half (ft = rt*4 + ktl), both row-tiles
static __device__ __forceinline__ void inter_half(const unsigned* __restrict__ qf_,
        const f32x4 (&S)[8], int rt, int l15, int g, int xsw,
        f32x4 &Cp0, f32x4 &Cp1)
{
#pragma unroll
    for (int ktl=0; ktl<4; ktl++){
        int ft = rt*4 + ktl;
        bf16x8 sh, sl; sfrag(S[2*ktl], S[2*ktl+1], sh, sl);
        {
            int rowb = l15*256;                 // row-tile 0
            uint4 q0 = *(const uint4*)&qf_[rowb + ((ft*32 + g*4) ^ xsw)];
            uint4 q1 = *(const uint4*)&qf_[rowb + ((ft*32 + 16 + g*4) ^ xsw)];
            bf16x8 qh, ql; unpk(q0, q1, qh, ql);
            Cp0 = MFMA16(qh, sh, Cp0);
            Cp0 = MFMA16(qh, sl, Cp0);
            Cp0 = MFMA16(ql, sh, Cp0);
        }
        {
            int rowb = (16 + l15)*256;          // row-tile 1
            uint4 q0 = *(const uint4*)&qf_[rowb + ((ft*32 + g*4) ^ xsw)];
            uint4 q1 = *(const uint4*)&qf_[rowb + ((ft*32 + 16 + g*4) ^ xsw)];
            bf16x8 qh, ql; unpk(q0, q1, qh, ql);
            Cp1 = MFMA16(qh, sh, Cp1);
            Cp1 = MFMA16(qh, sl, Cp1);
            Cp1 = MFMA16(ql, sh, Cp1);
        }
    }
}

// ---------------- init: P -> bf16 hi/lo frag-major planes ----------------
__global__ __launch_bounds__(256) void init_p_kernel(const float* __restrict__ proj,
        unsigned short* __restrict__ Pfh, unsigned short* __restrict__ Pfl){
    int i = blockIdx.x*256 + threadIdx.x;   // 16384
    float x = proj[i];
    unsigned short h = f2bh(x);
    unsigned short l = f2bh(x - bh2f(h));
    // frag-major: i = m*64 + d
    int m = i >> 6, d = i & 63;
    int w = m >> 5, mt = (m >> 4) & 1, l15 = m & 15;
    int kk = d >> 5, r5 = d & 31;
    int half = r5 >> 4, g = (r5 & 15) >> 2, jj = r5 & 3;
    int f = w*4 + kk*2 + mt, lane = g*16 + l15, j = half*4 + jj;
    int o = (f*64 + lane)*8 + j;
    Pfh[o] = h; Pfl[o] = l;
}

// ---------------- kmax: global max of k's data_dash (hi-only is safe) ----------------
__global__ __launch_bounds__(256) void kmax_kernel(const float* __restrict__ k,
        const unsigned short* __restrict__ Pfh, unsigned* __restrict__ kmax_u){
    __shared__ float red[4];
    int tid = threadIdx.x;
    int lane = tid & 63, w = tid >> 6;
    int l15 = lane & 15, g = lane >> 4;
    long r0 = (long)blockIdx.x * 32;
    bf16x8 xh[2][2];  // [kk][rt]
#pragma unroll
    for (int kk=0;kk<2;kk++)
#pragma unroll
      for (int rt=0;rt<2;rt++){
        const float* rp = k + (r0 + rt*16 + l15)*64 + kk*32 + g*4;
        float4 a = *(const float4*)rp;
        float4 b = *(const float4*)(rp + 16);
        float xs[8] = {a.x,a.y,a.z,a.w,b.x,b.y,b.z,b.w};
#pragma unroll
        for (int j=0;j<8;j++) xh[kk][rt][j] = (short)f2bh(xs[j]*DNORM);
      }
    float mx = -1e30f;
#pragma unroll
    for (int mtl=0; mtl<4; mtl++){
        int mtile = w*4 + mtl;
        bf16x8 pf[2];
#pragma unroll
        for (int kk=0;kk<2;kk++){
            // frag-major: m = mtile*16+l15 -> f = (mtile>>1)*4 + kk*2 + (mtile&1)
            int f = (mtile >> 1)*4 + kk*2 + (mtile & 1);
            pf[kk] = *(const bf16x8*)(Pfh + (f*64 + lane)*8);
        }
        f32x4 acc[2] = {f32x4{0.f,0.f,0.f,0.f}, f32x4{0.f,0.f,0.f,0.f}};
#pragma unroll
        for (int kk=0;kk<2;kk++)
#pragma unroll
          for (int rt=0;rt<2;rt++)
            acc[rt] = MFMA16(xh[kk][rt], pf[kk], acc[rt]);
#pragma unroll
        for (int rt=0;rt<2;rt++)
#pragma unroll
          for (int i=0;i<4;i++) mx = fmaxf(mx, acc[rt][i]);
    }
#pragma unroll
    for (int d=1; d<64; d<<=1) mx = fmaxf(mx, __shfl_xor(mx, d, 64));
    if (lane == 0) red[w] = mx;
    __syncthreads();
    if (tid == 0){
        float m2 = fmaxf(fmaxf(red[0],red[1]), fmaxf(red[2],red[3]));
        atomicMax(kmax_u, mapf(m2));
    }
}

// ---------------- B: per-chunk states S = Kf^T V, z = sum Kf ----------------
__global__ __launch_bounds__(512, 2) void b_kernel(const float* __restrict__ k,
        const float* __restrict__ v,
        const unsigned short* __restrict__ Pfh, const unsigned short* __restrict__ Pfl,
        const unsigned* __restrict__ kmax_u, float* __restrict__ states,
        int CH, int nch){
    __shared__ short Xh[4][64][8], Xl[4][64][8];
    __shared__ unsigned Vt_u[64][36];    // [e][t] packed hi/lo
    __shared__ float diagk_[32];
    int tid = threadIdx.x;
    int lane = tid & 63, w = tid >> 6;
    int l15 = lane & 15, g = lane >> 4;
    int cx = blockIdx.x, bh = blockIdx.y;
    int o = (cx == 0) ? 0 : CONDL + (cx-1)*CH;
    int nsub = ((cx == 0) ? CONDL : CH) >> 5;
    long rowbase = (long)bh * S_TOT + o;
    float kmax = unmapf(*kmax_u);
    f32x4 Sacc[2][4];   // [mt][et]
#pragma unroll
    for (int mt=0;mt<2;mt++)
#pragma unroll
      for (int et=0;et<4;et++) Sacc[mt][et] = f32x4{0.f,0.f,0.f,0.f};
    float zacc[2] = {0.f, 0.f};

    // T14 prefetch: per-thread fixed offsets within a 32-row subtile
    const float* kptr = k + rowbase*64 + (tid >> 4)*64 + (tid & 15)*4;
    const float* vptr = v + rowbase*64 + (tid >> 4)*64 + (tid & 15)*4;
    float4 kpre = *(const float4*)kptr;
    float4 vpre = *(const float4*)vptr;

    for (int st = 0; st < nsub; st++){
        // P0: k conversion (prefetched) + V staging (prefetched)
        conv_store(kpre, tid, Xh, Xl, diagk_);
        {
            int e4 = (tid & 15)*4;
            int t = tid >> 4;
            Vt_u[e4+0][t] = packhl(vpre.x);
            Vt_u[e4+1][t] = packhl(vpre.y);
            Vt_u[e4+2][t] = packhl(vpre.z);
            Vt_u[e4+3][t] = packhl(vpre.w);
        }
        __syncthreads();
        // P1: dd (P-frags streamed from L2-hot global) + kf finalize -> REGISTERS
        // (thread computes exactly the fragment elements it consumes in P2:
        //  rr=0 -> frag j=0..3, rr=1 -> frag j=4..7, per mt)
        f32x4 dk[2][2];
        __builtin_amdgcn_s_setprio(1);
        dd_frags_g(Xh, Xl, lane, w, Pfh, Pfl, dk);
        __builtin_amdgcn_s_setprio(0);
        float zd0 = 0.f, zd1 = 0.f;
        f32x4 ka[2], kb[2];   // [mt]: rr=0 quad / rr=1 quad
#pragma unroll
        for (int rr=0;rr<2;rr++){
            float dg0 = diagk_[rr*16 + g*4 + 0];
            float dg1 = diagk_[rr*16 + g*4 + 1];
            float dg2 = diagk_[rr*16 + g*4 + 2];
            float dg3 = diagk_[rr*16 + g*4 + 3];
#pragma unroll
            for (int mt=0;mt<2;mt++){
                float k0 = RATIO * (__expf(dk[rr][mt][0] - dg0 - kmax) + KEPS);
                float k1 = RATIO * (__expf(dk[rr][mt][1] - dg1 - kmax) + KEPS);
                float k2 = RATIO * (__expf(dk[rr][mt][2] - dg2 - kmax) + KEPS);
                float k3 = RATIO * (__expf(dk[rr][mt][3] - dg3 - kmax) + KEPS);
                if (mt == 0) zd0 += k0+k1+k2+k3; else zd1 += k0+k1+k2+k3;
                f32x4 kv{k0, k1, k2, k3};
                if (rr == 0) ka[mt] = kv; else kb[mt] = kv;
            }
        }
        zd0 += __shfl_xor(zd0, 16, 64); zd0 += __shfl_xor(zd0, 32, 64);
        zd1 += __shfl_xor(zd1, 16, 64); zd1 += __shfl_xor(zd1, 32, 64);
        zacc[0] += zd0; zacc[1] += zd1;
        // prefetch st+1 (covered by the delta MFMAs below)
        if (st + 1 < nsub){
            kpre = *(const float4*)(kptr + (st+1)*2048);
            vpre = *(const float4*)(vptr + (st+1)*2048);
        }
        // P2 (no barrier needed -- kf passes through registers):
        // state delta MFMAs
        __builtin_amdgcn_s_setprio(1);
#pragma unroll
        for (int mt=0;mt<2;mt++){
            bf16x8 kh, kl; sfrag(ka[mt], kb[mt], kh, kl);
#pragma unroll
            for (int et=0;et<4;et++){
                const uint4* vp0 = (const uint4*)&Vt_u[et*16 + l15][g*4];
                const uint4* vp1 = (const uint4*)&Vt_u[et*16 + l15][16 + g*4];
                bf16x8 vh, vl; unpk(*vp0, *vp1, vh, vl);
                Sacc[mt][et] = MFMA16(kh, vh, Sacc[mt][et]);
                Sacc[mt][et] = MFMA16(kh, vl, Sacc[mt][et]);
                Sacc[mt][et] = MFMA16(kl, vh, Sacc[mt][et]);
            }
        }
        __builtin_amdgcn_s_setprio(0);
        __syncthreads();   // end-of-iter: protects Xh/Xl/Vt_u/diagk overwrite
    }
    // write state slot
    float* Sg = states + ((long)(bh*nch + cx)) * SLOT_F;
#pragma unroll
    for (int mt=0;mt<2;mt++)
#pragma unroll
      for (int et=0;et<4;et++)
#pragma unroll
        for (int i=0;i<4;i++)
            Sg[((w*2+mt)*16 + g*4 + i)*64 + et*16 + l15] = Sacc[mt][et][i];
    if (g == 0){
        Sg[16384 + w*32 + l15]      = zacc[0];
        Sg[16384 + w*32 + 16 + l15] = zacc[1];
    }
}

// ---------------- C: exclusive scan over chunk slots ----------------
__global__ __launch_bounds__(256) void scan_kernel(float* __restrict__ states, int nch){
    int idx = blockIdx.x*256 + threadIdx.x;
    if (idx >= SLOT_F) return;
    float* base = states + (long)blockIdx.y * nch * SLOT_F + idx;
    if (nch == 32){
        // hoist all 32 strided loads into registers (all in flight), then store
        float vals[32];
#pragma unroll
        for (int c = 0; c < 32; c++) vals[c] = base[(long)c * SLOT_F];
        float prev = 0.f;
#pragma unroll
        for (int c = 0; c < 32; c++){
            base[(long)c * SLOT_F] = prev;
            prev += vals[c];
        }
    } else {
        float prev = 0.f;
        for (int c = 0; c < nch; c++){
            float t = base[(long)c * SLOT_F];
            base[(long)c * SLOT_F] = prev;
            prev += t;
        }
    }
}

// ---------------- D: outputs (split reg state, kfT tile, 106.75KB LDS) ----------------
__global__ __launch_bounds__(512, 1) void d_kernel(const float* __restrict__ q,
        const float* __restrict__ k, const float* __restrict__ v,
        const unsigned short* __restrict__ Pfh, const unsigned short* __restrict__ Pfl,
        const unsigned* __restrict__ kmax_u, const float* __restrict__ states,
        float* __restrict__ out, int CH, int nch){
    // LDS map (uints), total = 26,688 uints = 106,752 B (1 block/CU):
    //  [0,8192)      qf  [32][256]  row*256 + (m ^ ((row&7)<<2)), packed hi/lo
    //  [8192,16384)  kf  [256][32]  m*32 + (t ^ ((m&7)<<2)), packed hi/lo
    //                  head overlay (live P0-P2 only): dgq[32] f32, rmax[32] u32
    //  [16384,24576) kfT [32][256]  t*256 + (m ^ ((t&7)<<2))  (A-prod B-operand)
    //  [24576,26624) X frags (P0-P3) / A[32][32] + xch (P4-P7)
    //  [26624,26656) den f32[32]
    //  [26656,26688) dgk f32[32]
    __shared__ __attribute__((aligned(16))) unsigned lds_[26688];
    unsigned* qf_  = lds_;
    unsigned* kf_  = lds_ + 8192;
    unsigned* kfT_ = lds_ + 16384;
    unsigned* XA_  = lds_ + 24576;
    float*   den_ = (float*)(lds_ + 26624);
    float*   dgk_ = (float*)(lds_ + 26656);
    float*   dgq_ = (float*)kf_;
    unsigned* rmax_ = kf_ + 32;
    unsigned* A_ = XA_;
    float*   xch_ = (float*)(XA_ + 1024);
    short (*Xh)[64][8] = (short (*)[64][8])XA_;
    short (*Xl)[64][8] = (short (*)[64][8])(XA_ + 1024);

    int tid = threadIdx.x;
    int lane = tid & 63, w = tid >> 6;
    int l15 = lane & 15, g = lane >> 4;
    int et = w & 3, rt = w >> 2;
    bool owner = (rt == 0);     // owners: A at P4, inter at P6, output rows 0..15
    int cx = blockIdx.x, bh = blockIdx.y;
    bool causal = (cx > 0);
    int o = causal ? (CONDL + (cx-1)*CH) : 0;
    int nsub = (causal ? CH : CONDL) >> 5;
    float epsv = causal ? AEPS : 0.f;
    int slot = causal ? cx : 1;
    const float* Sg = states + ((long)(bh*nch + slot)) * SLOT_F;
    long rowbase = (long)bh * S_TOT + o;
    float kmax = unmapf(*kmax_u);
    int xsw = (l15 & 7) << 2;   // row/m/t & 7 == l15 & 7 for all our frag rows

    // P-fragments in registers (coalesced frag-major load, once)
    bf16x8 Ph_r[2][2], Pl_r[2][2];
    load_pfrags_fm(Pfh, Pfl, w, lane, Ph_r, Pl_r);

    // split state -> registers: wave (rt,et) holds features rt*128..+127:
    // S[Mtl][i] = S_mat[(rt*8+Mtl)*16 + g*4 + i][et*16 + l15]
    f32x4 S[8];
#pragma unroll
    for (int Mtl=0; Mtl<8; Mtl++){
#pragma unroll
        for (int i=0;i<4;i++)
            S[Mtl][i] = Sg[((rt*8 + Mtl)*16 + g*4 + i)*64 + et*16 + l15];
    }
    float z0 = Sg[16384 + w*32 + l15];
    float z1 = Sg[16384 + w*32 + 16 + l15];

    // prefetch pointers (per-thread fixed offsets within a 32-row subtile)
    const float* qptr = q + rowbase*64 + (tid >> 4)*64 + (tid & 15)*4;
    const float* kptr = k + rowbase*64 + (tid >> 4)*64 + (tid & 15)*4;
    float4 qpre = *(const float4*)qptr;

    for (int st = 0; st < nsub; st++){
        long r0 = rowbase + st*32;
        // ---- P0: k prefetch issue; q conversion + init ----
        float4 kpre;
        if (causal) kpre = *(const float4*)(kptr + st*2048);
        conv_store(qpre, tid, Xh, Xl, dgq_);
        if (tid < 32){ den_[tid] = 0.f; rmax_[tid] = 0u; }
        __syncthreads();                      // B1
        // ---- P1: dd_q + rowmax atomics ----
        f32x4 dq[2][2];
        dd_frags(Xh, Xl, lane, Ph_r, Pl_r, dq);
#pragma unroll
        for (int rr=0;rr<2;rr++)
#pragma unroll
          for (int i=0;i<4;i++){
            float mx = fmaxf(dq[rr][0][i], dq[rr][1][i]);
            mx = fmaxf(mx, __shfl_xor(mx, 1, 64));
            mx = fmaxf(mx, __shfl_xor(mx, 2, 64));
            mx = fmaxf(mx, __shfl_xor(mx, 4, 64));
            mx = fmaxf(mx, __shfl_xor(mx, 8, 64));
            if (l15 == 0) atomicMax(&rmax_[rr*16 + g*4 + i], mapf(mx));
          }
        __syncthreads();                      // B2
        // ---- P2: qf finalize + den(z) || k conversion (prefetched) ----
        {
#pragma unroll
            for (int rr=0;rr<2;rr++)
#pragma unroll
              for (int i=0;i<4;i++){
                int row = rr*16 + g*4 + i;
                float dgv = dgq_[row];
                float rm = unmapf(rmax_[row]);
                float s1p = 0.f, s2p = 0.f;
#pragma unroll
                for (int mt=0;mt<2;mt++){
                    float qv = RATIO * (__expf(dq[rr][mt][i] - dgv - rm) + KEPS);
                    s1p += qv;
                    s2p += qv * (mt ? z1 : z0);
                    int m = w*32 + mt*16 + l15;
                    qf_[row*256 + (m ^ ((row & 7) << 2))] = packhl(qv);
                }
#pragma unroll
                for (int d2=1; d2<16; d2<<=1){
                    s1p += __shfl_xor(s1p, d2, 64);
                    s2p += __shfl_xor(s2p, d2, 64);
                }
                if (l15 == 0) atomicAdd(&den_[row], s2p + epsv * s1p);
              }
        }
        if (causal) conv_store(kpre, tid, Xh, Xl, dgk_);
        __syncthreads();                      // B3
        // ---- P3: dd_k + kf/kfT finalize (b128/b32 stores) + z update ----
        if (causal){
            f32x4 dk[2][2];
            dd_frags(Xh, Xl, lane, Ph_r, Pl_r, dk);
            float zd0 = 0.f, zd1 = 0.f;
#pragma unroll
            for (int rr=0;rr<2;rr++){
                float dg0 = dgk_[rr*16 + g*4 + 0];
                float dg1 = dgk_[rr*16 + g*4 + 1];
                float dg2 = dgk_[rr*16 + g*4 + 2];
                float dg3 = dgk_[rr*16 + g*4 + 3];
#pragma unroll
                for (int mt=0;mt<2;mt++){
                    float k0 = RATIO * (__expf(dk[rr][mt][0] - dg0 - kmax) + KEPS);
                    float k1 = RATIO * (__expf(dk[rr][mt][1] - dg1 - kmax) + KEPS);
                    float k2 = RATIO * (__expf(dk[rr][mt][2] - dg2 - kmax) + KEPS);
                    float k3 = RATIO * (__expf(dk[rr][mt][3] - dg3 - kmax) + KEPS);
                    if (mt == 0) zd0 += k0+k1+k2+k3; else zd1 += k0+k1+k2+k3;
                    uint4 kw;
                    kw.x = packhl(k0); kw.y = packhl(k1);
                    kw.z = packhl(k2); kw.w = packhl(k3);
                    int m = w*32 + mt*16 + l15;
                    *(uint4*)&kf_[m*32 + ((rr*16 + g*4) ^ xsw)] = kw;
                    // kfT: same values, transposed tile (qf-identical pattern)
                    int t0r = rr*16 + g*4;
                    kfT_[(t0r+0)*256 + (m ^ ((((g*4)+0) & 7) << 2))] = kw.x;
                    kfT_[(t0r+1)*256 + (m ^ ((((g*4)+1) & 7) << 2))] = kw.y;
                    kfT_[(t0r+2)*256 + (m ^ ((((g*4)+2) & 7) << 2))] = kw.z;
                    kfT_[(t0r+3)*256 + (m ^ ((((g*4)+3) & 7) << 2))] = kw.w;
                }
            }
            zd0 += __shfl_xor(zd0, 16, 64); zd0 += __shfl_xor(zd0, 32, 64);
            zd1 += __shfl_xor(zd1, 16, 64); zd1 += __shfl_xor(zd1, 32, 64);
            z0 += zd0; z1 += zd1;
        }
        __syncthreads();                      // B4
        // ---- P4: q prefetch (st+1); owners: A-product; rt=1: inter + slot ----
        if (st + 1 < nsub) qpre = *(const float4*)(qptr + (st+1)*2048);
        float vv[8];
        if (causal){
            const float* vb = v + r0*64 + et*16 + l15;
#pragma unroll
            for (int p2=0;p2<2;p2++)
#pragma unroll
              for (int j=0;j<4;j++)
                vv[p2*4+j] = vb[(p2*16 + g*4 + j)*64];
        }
        f32x4 Cp0{0.f,0.f,0.f,0.f}, Cp1{0.f,0.f,0.f,0.f};
        if (owner){
            if (causal){
                int ar = et >> 1, tt = et & 1;
                int t = tt*16 + l15;
                int tb = t*256;
                f32x4 c{0.f,0.f,0.f,0.f};
                int rowb = (ar*16 + l15)*256;
                __builtin_amdgcn_s_setprio(1);
#pragma unroll
                for (int kt=0;kt<8;kt++){
                    uint4 q0 = *(const uint4*)&qf_[rowb + ((kt*32 + g*4) ^ xsw)];
                    uint4 q1 = *(const uint4*)&qf_[rowb + ((kt*32 + 16 + g*4) ^ xsw)];
                    bf16x8 qh, ql; unpk(q0, q1, qh, ql);
                    uint4 kt0 = *(const uint4*)&kfT_[tb + ((kt*32 + g*4) ^ xsw)];
                    uint4 kt1 = *(const uint4*)&kfT_[tb + ((kt*32 + 16 + g*4) ^ xsw)];
                    bf16x8 kh, kl; unpk(kt0, kt1, kh, kl);
                    c = MFMA16(qh, kh, c);
                    c = MFMA16(qh, kl, c);
                    c = MFMA16(ql, kh, c);
                }
                __builtin_amdgcn_s_setprio(0);
#pragma unroll
                for (int i=0;i<4;i++){
                    int r = ar*16 + g*4 + i;
                    float a = (t <= r) ? c[i] : 0.f;
                    A_[r*32 + (t ^ ((r & 7) << 2))] = packhl(a);
                    float p = a;
                    p += __shfl_xor(p, 1, 64);
                    p += __shfl_xor(p, 2, 64);
                    p += __shfl_xor(p, 4, 64);
                    p += __shfl_xor(p, 8, 64);
                    if (l15 == 0) atomicAdd(&den_[r], p);
                }
            }
        } else {
            __builtin_amdgcn_s_setprio(1);
            inter_half(qf_, S, rt, l15, g, xsw, Cp0, Cp1);
            __builtin_amdgcn_s_setprio(0);
            // away partial (row-tile 0) -> slot et; keep Cp1 (our quadrant)
            *(float4*)&xch_[(et*64 + lane)*4] = float4{Cp0[0],Cp0[1],Cp0[2],Cp0[3]};
        }
        __syncthreads();                      // B5
        // ---- P6: owners: inter + partner-add + slot write; all: delta + intra ----
        if (owner){
            __builtin_amdgcn_s_setprio(1);
            inter_half(qf_, S, rt, l15, g, xsw, Cp0, Cp1);
            __builtin_amdgcn_s_setprio(0);
            float4 pp = *(const float4*)&xch_[(et*64 + lane)*4];
            Cp0[0] += pp.x; Cp0[1] += pp.y; Cp0[2] += pp.z; Cp0[3] += pp.w;
            // away partial (row-tile 1) for partner
            *(float4*)&xch_[(et*64 + lane)*4] = float4{Cp1[0],Cp1[1],Cp1[2],Cp1[3]};
        }
        if (causal){
            f32x4 va{vv[0], vv[1], vv[2], vv[3]};
            f32x4 vb2{vv[4], vv[5], vv[6], vv[7]};
            bf16x8 vh, vl; sfrag(va, vb2, vh, vl);
            // delta over own feature half: S += Kf^T V
            __builtin_amdgcn_s_setprio(1);
#pragma unroll
            for (int Mtl=0;Mtl<8;Mtl++){
                int mb = ((rt*8 + Mtl)*16 + l15)*32;
                uint4 k0 = *(const uint4*)&kf_[mb + ((g*4) ^ xsw)];
                uint4 k1 = *(const uint4*)&kf_[mb + ((16 + g*4) ^ xsw)];
                bf16x8 kh, kl; unpk(k0, k1, kh, kl);
                S[Mtl] = MFMA16(kh, vh, S[Mtl]);
                S[Mtl] = MFMA16(kh, vl, S[Mtl]);
                S[Mtl] = MFMA16(kl, vh, S[Mtl]);
            }
            __builtin_amdgcn_s_setprio(0);
            // intra: A @ V for this wave's output row-tile (rt)
            int rb = (rt*16 + l15)*32;
            uint4 a0 = *(const uint4*)&A_[rb + ((g*4) ^ xsw)];
            uint4 a1 = *(const uint4*)&A_[rb + ((16 + g*4) ^ xsw)];
            bf16x8 ah, al; unpk(a0, a1, ah, al);
            f32x4& Ct = owner ? Cp0 : Cp1;
            Ct = MFMA16(ah, vh, Ct);
            Ct = MFMA16(ah, vl, Ct);
            Ct = MFMA16(al, vh, Ct);
        }
        if (owner){
#pragma unroll
            for (int i=0;i<4;i++){
                int row = g*4 + i;
                out[(r0 + row)*64 + et*16 + l15] = Cp0[i] / den_[row];
            }
        }
        __syncthreads();                      // B6
        // ---- P7: rt=1 waves: partner-add + output rows 16..31 ----
        if (!owner){
            float4 pp = *(const float4*)&xch_[(et*64 + lane)*4];
            Cp1[0] += pp.x; Cp1[1] += pp.y; Cp1[2] += pp.z; Cp1[3] += pp.w;
#pragma unroll
            for (int i=0;i<4;i++){
                int row = 16 + g*4 + i;
                out[(r0 + row)*64 + et*16 + l15] = Cp1[i] / den_[row];
            }
        }
        __syncthreads();                      // B7 (end)
    }
}

extern "C" void kernel_launch(void* const* d_in, const int* in_sizes, int n_in,
                              void* d_out, int out_size, void* d_ws, size_t ws_size,
                              hipStream_t stream) {
    const float* q = (const float*)d_in[0];
    const float* k = (const float*)d_in[1];
    const float* v = (const float*)d_in[2];
    const float* proj = (const float*)d_in[3];
    float* out = (float*)d_out;

    unsigned* kmax_u = (unsigned*)d_ws;
    // legacy flat Ph/Pl region at [256, 256+64KB) left unused
    unsigned short* Pfh = (unsigned short*)((char*)d_ws + 256 + 65536);
    unsigned short* Pfl = Pfh + 16384;
    float* states = (float*)((char*)d_ws + 256 + 131072);
    size_t fixed = 256 + 131072;

    int CH, nch;
    size_t need128 = fixed + (size_t)64 * 32 * SLOT_F * 4;
    if (ws_size >= need128){ CH = 128; nch = 32; }
    else                  { CH = 992; nch = 5;  }

    hipMemsetAsync(d_ws, 0, 4, stream);
    hipLaunchKernelGGL(init_p_kernel, dim3(64), dim3(256), 0, stream, proj, Pfh, Pfl);
    hipLaunchKernelGGL(kmax_kernel, dim3(8192), dim3(256), 0, stream, k, Pfh, kmax_u);
    hipLaunchKernelGGL(b_kernel, dim3(nch, 64), dim3(512), 0, stream, k, v, Pfh, Pfl, kmax_u, states, CH, nch);
    hipLaunchKernelGGL(scan_kernel, dim3(65, 64), dim3(256), 0, stream, states, nch);
    hipLaunchKernelGGL(d_kernel, dim3(nch, 64), dim3(512), 0, stream, q, k, v, Pfh, Pfl, kmax_u, states, out, CH, nch);
}